// Round 1
// baseline (520.463 us; speedup 1.0000x reference)
//
#include <hip/hip_runtime.h>
#include <math.h>

// ---------------------------------------------------------------------------
// BasedBlock: B=4 L=2048 d=1024 h=16 f=16 hd=64 w=64, D=1+f+f*f=273
// Round 6: phaseC3 — 1-wave/64-thread blocks (4096), barrier-free.
//   * LDS 12.8KB/block (S_l[32][128] + qs[32][36]) -> 12 blocks/CU
//   * Qf gen via dup+rotated q-table: aligned float4 LDS reads (j-side) +
//     <=2 scalar reads (i-side), replacing ~280 ds_read_b32/wave
//   * causal pruning: quarter qw does 2(qw+1) intra sn-steps, (qw+1) PV ks
// ---------------------------------------------------------------------------

#define LL 2048
#define DD 1024
#define DFEAT 273
#define NC 16
#define CHUNK 128

typedef __attribute__((ext_vector_type(8))) short short8;
typedef __attribute__((ext_vector_type(4))) float f32x4;

#define SQ 0.42044820762685725f   // sqrt(1/(sqrt(2)*sqrt(16))) = sqrt(0.176776...)
#define LF 1.18920711500272107f   // 0.5 / SQ

__device__ __forceinline__ float4 f4(float a, float b, float c, float d) {
  float4 r; r.x = a; r.y = b; r.z = c; r.w = d; return r;
}

__device__ __forceinline__ unsigned short f2bf(float f) {
  union { float f; unsigned u; } v; v.f = f;
  unsigned r = v.u + 0x7fffu + ((v.u >> 16) & 1u);
  return (unsigned short)(r >> 16);
}

__device__ __forceinline__ float bf2f(unsigned short u) {
  union { unsigned u; float f; } v; v.u = ((unsigned)u) << 16; return v.f;
}

// --------------------------- cast kernels ----------------------------------
__global__ __launch_bounds__(256) void cast_bf16(
    const float* __restrict__ in, unsigned short* __restrict__ o, int n4) {
  int i = blockIdx.x * 256 + threadIdx.x;
  if (i < n4) {
    float4 v = ((const float4*)in)[i];
    ushort4 r;
    r.x = f2bf(v.x); r.y = f2bf(v.y); r.z = f2bf(v.z); r.w = f2bf(v.w);
    ((ushort4*)o)[i] = r;
  }
}

// W[K][N] fp32 -> Wt[N][K] bf16
__global__ __launch_bounds__(256) void castT(
    const float* __restrict__ W, unsigned short* __restrict__ Wt, int K, int N) {
  __shared__ float t[64][65];
  int k0 = blockIdx.x * 64, n0 = blockIdx.y * 64;
  int tid = threadIdx.x;
#pragma unroll
  for (int p = 0; p < 16; p++) {
    int idx = p * 256 + tid;
    int r = idx >> 6, c = idx & 63;
    t[r][c] = W[(size_t)(k0 + r) * N + n0 + c];
  }
  __syncthreads();
#pragma unroll
  for (int p = 0; p < 16; p++) {
    int idx = p * 256 + tid;
    int rn = idx >> 6, ck = idx & 63;
    Wt[(size_t)(n0 + rn) * K + k0 + ck] = f2bf(t[ck][rn]);
  }
}

// --------------------------- MFMA GEMM -------------------------------------
__global__ __launch_bounds__(256) void gemm_mfma(
    const unsigned short* __restrict__ A, const unsigned short* __restrict__ Bt,
    const float* __restrict__ bias, float* __restrict__ C,
    unsigned short* __restrict__ Cb, int M, int N, int K) {
  __shared__ unsigned short As[128 * 64];
  __shared__ unsigned short Bs[128 * 64];
  const int tid = threadIdx.x;
  const int lane = tid & 63, w = tid >> 6;
  const int row0 = blockIdx.x * 128, col0 = blockIdx.y * 128;
  const int wm0 = (w & 1) * 64, wn0 = (w >> 1) * 64;
  const int lr = lane >> 3;
  const int gc = (lane & 7) ^ lr;
  const unsigned short* aP = A + (size_t)(row0 + w * 32 + lr) * K + gc * 8;
  const unsigned short* bP = Bt + (size_t)(col0 + w * 32 + lr) * K + gc * 8;
  unsigned short* asW = As + w * 2048;
  unsigned short* bsW = Bs + w * 2048;
  const int m15 = lane & 15, quad = lane >> 4;
  f32x4 acc[4][4] = {};
  for (int k0 = 0; k0 < K; k0 += 64) {
#pragma unroll
    for (int i = 0; i < 4; i++) {
      __builtin_amdgcn_global_load_lds(
          (const __attribute__((address_space(1))) unsigned int*)(const void*)(aP + (size_t)(i * 8) * K + k0),
          (__attribute__((address_space(3))) unsigned int*)(void*)(asW + i * 512), 16, 0, 0);
      __builtin_amdgcn_global_load_lds(
          (const __attribute__((address_space(1))) unsigned int*)(const void*)(bP + (size_t)(i * 8) * K + k0),
          (__attribute__((address_space(3))) unsigned int*)(void*)(bsW + i * 512), 16, 0, 0);
    }
    __syncthreads();
#pragma unroll
    for (int ks = 0; ks < 2; ks++) {
      short8 aF[4], bF[4];
#pragma unroll
      for (int mi = 0; mi < 4; mi++) {
        int r = wm0 + mi * 16 + m15;
        int g = (ks * 4 + quad) ^ (r & 7);
        aF[mi] = *(const short8*)(As + r * 64 + g * 8);
      }
#pragma unroll
      for (int ni = 0; ni < 4; ni++) {
        int r = wn0 + ni * 16 + m15;
        int g = (ks * 4 + quad) ^ (r & 7);
        bF[ni] = *(const short8*)(Bs + r * 64 + g * 8);
      }
#pragma unroll
      for (int mi = 0; mi < 4; mi++)
#pragma unroll
        for (int ni = 0; ni < 4; ni++)
          acc[mi][ni] = __builtin_amdgcn_mfma_f32_16x16x32_bf16(
              aF[mi], bF[ni], acc[mi][ni], 0, 0, 0);
    }
    __syncthreads();
  }
#pragma unroll
  for (int mi = 0; mi < 4; mi++)
#pragma unroll
    for (int ni = 0; ni < 4; ni++) {
      int col = col0 + wn0 + ni * 16 + m15;
      float bb = bias[col];
#pragma unroll
      for (int r = 0; r < 4; r++) {
        int row = row0 + wm0 + mi * 16 + quad * 4 + r;
        float val = acc[mi][ni][r] + bb;
        if (Cb) Cb[(size_t)row * N + col] = f2bf(val);
        else C[(size_t)row * N + col] = val;
      }
    }
}

// ------------------------------ transV -------------------------------------
// v_b[t][h*64+c] -> vT[bh][c][t]
__global__ __launch_bounds__(256) void transV(
    const unsigned short* __restrict__ v_b, unsigned short* __restrict__ vT) {
  __shared__ unsigned short Tv[64][72];
  const int blk = blockIdx.x;
  const int bh = blk >> 5, tt = blk & 31;
  const int b = bh >> 4, hh = bh & 15;
  const int t0 = tt * 64;
  const int tid = threadIdx.x;
  {
    int t = tid >> 2, cs = tid & 3;
    const unsigned short* p = v_b + ((size_t)(b * LL + t0 + t)) * DD + hh * 64 + cs * 16;
    *(short8*)&Tv[t][cs * 16] = *(const short8*)p;
    *(short8*)&Tv[t][cs * 16 + 8] = *(const short8*)(p + 8);
  }
  __syncthreads();
  {
    int c = tid & 63, ts = tid >> 6;
    unsigned short vals[16];
#pragma unroll
    for (int j = 0; j < 16; j++) vals[j] = Tv[ts * 16 + j][c];
    unsigned short* op = vT + ((size_t)bh * 64 + c) * LL + t0 + ts * 16;
    *(short8*)op = *(short8*)&vals[0];
    *(short8*)(op + 8) = *(short8*)&vals[8];
  }
}

// ------------------------------ phase A ------------------------------------
// KVc_t[bh][ck][c][f] = sum_t Kf[t][f] V[t][c] (bf16); kstc[bh][ck][f].
__global__ __launch_bounds__(256) void phaseA2(
    const unsigned short* __restrict__ klin, const unsigned short* __restrict__ vT,
    unsigned short* __restrict__ KVc_t, unsigned short* __restrict__ kstc) {
  __shared__ unsigned short kT[16][136];   // kT[i][t] = bf16(k[t][i]*SQ)
  const int tid = threadIdx.x, lane = tid & 63, w = tid >> 6;
  const int m15 = lane & 15, quad = lane >> 4;
  const int bh = blockIdx.x >> 4, ck = blockIdx.x & 15;
  const int b = bh >> 4, hh = bh & 15;
  const int t0 = ck * CHUNK;
  {
    int r = tid >> 1, half = tid & 1;
    short8 kv = *(const short8*)(klin + ((size_t)(b * LL + t0 + r)) * 256 + hh * 16 + half * 8);
#pragma unroll
    for (int j = 0; j < 8; j++)
      kT[half * 8 + j][r] = f2bf(bf2f(((unsigned short*)&kv)[j]) * SQ);
  }
  __syncthreads();
  short8 ones8 = {16256, 16256, 16256, 16256, 16256, 16256, 16256, 16256};
  short8 zer8 = {0, 0, 0, 0, 0, 0, 0, 0};
  f32x4 acc[5][5] = {};
  const unsigned short* vbase = vT + (size_t)bh * 64 * LL + t0;
#pragma unroll
  for (int ks = 0; ks < 4; ++ks) {
    const int tt = ks * 32 + quad * 8;
    short8 aF[5], bF[5];
#pragma unroll
    for (int mi = 0; mi < 5; mi++) {
      int r = (w * 5 + mi) * 16 + m15;
      short8 av;
      unsigned short* pv = (unsigned short*)&av;
      if (r == 0) {
        av = ones8;
      } else if (r < 17) {
        short8 k1 = *(const short8*)&kT[r - 1][tt];
#pragma unroll
        for (int j = 0; j < 8; j++) pv[j] = f2bf(bf2f(((unsigned short*)&k1)[j]) * LF);
      } else if (r < DFEAT) {
        int ij = r - 17;
        short8 k1 = *(const short8*)&kT[ij >> 4][tt];
        short8 k2 = *(const short8*)&kT[ij & 15][tt];
#pragma unroll
        for (int j = 0; j < 8; j++)
          pv[j] = f2bf(bf2f(((unsigned short*)&k1)[j]) * bf2f(((unsigned short*)&k2)[j]));
      } else {
        av = zer8;
      }
      aF[mi] = av;
    }
#pragma unroll
    for (int ni = 0; ni < 4; ni++)
      bF[ni] = *(const short8*)(vbase + ((size_t)(ni * 16 + m15)) * LL + tt);
    bF[4] = (m15 == 0) ? ones8 : zer8;
#pragma unroll
    for (int mi = 0; mi < 5; mi++)
#pragma unroll
      for (int ni = 0; ni < 5; ni++)
        acc[mi][ni] = __builtin_amdgcn_mfma_f32_16x16x32_bf16(
            aF[mi], bF[ni], acc[mi][ni], 0, 0, 0);
  }
  const size_t cb = ((size_t)bh * NC + ck) * (64 * 288);
  const size_t kb = ((size_t)bh * NC + ck) * 288;
#pragma unroll
  for (int mi = 0; mi < 5; mi++) {
    int fb = (w * 5 + mi) * 16 + quad * 4;
    if (fb < 288) {
#pragma unroll
      for (int ni = 0; ni < 4; ni++) {
        int c = ni * 16 + m15;
        ushort4 sv;
        sv.x = f2bf(acc[mi][ni][0]); sv.y = f2bf(acc[mi][ni][1]);
        sv.z = f2bf(acc[mi][ni][2]); sv.w = f2bf(acc[mi][ni][3]);
        *(ushort4*)(KVc_t + cb + (size_t)c * 288 + fb) = sv;
      }
      if (m15 == 0) {
        ushort4 sv;
        sv.x = f2bf(acc[mi][4][0]); sv.y = f2bf(acc[mi][4][1]);
        sv.z = f2bf(acc[mi][4][2]); sv.w = f2bf(acc[mi][4][3]);
        *(ushort4*)(kstc + kb + fb) = sv;
      }
    }
  }
}

// ------------------------------ phase B ------------------------------------
// Blocks [0,576): KV scan (thread per (bh,c,f8)); [576,585): kst scan.
__global__ __launch_bounds__(256) void phaseB3(
    const unsigned short* __restrict__ KVc_t, const unsigned short* __restrict__ kstc,
    const float* __restrict__ kv0, const float* __restrict__ kst0,
    unsigned short* __restrict__ KVp_t, unsigned short* __restrict__ kstp,
    float* __restrict__ kv_out, float* __restrict__ kst_out) {
  const int tid = threadIdx.x;
  if (blockIdx.x < 576) {
    int gid = blockIdx.x * 256 + tid;
    int bh = gid / 2304, rem = gid - bh * 2304;
    int c = rem / 36, fg = rem - c * 36;
    int f0 = fg * 8;
    float acc[8];
#pragma unroll
    for (int j = 0; j < 8; j++) {
      int f = f0 + j;
      acc[j] = (f < DFEAT) ? kv0[((size_t)bh * DFEAT + f) * 64 + c] : 0.0f;
    }
    size_t base = ((size_t)bh * NC) * (64 * 288) + (size_t)c * 288 + f0;
    for (int ck = 0; ck < NC; ck++) {
      size_t idx = base + (size_t)ck * (64 * 288);
      short8 t = *(const short8*)(KVc_t + idx);
      unsigned short ov[8];
#pragma unroll
      for (int j = 0; j < 8; j++) {
        ov[j] = f2bf(acc[j]);
        acc[j] += bf2f(((unsigned short*)&t)[j]);
      }
      *(short8*)(KVp_t + idx) = *(short8*)ov;
    }
#pragma unroll
    for (int j = 0; j < 8; j++) {
      int f = f0 + j;
      if (f < DFEAT) kv_out[((size_t)bh * DFEAT + f) * 64 + c] = acc[j];
    }
  } else {
    int idx0 = (blockIdx.x - 576) * 256 + tid;   // 0..2303
    int bh = idx0 / 36, fg = idx0 - bh * 36;
    int f0 = fg * 8;
    float acc[8];
#pragma unroll
    for (int j = 0; j < 8; j++) {
      int f = f0 + j;
      acc[j] = (f < DFEAT) ? kst0[bh * DFEAT + f] : 0.0f;
    }
    for (int ck = 0; ck < NC; ck++) {
      size_t idx = ((size_t)bh * NC + ck) * 288 + f0;
      short8 t = *(const short8*)(kstc + idx);
      unsigned short ov[8];
#pragma unroll
      for (int j = 0; j < 8; j++) {
        ov[j] = f2bf(acc[j]);
        acc[j] += bf2f(((unsigned short*)&t)[j]);
      }
      *(short8*)(kstp + idx) = *(short8*)ov;
    }
#pragma unroll
    for (int j = 0; j < 8; j++) {
      int f = f0 + j;
      if (f < DFEAT) kst_out[bh * DFEAT + f] = acc[j];
    }
  }
}

// ------------------------------ phase C ------------------------------------
// 1 wave / 64 threads per block; 4096 blocks = (bh, ck, qw) with qw = 32-row
// quarter of the 128-row chunk. Barrier-free (S_l strictly wave-private).
__global__ __launch_bounds__(64, 3) void phaseC3(
    const unsigned short* __restrict__ qlin, const unsigned short* __restrict__ klin,
    const unsigned short* __restrict__ vT, const unsigned short* __restrict__ KVp_t,
    const unsigned short* __restrict__ kstp, unsigned short* __restrict__ outs) {
  __shared__ float qs[32][36];              // [0..15]=q*SQ, [16..31]=rot-by-7 dup
  __shared__ unsigned short S_l[32 * 128];  // 8 KB, swizzled intra scores
  const int lane = threadIdx.x;
  const int m15 = lane & 15, quad = lane >> 4;
  const int blk = blockIdx.x;
  const int bh = blk >> 6, ck = (blk >> 2) & 15, qw = blk & 3;
  const int b = bh >> 4, hh = bh & 15;
  const int t0 = ck * CHUNK;
  const int tr0 = qw * 32;
  const unsigned short* qbase = qlin + ((size_t)(b * LL + t0 + tr0)) * 256 + hh * 16;
  const unsigned short* kbase = klin + ((size_t)(b * LL + t0)) * 256 + hh * 16;
  // ---- fill qs (wave-private rows, no barrier) ----
  {
    int r = lane >> 1, h8 = lane & 1;
    short8 qv = *(const short8*)(qbase + (size_t)r * 256 + h8 * 8);
    float qf[8];
#pragma unroll
    for (int j = 0; j < 8; j++) qf[j] = bf2f(((unsigned short*)&qv)[j]) * SQ;
    *(float4*)&qs[r][h8 * 8] = f4(qf[0], qf[1], qf[2], qf[3]);
    *(float4*)&qs[r][h8 * 8 + 4] = f4(qf[4], qf[5], qf[6], qf[7]);
#pragma unroll
    for (int j = 0; j < 8; j++)
      qs[r][16 + ((h8 * 8 + j + 9) & 15)] = qf[j];   // rot[m] = q[(m+7)&15]
  }
  short8 ones8 = {16256, 16256, 16256, 16256, 16256, 16256, 16256, 16256};
  short8 zer8 = {0, 0, 0, 0, 0, 0, 0, 0};
  f32x4 acc[2][5] = {};
  const unsigned short* KVb = KVp_t + ((size_t)(bh * NC + ck)) * (64 * 288);
  const unsigned short* kstb = kstp + ((size_t)(bh * NC + ck)) * 288;
  // ---- pass 1: inter (Qf @ KV'), K = 288 ----
#pragma unroll
  for (int ks = 0; ks < 9; ++ks) {
    const int fs = ks * 32 + quad * 8;
    short8 aF[2], bF[5];
#pragma unroll
    for (int ni = 0; ni < 4; ni++)
      bF[ni] = *(const short8*)(KVb + ((size_t)(ni * 16 + m15)) * 288 + fs);
    bF[4] = (m15 == 0) ? *(const short8*)(kstb + fs) : zer8;
#pragma unroll
    for (int mi = 0; mi < 2; mi++) {
      const float* qr = &qs[mi * 16 + m15][0];
      unsigned short pv[8];
      if (ks == 0) {
        // f = quad*8 + j in [0,32): mix of const-1, linear, i=0 products
        float qr0 = qr[0];
#pragma unroll
        for (int j = 0; j < 8; j++) {
          int f = (quad << 3) + j;
          int fl = f - 1; fl = fl < 0 ? 0 : fl;
          int fm = f - 17; fm = fm < 0 ? 0 : fm;     // < 16 here
          float lin = qr[fl] * LF;
          float prod = qr0 * qr[fm];
          float val = (f == 0) ? 1.0f : ((f < 17) ? lin : prod);
          pv[j] = f2bf(val);
        }
      } else {
        // all products: i = (f-17)>>4, jj = (f-17)&15; jj0 in {7,15}
        int base = fs - 17;                 // >= 15
        int i0 = base >> 4;
        float qi0 = qr[i0];
        float qi1 = qr[i0 + 1];
        const float* qv = qr + 16 + (base & 8);   // aligned 32B window (rot dup)
        float qj[8];
        *(float4*)&qj[0] = *(const float4*)qv;
        *(float4*)&qj[4] = *(const float4*)(qv + 4);
        float qiB = (quad & 1) ? qi0 : qi1;       // jj0==7 -> i const; ==15 -> bump after j=0
#pragma unroll
        for (int j = 0; j < 8; j++) {
          float qi = (j == 0) ? qi0 : qiB;
          float val = qi * qj[j];
          if (ks == 8) val = ((quad << 3) + j < 17) ? val : 0.0f;  // f >= 273 -> 0
          pv[j] = f2bf(val);
        }
      }
      aF[mi] = *(short8*)pv;
    }
#pragma unroll
    for (int mi = 0; mi < 2; mi++)
#pragma unroll
      for (int ni = 0; ni < 5; ni++)
        acc[mi][ni] = __builtin_amdgcn_mfma_f32_16x16x32_bf16(
            aF[mi], bF[ni], acc[mi][ni], 0, 0, 0);
  }
  // ---- intra: u = q@k^T (K=16 pad 32) -> poly/mask -> S_l (wave-private) ----
  const int nsn = 2 * qw + 2;               // s covers [0, (qw+1)*32)
  {
    short8 aU[2], bU[8];
    aU[0] = (quad < 2) ? *(const short8*)(qbase + (size_t)m15 * 256 + quad * 8) : zer8;
    aU[1] = (quad < 2) ? *(const short8*)(qbase + (size_t)(16 + m15) * 256 + quad * 8) : zer8;
#pragma unroll
    for (int sn = 0; sn < 8; sn++) {
      if (sn < nsn) {
        int s = sn * 16 + m15;
        bU[sn] = (quad < 2) ? *(const short8*)(kbase + (size_t)s * 256 + quad * 8) : zer8;
      }
    }
#pragma unroll
    for (int mi = 0; mi < 2; mi++) {
#pragma unroll
      for (int sn = 0; sn < 8; sn++) {
        if (sn < nsn) {
          f32x4 zz = {0.f, 0.f, 0.f, 0.f};
          f32x4 u = __builtin_amdgcn_mfma_f32_16x16x32_bf16(aU[mi], bU[sn], zz, 0, 0, 0);
          int s = sn * 16 + m15;
          int gRow = s >> 3;
#pragma unroll
          for (int rr = 0; rr < 4; rr++) {
            int tl = mi * 16 + quad * 4 + rr;        // local row 0..31
            int tc = tr0 + tl;                       // chunk-local row for mask
            float uu = u[rr];
            float sv = (s <= tc) ? fmaf(uu, fmaf(uu, 0.03125f, 0.25f), 1.0f) : 0.0f;
            int p = gRow ^ (tl & 7);
            S_l[tl * 128 + p * 8 + (s & 7)] = f2bf(sv);
          }
        }
      }
    }
  }
  // ---- pass 2: S @ V' — no barrier (same-wave LDS RAW) ----
  const unsigned short* vbase = vT + (size_t)bh * 64 * LL + t0;
#pragma unroll
  for (int ks = 0; ks < 4; ++ks) {
    if (ks <= qw) {
      const int tt = ks * 32 + quad * 8;
      short8 aF[2], bF[5];
#pragma unroll
      for (int mi = 0; mi < 2; mi++) {
        int tl = mi * 16 + m15;
        int p = (ks * 4 + quad) ^ (tl & 7);
        aF[mi] = *(const short8*)&S_l[tl * 128 + p * 8];
      }
#pragma unroll
      for (int ni = 0; ni < 4; ni++)
        bF[ni] = *(const short8*)(vbase + ((size_t)(ni * 16 + m15)) * LL + tt);
      bF[4] = (m15 == 0) ? ones8 : zer8;
#pragma unroll
      for (int mi = 0; mi < 2; mi++)
#pragma unroll
        for (int ni = 0; ni < 5; ni++)
          acc[mi][ni] = __builtin_amdgcn_mfma_f32_16x16x32_bf16(
              aF[mi], bF[ni], acc[mi][ni], 0, 0, 0);
    }
  }
  // ---- epilogue ----
#pragma unroll
  for (int mi = 0; mi < 2; mi++) {
#pragma unroll
    for (int rr = 0; rr < 4; rr++) {
      float den = __shfl(acc[mi][4][rr], (lane & 48));
      float inv = 1.0f / (den + 1e-6f);
      int tl = mi * 16 + quad * 4 + rr;
      unsigned short* op = outs + ((size_t)(b * LL + t0 + tr0 + tl)) * DD + hh * 64;
#pragma unroll
      for (int ni = 0; ni < 4; ni++)
        op[ni * 16 + m15] = f2bf(acc[mi][ni][rr] * inv);
    }
  }
}

// --------------------------- last-row k2/v2 --------------------------------
__global__ __launch_bounds__(256) void lastrow_qkv(
    const float* __restrict__ x1,
    const float* __restrict__ Wk, const float* __restrict__ bk,
    const float* __restrict__ Wv, const float* __restrict__ bv,
    float* __restrict__ klast, float* __restrict__ vlast) {
  int gid = blockIdx.x * 256 + threadIdx.x;
  int which = gid >> 12;
  int b = (gid >> 10) & 3;
  int n = gid & 1023;
  const float* W = which ? Wv : Wk;
  const float* xr = x1 + ((size_t)(b * LL + LL - 1)) * DD;
  float s = 0.f;
  for (int k = 0; k < 1024; k++) s = fmaf(xr[k], W[(size_t)k * 1024 + n], s);
  s += which ? bv[n] : bk[n];
  (which ? vlast : klast)[b * 1024 + n] = s;
}

// --------------------------- window attention ------------------------------
__global__ __launch_bounds__(256) void window_attn(
    const float* __restrict__ q2, const float* __restrict__ klast,
    const float* __restrict__ vlast, const float* __restrict__ kbuf,
    const float* __restrict__ vbufw, unsigned short* __restrict__ win) {
  __shared__ float ukT[64][68];
  __shared__ float uvs[64][68];
  __shared__ float S[64][68];
  const int tid = threadIdx.x;
  const int bh = blockIdx.x >> 5, tile = blockIdx.x & 31;
  const int b = bh >> 4, hh = bh & 15;
#pragma unroll
  for (int p = 0; p < 4; p++) {
    int g = tid + p * 256;
    int wi = g >> 4, d4 = (g & 15) * 4;
    const float* kp = (wi < 63) ? (kbuf + ((size_t)hh * 64 + wi + 1) * 64 + d4)
                                : (klast + (size_t)b * 1024 + hh * 64 + d4);
    float4 kk = *(const float4*)kp;
    ukT[d4 + 0][wi] = kk.x; ukT[d4 + 1][wi] = kk.y;
    ukT[d4 + 2][wi] = kk.z; ukT[d4 + 3][wi] = kk.w;
    const float* vp = (wi < 63) ? (vbufw + ((size_t)hh * 64 + wi + 1) * 64 + d4)
                                : (vlast + (size_t)b * 1024 + hh * 64 + d4);
    *(float4*)&uvs[wi][d4] = *(const float4*)vp;
    const float* qp = q2 + ((size_t)(b * LL + tile * 64 + wi)) * DD + hh * 64 + d4;
    *(float4*)&S[wi][d4] = *(const float4*)qp;
  }
  __syncthreads();
  const int tx = tid & 7, ty = tid >> 3;
  const int t2 = ty * 2;
  float a[2][8] = {};
  for (int d = 0; d < 64; ++d) {
    float q0 = S[t2][d], q1 = S[t2 + 1][d];
    float4 u0 = *(const float4*)&ukT[d][tx * 8];
    float4 u1 = *(const float4*)&ukT[d][tx * 8 + 4];
    float uk8[8] = {u0.x, u0.y, u0.z, u0.w, u1.x, u1.y, u1.z, u1.w};
#pragma unroll
    for (int j = 0; j < 8; j++) {
      a[0][j] = fmaf(q0, uk8[j], a[0][j]);
      a[1][j] = fmaf(q1, uk8[j], a[1][j]);
    }
  }
  __syncthreads();
#pragma unroll
  for (int ii = 0; ii < 2; ii++) {
    *(float4*)&S[t2 + ii][tx * 8] =
        f4(a[ii][0] * 0.125f, a[ii][1] * 0.125f, a[ii][2] * 0.125f, a[ii][3] * 0.125f);
    *(float4*)&S[t2 + ii][tx * 8 + 4] =
        f4(a[ii][4] * 0.125f, a[ii][5] * 0.125f, a[ii][6] * 0.125f, a[ii][7] * 0.125f);
  }
  __syncthreads();
  if (tid < 64) {
    float v[64];
#pragma unroll
    for (int i = 0; i < 16; i++) *(float4*)&v[i * 4] = *(const float4*)&S[tid][i * 4];
    float m = v[0];
#pragma unroll
    for (int i = 1; i < 64; i++) m = fmaxf(m, v[i]);
    float l = 0.f;
#pragma unroll
    for (int i = 0; i < 64; i++) { v[i] = expf(v[i] - m); l += v[i]; }
    float inv = 1.0f / l;
#pragma unroll
    for (int i = 0; i < 16; i++)
      *(float4*)&S[tid][i * 4] =
          f4(v[i * 4] * inv, v[i * 4 + 1] * inv, v[i * 4 + 2] * inv, v[i * 4 + 3] * inv);
  }
  __syncthreads();
  float o[2][8] = {};
  for (int w = 0; w < 64; ++w) {
    float a0 = S[t2][w], a1 = S[t2 + 1][w];
    float4 x0 = *(const float4*)&uvs[w][tx * 8];
    float4 x1v = *(const float4*)&uvs[w][tx * 8 + 4];
    float uv8[8] = {x0.x, x0.y, x0.z, x0.w, x1v.x, x1v.y, x1v.z, x1v.w};
#pragma unroll
    for (int j = 0; j < 8; j++) {
      o[0][j] = fmaf(a0, uv8[j], o[0][j]);
      o[1][j] = fmaf(a1, uv8[j], o[1][j]);
    }
  }
#pragma unroll
  for (int ii = 0; ii < 2; ii++) {
    unsigned short* wp = win + ((size_t)(b * LL + tile * 64 + t2 + ii)) * DD + hh * 64 + tx * 8;
    ushort4 r0, r1;
    r0.x = f2bf(o[ii][0]); r0.y = f2bf(o[ii][1]); r0.z = f2bf(o[ii][2]); r0.w = f2bf(o[ii][3]);
    r1.x = f2bf(o[ii][4]); r1.y = f2bf(o[ii][5]); r1.z = f2bf(o[ii][6]); r1.w = f2bf(o[ii][7]);
    *(ushort4*)wp = r0;
    *(ushort4*)(wp + 4) = r1;
  }
}

// ------------------------------ LayerNorm ----------------------------------
__global__ __launch_bounds__(256) void ln_add(
    const float* __restrict__ A, const float* __restrict__ Bm,
    const float* __restrict__ gamma, const float* __restrict__ beta,
    float* __restrict__ out, unsigned short* __restrict__ outb) {
  const int row = blockIdx.x, tid = threadIdx.x;
  float4 va = ((const float4*)(A + (size_t)row * DD))[tid];
  float4 vb = ((const float4*)(Bm + (size_t)row * DD))[tid];
  float4 s4 = f4(va.x + vb.x, va.y + vb.y, va.z + vb.z, va.w + vb.w);
  float s = s4.x + s4.y + s4.z + s4.w;
  float ss = s4.x * s4.x + s4.y * s4.y + s4.z * s4.z + s4.w * s4.w;
  for (int o = 32; o; o >>= 1) { s += __shfl_xor(s, o); ss += __shfl_xor(ss, o); }
  __shared__ float red[8];
  int wid = tid >> 6;
  if ((tid & 63) == 0) { red[wid * 2] = s; red[wid * 2 + 1] = ss; }
  __syncthreads();
  float tot = red[0] + red[2] + red[4] + red[6];
  float tots = red[1] + red[3] + red[5] + red[7];
  float mu = tot * (1.0f / 1024.0f);
  float var = tots * (1.0f / 1024.0f) - mu * mu;
  float rstd = rsqrtf(var + 1e-5f);
  float4 g = ((const float4*)gamma)[tid];
  float4 be = ((const float4*)beta)[tid];
  float4 o = f4((s4.x - mu) * rstd * g.x + be.x, (s4.y - mu) * rstd * g.y + be.y,
                (s4.z - mu) * rstd * g.z + be.z, (s4.w - mu) * rstd * g.w + be.w);
  ((float4*)(out + (size_t)row * DD))[tid] = o;
  if (outb) {
    ushort4 r;
    r.x = f2bf(o.x); r.y = f2bf(o.y); r.z = f2bf(o.z); r.w = f2bf(o.w);
    ((ushort4*)(outb + (size_t)row * DD))[tid] = r;
  }
}

// ------------------------------ launch -------------------------------------
extern "C" void kernel_launch(void* const* d_in, const int* in_sizes, int n_in,
                              void* d_out, int out_size, void* d_ws, size_t ws_size,
                              hipStream_t stream) {
  (void)in_sizes; (void)n_in; (void)out_size; (void)ws_size;
  const float* x      = (const float*)d_in[0];
  const float* kv0    = (const float*)d_in[1];
  const float* kst0   = (const float*)d_in[2];
  const float* kbuf   = (const float*)d_in[3];
  const float* vbufw  = (const float*)d_in[4];
  const float* Wq_lin = (const float*)d_in[5];
  const float* bq_lin = (const float*)d_in[6];
  const float* Wk_lin = (const float*)d_in[7];
  const float* bk_lin = (const float*)d_in[8];
  const float* Wv_lin = (const float*)d_in[9];
  const float* bv_lin = (const float*)d_in[10];
  const float* Wo_lin = (const float*)d_in[11];
  const float* bo_lin = (const float*)d_in[12];
  const float* Wq     = (const float*)d_in[13];
  const float* bq     = (const float*)d_in[14];
  const float* Wk     = (const float*)d_in[15];
  const float* bk     = (const float*)d_in[16];
  const float* Wv     = (const float*)d_in[17];
  const float* bv     = (const float*)d_in[18];
  const float* Wo     = (const float*)d_in[19];
  const float* bo     = (const float*)d_in[20];
  const float* gamma  = (const float*)d_in[21];
  const float* beta   = (const float*)d_in[22];

  float* out = (float*)d_out;
  float* kv_out  = out + 8388608;
  float* kst_out = out + 8388608 + 1118208;

  float* ws = (float*)d_ws;
  const size_t MF = 1024 * 1024;
  // float-offset layout (lifetimes in comments)
  unsigned short* qlin_b = (unsigned short*)(ws);              // [0,1)  until phaseC
  unsigned short* klin_b = (unsigned short*)(ws + 1 * MF);     // [1,2)  until phaseC
  unsigned short* v_b    = (unsigned short*)(ws + 2 * MF);     // [2,6)  until transV
  unsigned short* vT     = (unsigned short*)(ws + 6 * MF);     // [6,10) until phaseC
  unsigned short* KVc_t  = (unsigned short*)(ws + 10 * MF);    // [10,19) A->B
  unsigned short* kstc   = (unsigned short*)(ws + 19 * MF);    // [19,19.15) A->B
  unsigned short* KVp_t  = (unsigned short*)(ws + 20 * MF);    // [20,29) B->C
  unsigned short* kstp   = (unsigned short*)(ws + 29 * MF);    // [29,29.15) B->C
  unsigned short* x_bf   = (unsigned short*)(ws + 30 * MF);    // [30,34) until v GEMM
  unsigned short* outs_bf = (unsigned short*)(ws + 2 * MF);    // [2,6)  C->O1 (v_b dead)
  float* tmp  = ws + 10 * MF;                                  // [10,18) O1->ln (KVc_t dead)
  float* x1   = ws + 20 * MF;                                  // [20,28) (KVp_t dead)
  unsigned short* x1b = (unsigned short*)(ws + 30 * MF);       // [30,32) (x_bf dead)
  float* q2   = ws;                                            // [0,8)  (qlin/klin/outs/vT dead)
  unsigned short* winb = (unsigned short*)(ws + 8 * MF);       // [8,12) (tmp dead)
  float* tmp2 = ws + 12 * MF;                                  // [12,20)
  float* klast = ws + 34 * MF;
  float* vlast = klast + 4096;
  unsigned short* WtQL = (unsigned short*)(ws + 35 * MF);
  unsigned short* WtKL = WtQL + 262144;
  unsigned short* WtVL = WtQL + 524288;
  unsigned short* WtO1 = WtQL + 1572864;
  unsigned short* WtQ2 = WtQL + 2621440;
  unsigned short* WtO2 = WtQL + 3670016;

  dim3 blk(256);
  cast_bf16<<<8192, blk, 0, stream>>>(x, x_bf, 2097152);
  castT<<<dim3(16, 4), blk, 0, stream>>>(Wq_lin, WtQL, 1024, 256);
  castT<<<dim3(16, 4), blk, 0, stream>>>(Wk_lin, WtKL, 1024, 256);
  castT<<<dim3(16, 16), blk, 0, stream>>>(Wv_lin, WtVL, 1024, 1024);
  castT<<<dim3(16, 16), blk, 0, stream>>>(Wo_lin, WtO1, 1024, 1024);
  castT<<<dim3(16, 16), blk, 0, stream>>>(Wq, WtQ2, 1024, 1024);
  castT<<<dim3(16, 16), blk, 0, stream>>>(Wo, WtO2, 1024, 1024);
  gemm_mfma<<<dim3(64, 2), blk, 0, stream>>>(x_bf, WtQL, bq_lin, (float*)0, qlin_b, 8192, 256, 1024);
  gemm_mfma<<<dim3(64, 2), blk, 0, stream>>>(x_bf, WtKL, bk_lin, (float*)0, klin_b, 8192, 256, 1024);
  gemm_mfma<<<dim3(64, 8), blk, 0, stream>>>(x_bf, WtVL, bv_lin, (float*)0, v_b, 8192, 1024, 1024);
  transV<<<2048, blk, 0, stream>>>(v_b, vT);
  phaseA2<<<1024, blk, 0, stream>>>(klin_b, vT, KVc_t, kstc);
  phaseB3<<<585, blk, 0, stream>>>(KVc_t, kstc, kv0, kst0, KVp_t, kstp, kv_out, kst_out);
  phaseC3<<<4096, dim3(64), 0, stream>>>(qlin_b, klin_b, vT, KVp_t, kstp, outs_bf);
  gemm_mfma<<<dim3(64, 8), blk, 0, stream>>>(outs_bf, WtO1, bo_lin, tmp, (unsigned short*)0, 8192, 1024, 1024);
  ln_add<<<8192, blk, 0, stream>>>(x, tmp, gamma, beta, x1, x1b);
  gemm_mfma<<<dim3(64, 8), blk, 0, stream>>>(x1b, WtQ2, bq, q2, (unsigned short*)0, 8192, 1024, 1024);
  lastrow_qkv<<<32, blk, 0, stream>>>(x1, Wk, bk, Wv, bv, klast, vlast);
  window_attn<<<2048, blk, 0, stream>>>(q2, klast, vlast, kbuf, vbufw, winb);
  gemm_mfma<<<dim3(64, 8), blk, 0, stream>>>(winb, WtO2, bo, tmp2, (unsigned short*)0, 8192, 1024, 1024);
  ln_add<<<8192, blk, 0, stream>>>(x1, tmp2, gamma, beta, out, (unsigned short*)0);
}

// Round 2
// 494.300 us; speedup vs baseline: 1.0529x; 1.0529x over previous
//
#include <hip/hip_runtime.h>
#include <math.h>

// ---------------------------------------------------------------------------
// BasedBlock: B=4 L=2048 d=1024 h=16 f=16 hd=64 w=64, D=1+f+f*f=273
// Round 7: window_attn -> MFMA (window_attn2 + prep_window), q2 kept in bf16.
//   * prep_window: bf16 ukb[bh][w][d], uvT[bh][c][w] built once (L2-resident)
//   * window_attn2: 4-wave blocks, 128 q-rows, barrier-free; QK^T and PV on
//     MFMA; wave-parallel softmax via shfl_xor on C-fragment layout;
//     A weights staged bf16 through wave-private swizzled S_l (16KB LDS)
// ---------------------------------------------------------------------------

#define LL 2048
#define DD 1024
#define DFEAT 273
#define NC 16
#define CHUNK 128

typedef __attribute__((ext_vector_type(8))) short short8;
typedef __attribute__((ext_vector_type(4))) float f32x4;

#define SQ 0.42044820762685725f   // sqrt(1/(sqrt(2)*sqrt(16))) = sqrt(0.176776...)
#define LF 1.18920711500272107f   // 0.5 / SQ

__device__ __forceinline__ float4 f4(float a, float b, float c, float d) {
  float4 r; r.x = a; r.y = b; r.z = c; r.w = d; return r;
}

__device__ __forceinline__ unsigned short f2bf(float f) {
  union { float f; unsigned u; } v; v.f = f;
  unsigned r = v.u + 0x7fffu + ((v.u >> 16) & 1u);
  return (unsigned short)(r >> 16);
}

__device__ __forceinline__ float bf2f(unsigned short u) {
  union { unsigned u; float f; } v; v.u = ((unsigned)u) << 16; return v.f;
}

// --------------------------- cast kernels ----------------------------------
__global__ __launch_bounds__(256) void cast_bf16(
    const float* __restrict__ in, unsigned short* __restrict__ o, int n4) {
  int i = blockIdx.x * 256 + threadIdx.x;
  if (i < n4) {
    float4 v = ((const float4*)in)[i];
    ushort4 r;
    r.x = f2bf(v.x); r.y = f2bf(v.y); r.z = f2bf(v.z); r.w = f2bf(v.w);
    ((ushort4*)o)[i] = r;
  }
}

// W[K][N] fp32 -> Wt[N][K] bf16
__global__ __launch_bounds__(256) void castT(
    const float* __restrict__ W, unsigned short* __restrict__ Wt, int K, int N) {
  __shared__ float t[64][65];
  int k0 = blockIdx.x * 64, n0 = blockIdx.y * 64;
  int tid = threadIdx.x;
#pragma unroll
  for (int p = 0; p < 16; p++) {
    int idx = p * 256 + tid;
    int r = idx >> 6, c = idx & 63;
    t[r][c] = W[(size_t)(k0 + r) * N + n0 + c];
  }
  __syncthreads();
#pragma unroll
  for (int p = 0; p < 16; p++) {
    int idx = p * 256 + tid;
    int rn = idx >> 6, ck = idx & 63;
    Wt[(size_t)(n0 + rn) * K + k0 + ck] = f2bf(t[ck][rn]);
  }
}

// --------------------------- MFMA GEMM -------------------------------------
__global__ __launch_bounds__(256) void gemm_mfma(
    const unsigned short* __restrict__ A, const unsigned short* __restrict__ Bt,
    const float* __restrict__ bias, float* __restrict__ C,
    unsigned short* __restrict__ Cb, int M, int N, int K) {
  __shared__ unsigned short As[128 * 64];
  __shared__ unsigned short Bs[128 * 64];
  const int tid = threadIdx.x;
  const int lane = tid & 63, w = tid >> 6;
  const int row0 = blockIdx.x * 128, col0 = blockIdx.y * 128;
  const int wm0 = (w & 1) * 64, wn0 = (w >> 1) * 64;
  const int lr = lane >> 3;
  const int gc = (lane & 7) ^ lr;
  const unsigned short* aP = A + (size_t)(row0 + w * 32 + lr) * K + gc * 8;
  const unsigned short* bP = Bt + (size_t)(col0 + w * 32 + lr) * K + gc * 8;
  unsigned short* asW = As + w * 2048;
  unsigned short* bsW = Bs + w * 2048;
  const int m15 = lane & 15, quad = lane >> 4;
  f32x4 acc[4][4] = {};
  for (int k0 = 0; k0 < K; k0 += 64) {
#pragma unroll
    for (int i = 0; i < 4; i++) {
      __builtin_amdgcn_global_load_lds(
          (const __attribute__((address_space(1))) unsigned int*)(const void*)(aP + (size_t)(i * 8) * K + k0),
          (__attribute__((address_space(3))) unsigned int*)(void*)(asW + i * 512), 16, 0, 0);
      __builtin_amdgcn_global_load_lds(
          (const __attribute__((address_space(1))) unsigned int*)(const void*)(bP + (size_t)(i * 8) * K + k0),
          (__attribute__((address_space(3))) unsigned int*)(void*)(bsW + i * 512), 16, 0, 0);
    }
    __syncthreads();
#pragma unroll
    for (int ks = 0; ks < 2; ks++) {
      short8 aF[4], bF[4];
#pragma unroll
      for (int mi = 0; mi < 4; mi++) {
        int r = wm0 + mi * 16 + m15;
        int g = (ks * 4 + quad) ^ (r & 7);
        aF[mi] = *(const short8*)(As + r * 64 + g * 8);
      }
#pragma unroll
      for (int ni = 0; ni < 4; ni++) {
        int r = wn0 + ni * 16 + m15;
        int g = (ks * 4 + quad) ^ (r & 7);
        bF[ni] = *(const short8*)(Bs + r * 64 + g * 8);
      }
#pragma unroll
      for (int mi = 0; mi < 4; mi++)
#pragma unroll
        for (int ni = 0; ni < 4; ni++)
          acc[mi][ni] = __builtin_amdgcn_mfma_f32_16x16x32_bf16(
              aF[mi], bF[ni], acc[mi][ni], 0, 0, 0);
    }
    __syncthreads();
  }
#pragma unroll
  for (int mi = 0; mi < 4; mi++)
#pragma unroll
    for (int ni = 0; ni < 4; ni++) {
      int col = col0 + wn0 + ni * 16 + m15;
      float bb = bias[col];
#pragma unroll
      for (int r = 0; r < 4; r++) {
        int row = row0 + wm0 + mi * 16 + quad * 4 + r;
        float val = acc[mi][ni][r] + bb;
        if (Cb) Cb[(size_t)row * N + col] = f2bf(val);
        else C[(size_t)row * N + col] = val;
      }
    }
}

// ------------------------------ transV -------------------------------------
// v_b[t][h*64+c] -> vT[bh][c][t]
__global__ __launch_bounds__(256) void transV(
    const unsigned short* __restrict__ v_b, unsigned short* __restrict__ vT) {
  __shared__ unsigned short Tv[64][72];
  const int blk = blockIdx.x;
  const int bh = blk >> 5, tt = blk & 31;
  const int b = bh >> 4, hh = bh & 15;
  const int t0 = tt * 64;
  const int tid = threadIdx.x;
  {
    int t = tid >> 2, cs = tid & 3;
    const unsigned short* p = v_b + ((size_t)(b * LL + t0 + t)) * DD + hh * 64 + cs * 16;
    *(short8*)&Tv[t][cs * 16] = *(const short8*)p;
    *(short8*)&Tv[t][cs * 16 + 8] = *(const short8*)(p + 8);
  }
  __syncthreads();
  {
    int c = tid & 63, ts = tid >> 6;
    unsigned short vals[16];
#pragma unroll
    for (int j = 0; j < 16; j++) vals[j] = Tv[ts * 16 + j][c];
    unsigned short* op = vT + ((size_t)bh * 64 + c) * LL + t0 + ts * 16;
    *(short8*)op = *(short8*)&vals[0];
    *(short8*)(op + 8) = *(short8*)&vals[8];
  }
}

// ------------------------------ phase A ------------------------------------
// KVc_t[bh][ck][c][f] = sum_t Kf[t][f] V[t][c] (bf16); kstc[bh][ck][f].
__global__ __launch_bounds__(256) void phaseA2(
    const unsigned short* __restrict__ klin, const unsigned short* __restrict__ vT,
    unsigned short* __restrict__ KVc_t, unsigned short* __restrict__ kstc) {
  __shared__ unsigned short kT[16][136];   // kT[i][t] = bf16(k[t][i]*SQ)
  const int tid = threadIdx.x, lane = tid & 63, w = tid >> 6;
  const int m15 = lane & 15, quad = lane >> 4;
  const int bh = blockIdx.x >> 4, ck = blockIdx.x & 15;
  const int b = bh >> 4, hh = bh & 15;
  const int t0 = ck * CHUNK;
  {
    int r = tid >> 1, half = tid & 1;
    short8 kv = *(const short8*)(klin + ((size_t)(b * LL + t0 + r)) * 256 + hh * 16 + half * 8);
#pragma unroll
    for (int j = 0; j < 8; j++)
      kT[half * 8 + j][r] = f2bf(bf2f(((unsigned short*)&kv)[j]) * SQ);
  }
  __syncthreads();
  short8 ones8 = {16256, 16256, 16256, 16256, 16256, 16256, 16256, 16256};
  short8 zer8 = {0, 0, 0, 0, 0, 0, 0, 0};
  f32x4 acc[5][5] = {};
  const unsigned short* vbase = vT + (size_t)bh * 64 * LL + t0;
#pragma unroll
  for (int ks = 0; ks < 4; ++ks) {
    const int tt = ks * 32 + quad * 8;
    short8 aF[5], bF[5];
#pragma unroll
    for (int mi = 0; mi < 5; mi++) {
      int r = (w * 5 + mi) * 16 + m15;
      short8 av;
      unsigned short* pv = (unsigned short*)&av;
      if (r == 0) {
        av = ones8;
      } else if (r < 17) {
        short8 k1 = *(const short8*)&kT[r - 1][tt];
#pragma unroll
        for (int j = 0; j < 8; j++) pv[j] = f2bf(bf2f(((unsigned short*)&k1)[j]) * LF);
      } else if (r < DFEAT) {
        int ij = r - 17;
        short8 k1 = *(const short8*)&kT[ij >> 4][tt];
        short8 k2 = *(const short8*)&kT[ij & 15][tt];
#pragma unroll
        for (int j = 0; j < 8; j++)
          pv[j] = f2bf(bf2f(((unsigned short*)&k1)[j]) * bf2f(((unsigned short*)&k2)[j]));
      } else {
        av = zer8;
      }
      aF[mi] = av;
    }
#pragma unroll
    for (int ni = 0; ni < 4; ni++)
      bF[ni] = *(const short8*)(vbase + ((size_t)(ni * 16 + m15)) * LL + tt);
    bF[4] = (m15 == 0) ? ones8 : zer8;
#pragma unroll
    for (int mi = 0; mi < 5; mi++)
#pragma unroll
      for (int ni = 0; ni < 5; ni++)
        acc[mi][ni] = __builtin_amdgcn_mfma_f32_16x16x32_bf16(
            aF[mi], bF[ni], acc[mi][ni], 0, 0, 0);
  }
  const size_t cb = ((size_t)bh * NC + ck) * (64 * 288);
  const size_t kb = ((size_t)bh * NC + ck) * 288;
#pragma unroll
  for (int mi = 0; mi < 5; mi++) {
    int fb = (w * 5 + mi) * 16 + quad * 4;
    if (fb < 288) {
#pragma unroll
      for (int ni = 0; ni < 4; ni++) {
        int c = ni * 16 + m15;
        ushort4 sv;
        sv.x = f2bf(acc[mi][ni][0]); sv.y = f2bf(acc[mi][ni][1]);
        sv.z = f2bf(acc[mi][ni][2]); sv.w = f2bf(acc[mi][ni][3]);
        *(ushort4*)(KVc_t + cb + (size_t)c * 288 + fb) = sv;
      }
      if (m15 == 0) {
        ushort4 sv;
        sv.x = f2bf(acc[mi][4][0]); sv.y = f2bf(acc[mi][4][1]);
        sv.z = f2bf(acc[mi][4][2]); sv.w = f2bf(acc[mi][4][3]);
        *(ushort4*)(kstc + kb + fb) = sv;
      }
    }
  }
}

// ------------------------------ phase B ------------------------------------
// Blocks [0,576): KV scan (thread per (bh,c,f8)); [576,585): kst scan.
__global__ __launch_bounds__(256) void phaseB3(
    const unsigned short* __restrict__ KVc_t, const unsigned short* __restrict__ kstc,
    const float* __restrict__ kv0, const float* __restrict__ kst0,
    unsigned short* __restrict__ KVp_t, unsigned short* __restrict__ kstp,
    float* __restrict__ kv_out, float* __restrict__ kst_out) {
  const int tid = threadIdx.x;
  if (blockIdx.x < 576) {
    int gid = blockIdx.x * 256 + tid;
    int bh = gid / 2304, rem = gid - bh * 2304;
    int c = rem / 36, fg = rem - c * 36;
    int f0 = fg * 8;
    float acc[8];
#pragma unroll
    for (int j = 0; j < 8; j++) {
      int f = f0 + j;
      acc[j] = (f < DFEAT) ? kv0[((size_t)bh * DFEAT + f) * 64 + c] : 0.0f;
    }
    size_t base = ((size_t)bh * NC) * (64 * 288) + (size_t)c * 288 + f0;
    for (int ck = 0; ck < NC; ck++) {
      size_t idx = base + (size_t)ck * (64 * 288);
      short8 t = *(const short8*)(KVc_t + idx);
      unsigned short ov[8];
#pragma unroll
      for (int j = 0; j < 8; j++) {
        ov[j] = f2bf(acc[j]);
        acc[j] += bf2f(((unsigned short*)&t)[j]);
      }
      *(short8*)(KVp_t + idx) = *(short8*)ov;
    }
#pragma unroll
    for (int j = 0; j < 8; j++) {
      int f = f0 + j;
      if (f < DFEAT) kv_out[((size_t)bh * DFEAT + f) * 64 + c] = acc[j];
    }
  } else {
    int idx0 = (blockIdx.x - 576) * 256 + tid;   // 0..2303
    int bh = idx0 / 36, fg = idx0 - bh * 36;
    int f0 = fg * 8;
    float acc[8];
#pragma unroll
    for (int j = 0; j < 8; j++) {
      int f = f0 + j;
      acc[j] = (f < DFEAT) ? kst0[bh * DFEAT + f] : 0.0f;
    }
    for (int ck = 0; ck < NC; ck++) {
      size_t idx = ((size_t)bh * NC + ck) * 288 + f0;
      short8 t = *(const short8*)(kstc + idx);
      unsigned short ov[8];
#pragma unroll
      for (int j = 0; j < 8; j++) {
        ov[j] = f2bf(acc[j]);
        acc[j] += bf2f(((unsigned short*)&t)[j]);
      }
      *(short8*)(kstp + idx) = *(short8*)ov;
    }
#pragma unroll
    for (int j = 0; j < 8; j++) {
      int f = f0 + j;
      if (f < DFEAT) kst_out[bh * DFEAT + f] = acc[j];
    }
  }
}

// ------------------------------ phase C ------------------------------------
// 1 wave / 64 threads per block; 4096 blocks = (bh, ck, qw) with qw = 32-row
// quarter of the 128-row chunk. Barrier-free (S_l strictly wave-private).
__global__ __launch_bounds__(64, 3) void phaseC3(
    const unsigned short* __restrict__ qlin, const unsigned short* __restrict__ klin,
    const unsigned short* __restrict__ vT, const unsigned short* __restrict__ KVp_t,
    const unsigned short* __restrict__ kstp, unsigned short* __restrict__ outs) {
  __shared__ float qs[32][36];              // [0..15]=q*SQ, [16..31]=rot-by-7 dup
  __shared__ unsigned short S_l[32 * 128];  // 8 KB, swizzled intra scores
  const int lane = threadIdx.x;
  const int m15 = lane & 15, quad = lane >> 4;
  const int blk = blockIdx.x;
  const int bh = blk >> 6, ck = (blk >> 2) & 15, qw = blk & 3;
  const int b = bh >> 4, hh = bh & 15;
  const int t0 = ck * CHUNK;
  const int tr0 = qw * 32;
  const unsigned short* qbase = qlin + ((size_t)(b * LL + t0 + tr0)) * 256 + hh * 16;
  const unsigned short* kbase = klin + ((size_t)(b * LL + t0)) * 256 + hh * 16;
  // ---- fill qs (wave-private rows, no barrier) ----
  {
    int r = lane >> 1, h8 = lane & 1;
    short8 qv = *(const short8*)(qbase + (size_t)r * 256 + h8 * 8);
    float qf[8];
#pragma unroll
    for (int j = 0; j < 8; j++) qf[j] = bf2f(((unsigned short*)&qv)[j]) * SQ;
    *(float4*)&qs[r][h8 * 8] = f4(qf[0], qf[1], qf[2], qf[3]);
    *(float4*)&qs[r][h8 * 8 + 4] = f4(qf[4], qf[5], qf[6], qf[7]);
#pragma unroll
    for (int j = 0; j < 8; j++)
      qs[r][16 + ((h8 * 8 + j + 9) & 15)] = qf[j];   // rot[m] = q[(m+7)&15]
  }
  short8 ones8 = {16256, 16256, 16256, 16256, 16256, 16256, 16256, 16256};
  short8 zer8 = {0, 0, 0, 0, 0, 0, 0, 0};
  f32x4 acc[2][5] = {};
  const unsigned short* KVb = KVp_t + ((size_t)(bh * NC + ck)) * (64 * 288);
  const unsigned short* kstb = kstp + ((size_t)(bh * NC + ck)) * 288;
  // ---- pass 1: inter (Qf @ KV'), K = 288 ----
#pragma unroll
  for (int ks = 0; ks < 9; ++ks) {
    const int fs = ks * 32 + quad * 8;
    short8 aF[2], bF[5];
#pragma unroll
    for (int ni = 0; ni < 4; ni++)
      bF[ni] = *(const short8*)(KVb + ((size_t)(ni * 16 + m15)) * 288 + fs);
    bF[4] = (m15 == 0) ? *(const short8*)(kstb + fs) : zer8;
#pragma unroll
    for (int mi = 0; mi < 2; mi++) {
      const float* qr = &qs[mi * 16 + m15][0];
      unsigned short pv[8];
      if (ks == 0) {
        // f = quad*8 + j in [0,32): mix of const-1, linear, i=0 products
        float qr0 = qr[0];
#pragma unroll
        for (int j = 0; j < 8; j++) {
          int f = (quad << 3) + j;
          int fl = f - 1; fl = fl < 0 ? 0 : fl;
          int fm = f - 17; fm = fm < 0 ? 0 : fm;     // < 16 here
          float lin = qr[fl] * LF;
          float prod = qr0 * qr[fm];
          float val = (f == 0) ? 1.0f : ((f < 17) ? lin : prod);
          pv[j] = f2bf(val);
        }
      } else {
        // all products: i = (f-17)>>4, jj = (f-17)&15; jj0 in {7,15}
        int base = fs - 17;                 // >= 15
        int i0 = base >> 4;
        float qi0 = qr[i0];
        float qi1 = qr[i0 + 1];
        const float* qv = qr + 16 + (base & 8);   // aligned 32B window (rot dup)
        float qj[8];
        *(float4*)&qj[0] = *(const float4*)qv;
        *(float4*)&qj[4] = *(const float4*)(qv + 4);
        float qiB = (quad & 1) ? qi0 : qi1;       // jj0==7 -> i const; ==15 -> bump after j=0
#pragma unroll
        for (int j = 0; j < 8; j++) {
          float qi = (j == 0) ? qi0 : qiB;
          float val = qi * qj[j];
          if (ks == 8) val = ((quad << 3) + j < 17) ? val : 0.0f;  // f >= 273 -> 0
          pv[j] = f2bf(val);
        }
      }
      aF[mi] = *(short8*)pv;
    }
#pragma unroll
    for (int mi = 0; mi < 2; mi++)
#pragma unroll
      for (int ni = 0; ni < 5; ni++)
        acc[mi][ni] = __builtin_amdgcn_mfma_f32_16x16x32_bf16(
            aF[mi], bF[ni], acc[mi][ni], 0, 0, 0);
  }
  // ---- intra: u = q@k^T (K=16 pad 32) -> poly/mask -> S_l (wave-private) ----
  const int nsn = 2 * qw + 2;               // s covers [0, (qw+1)*32)
  {
    short8 aU[2], bU[8];
    aU[0] = (quad < 2) ? *(const short8*)(qbase + (size_t)m15 * 256 + quad * 8) : zer8;
    aU[1] = (quad < 2) ? *(const short8*)(qbase + (size_t)(16 + m15) * 256 + quad * 8) : zer8;
#pragma unroll
    for (int sn = 0; sn < 8; sn++) {
      if (sn < nsn) {
        int s = sn * 16 + m15;
        bU[sn] = (quad < 2) ? *(const short8*)(kbase + (size_t)s * 256 + quad * 8) : zer8;
      }
    }
#pragma unroll
    for (int mi = 0; mi < 2; mi++) {
#pragma unroll
      for (int sn = 0; sn < 8; sn++) {
        if (sn < nsn) {
          f32x4 zz = {0.f, 0.f, 0.f, 0.f};
          f32x4 u = __builtin_amdgcn_mfma_f32_16x16x32_bf16(aU[mi], bU[sn], zz, 0, 0, 0);
          int s = sn * 16 + m15;
          int gRow = s >> 3;
#pragma unroll
          for (int rr = 0; rr < 4; rr++) {
            int tl = mi * 16 + quad * 4 + rr;        // local row 0..31
            int tc = tr0 + tl;                       // chunk-local row for mask
            float uu = u[rr];
            float sv = (s <= tc) ? fmaf(uu, fmaf(uu, 0.03125f, 0.25f), 1.0f) : 0.0f;
            int p = gRow ^ (tl & 7);
            S_l[tl * 128 + p * 8 + (s & 7)] = f2bf(sv);
          }
        }
      }
    }
  }
  // ---- pass 2: S @ V' — no barrier (same-wave LDS RAW) ----
  const unsigned short* vbase = vT + (size_t)bh * 64 * LL + t0;
#pragma unroll
  for (int ks = 0; ks < 4; ++ks) {
    if (ks <= qw) {
      const int tt = ks * 32 + quad * 8;
      short8 aF[2], bF[5];
#pragma unroll
      for (int mi = 0; mi < 2; mi++) {
        int tl = mi * 16 + m15;
        int p = (ks * 4 + quad) ^ (tl & 7);
        aF[mi] = *(const short8*)&S_l[tl * 128 + p * 8];
      }
#pragma unroll
      for (int ni = 0; ni < 4; ni++)
        bF[ni] = *(const short8*)(vbase + ((size_t)(ni * 16 + m15)) * LL + tt);
      bF[4] = (m15 == 0) ? ones8 : zer8;
#pragma unroll
      for (int mi = 0; mi < 2; mi++)
#pragma unroll
        for (int ni = 0; ni < 5; ni++)
          acc[mi][ni] = __builtin_amdgcn_mfma_f32_16x16x32_bf16(
              aF[mi], bF[ni], acc[mi][ni], 0, 0, 0);
    }
  }
  // ---- epilogue ----
#pragma unroll
  for (int mi = 0; mi < 2; mi++) {
#pragma unroll
    for (int rr = 0; rr < 4; rr++) {
      float den = __shfl(acc[mi][4][rr], (lane & 48));
      float inv = 1.0f / (den + 1e-6f);
      int tl = mi * 16 + quad * 4 + rr;
      unsigned short* op = outs + ((size_t)(b * LL + t0 + tr0 + tl)) * DD + hh * 64;
#pragma unroll
      for (int ni = 0; ni < 4; ni++)
        op[ni * 16 + m15] = f2bf(acc[mi][ni][rr] * inv);
    }
  }
}

// --------------------------- last-row k2/v2 --------------------------------
__global__ __launch_bounds__(256) void lastrow_qkv(
    const float* __restrict__ x1,
    const float* __restrict__ Wk, const float* __restrict__ bk,
    const float* __restrict__ Wv, const float* __restrict__ bv,
    float* __restrict__ klast, float* __restrict__ vlast) {
  int gid = blockIdx.x * 256 + threadIdx.x;
  int which = gid >> 12;
  int b = (gid >> 10) & 3;
  int n = gid & 1023;
  const float* W = which ? Wv : Wk;
  const float* xr = x1 + ((size_t)(b * LL + LL - 1)) * DD;
  float s = 0.f;
  for (int k = 0; k < 1024; k++) s = fmaf(xr[k], W[(size_t)k * 1024 + n], s);
  s += which ? bv[n] : bk[n];
  (which ? vlast : klast)[b * 1024 + n] = s;
}

// --------------------------- window prep -----------------------------------
// Build bf16 ukb[bh][w][d] and uvT[bh][c][w] from fp32 kbuf/vbufw + klast/vlast.
__global__ __launch_bounds__(256) void prep_window(
    const float* __restrict__ kbuf, const float* __restrict__ vbufw,
    const float* __restrict__ klast, const float* __restrict__ vlast,
    unsigned short* __restrict__ ukb, unsigned short* __restrict__ uvT) {
  __shared__ float Tv[64][68];
  const int bh = blockIdx.x;
  const int b = bh >> 4, hh = bh & 15;
  const int tid = threadIdx.x;
  const int wi = tid >> 2, d0 = (tid & 3) * 16;
  // uk row (shift-by-one window): straight bf16 convert
  {
    const float* kp = (wi < 63) ? (kbuf + ((size_t)hh * 64 + wi + 1) * 64 + d0)
                                : (klast + (size_t)b * 1024 + hh * 64 + d0);
    unsigned short* op = ukb + ((size_t)bh * 64 + wi) * 64 + d0;
#pragma unroll
    for (int j4 = 0; j4 < 4; j4++) {
      float4 v = *(const float4*)(kp + j4 * 4);
      ushort4 r;
      r.x = f2bf(v.x); r.y = f2bf(v.y); r.z = f2bf(v.z); r.w = f2bf(v.w);
      *(ushort4*)(op + j4 * 4) = r;
    }
  }
  // uv: stage fp32 rows, then write transposed bf16
  {
    const float* vp = (wi < 63) ? (vbufw + ((size_t)hh * 64 + wi + 1) * 64 + d0)
                                : (vlast + (size_t)b * 1024 + hh * 64 + d0);
#pragma unroll
    for (int j4 = 0; j4 < 4; j4++)
      *(float4*)&Tv[wi][d0 + j4 * 4] = *(const float4*)(vp + j4 * 4);
  }
  __syncthreads();
  {
    int c = tid & 63, w0 = (tid >> 6) * 16;
    unsigned short* op = uvT + ((size_t)bh * 64 + c) * 64 + w0;
    unsigned short vals[16];
#pragma unroll
    for (int j = 0; j < 16; j++) vals[j] = f2bf(Tv[w0 + j][c]);
    *(short8*)op = *(short8*)&vals[0];
    *(short8*)(op + 8) = *(short8*)&vals[8];
  }
}

// --------------------------- window attention ------------------------------
// MFMA version: 1024 blocks = (bh, tile of 128 q-rows), 4 waves, barrier-free.
// scores = q2b @ ukb^T / 8; softmax over w (64); out = A @ uv.
__global__ __launch_bounds__(256) void window_attn2(
    const unsigned short* __restrict__ q2b, const unsigned short* __restrict__ ukb,
    const unsigned short* __restrict__ uvT, unsigned short* __restrict__ win) {
  __shared__ unsigned short S_l[128 * 64];   // 16 KB, swizzled softmax weights
  const int tid = threadIdx.x, lane = tid & 63, w = tid >> 6;
  const int m15 = lane & 15, quad = lane >> 4;
  const int bh = blockIdx.x >> 4, tile = blockIdx.x & 15;
  const int b = bh >> 4, hh = bh & 15;
  const int t0 = tile * 128 + w * 32;        // this wave's 32 rows (within b)
  const unsigned short* ukbase = ukb + (size_t)bh * 64 * 64;
  const unsigned short* uvbase = uvT + (size_t)bh * 64 * 64;
  // ---- QK^T (K=64) ----
  f32x4 accS[2][4] = {};
#pragma unroll
  for (int ks = 0; ks < 2; ks++) {
    short8 aF[2], bF[4];
#pragma unroll
    for (int mi = 0; mi < 2; mi++)
      aF[mi] = *(const short8*)(q2b + ((size_t)(b * LL + t0 + mi * 16 + m15)) * DD +
                                hh * 64 + ks * 32 + quad * 8);
#pragma unroll
    for (int ni = 0; ni < 4; ni++)
      bF[ni] = *(const short8*)(ukbase + ((size_t)(ni * 16 + m15)) * 64 + ks * 32 + quad * 8);
#pragma unroll
    for (int mi = 0; mi < 2; mi++)
#pragma unroll
      for (int ni = 0; ni < 4; ni++)
        accS[mi][ni] = __builtin_amdgcn_mfma_f32_16x16x32_bf16(
            aF[mi], bF[ni], accS[mi][ni], 0, 0, 0);
  }
  // ---- wave-parallel softmax over w (rows live across 16 lanes x 4 ni) ----
#pragma unroll
  for (int mi = 0; mi < 2; mi++) {
#pragma unroll
    for (int rr = 0; rr < 4; rr++) {
      float s0 = accS[mi][0][rr] * 0.125f;
      float s1 = accS[mi][1][rr] * 0.125f;
      float s2 = accS[mi][2][rr] * 0.125f;
      float s3 = accS[mi][3][rr] * 0.125f;
      float m = fmaxf(fmaxf(s0, s1), fmaxf(s2, s3));
      m = fmaxf(m, __shfl_xor(m, 1));
      m = fmaxf(m, __shfl_xor(m, 2));
      m = fmaxf(m, __shfl_xor(m, 4));
      m = fmaxf(m, __shfl_xor(m, 8));
      float p0 = __expf(s0 - m), p1 = __expf(s1 - m);
      float p2 = __expf(s2 - m), p3 = __expf(s3 - m);
      float l = p0 + p1 + p2 + p3;
      l += __shfl_xor(l, 1);
      l += __shfl_xor(l, 2);
      l += __shfl_xor(l, 4);
      l += __shfl_xor(l, 8);
      float inv = 1.0f / l;
      int tl = w * 32 + mi * 16 + quad * 4 + rr;
      int t7 = tl & 7;
      float pr[4] = {p0 * inv, p1 * inv, p2 * inv, p3 * inv};
#pragma unroll
      for (int ni = 0; ni < 4; ni++) {
        int s = ni * 16 + m15;
        S_l[tl * 64 + ((s >> 3) ^ t7) * 8 + (s & 7)] = f2bf(pr[ni]);
      }
    }
  }
  // ---- PV (K=64) — same-wave LDS RAW, no barrier ----
  f32x4 accO[2][4] = {};
#pragma unroll
  for (int ks = 0; ks < 2; ks++) {
    short8 aF[2], bF[4];
#pragma unroll
    for (int mi = 0; mi < 2; mi++) {
      int tl = w * 32 + mi * 16 + m15;
      int g = (ks * 4 + quad) ^ (tl & 7);
      aF[mi] = *(const short8*)&S_l[tl * 64 + g * 8];
    }
#pragma unroll
    for (int ni = 0; ni < 4; ni++)
      bF[ni] = *(const short8*)(uvbase + ((size_t)(ni * 16 + m15)) * 64 + ks * 32 + quad * 8);
#pragma unroll
    for (int mi = 0; mi < 2; mi++)
#pragma unroll
      for (int ni = 0; ni < 4; ni++)
        accO[mi][ni] = __builtin_amdgcn_mfma_f32_16x16x32_bf16(
            aF[mi], bF[ni], accO[mi][ni], 0, 0, 0);
  }
  // ---- epilogue ----
#pragma unroll
  for (int mi = 0; mi < 2; mi++) {
#pragma unroll
    for (int rr = 0; rr < 4; rr++) {
      int row = t0 + mi * 16 + quad * 4 + rr;
      unsigned short* op = win + ((size_t)(b * LL + row)) * DD + hh * 64;
#pragma unroll
      for (int ni = 0; ni < 4; ni++)
        op[ni * 16 + m15] = f2bf(accO[mi][ni][rr]);
    }
  }
}

// ------------------------------ LayerNorm ----------------------------------
__global__ __launch_bounds__(256) void ln_add(
    const float* __restrict__ A, const float* __restrict__ Bm,
    const float* __restrict__ gamma, const float* __restrict__ beta,
    float* __restrict__ out, unsigned short* __restrict__ outb) {
  const int row = blockIdx.x, tid = threadIdx.x;
  float4 va = ((const float4*)(A + (size_t)row * DD))[tid];
  float4 vb = ((const float4*)(Bm + (size_t)row * DD))[tid];
  float4 s4 = f4(va.x + vb.x, va.y + vb.y, va.z + vb.z, va.w + vb.w);
  float s = s4.x + s4.y + s4.z + s4.w;
  float ss = s4.x * s4.x + s4.y * s4.y + s4.z * s4.z + s4.w * s4.w;
  for (int o = 32; o; o >>= 1) { s += __shfl_xor(s, o); ss += __shfl_xor(ss, o); }
  __shared__ float red[8];
  int wid = tid >> 6;
  if ((tid & 63) == 0) { red[wid * 2] = s; red[wid * 2 + 1] = ss; }
  __syncthreads();
  float tot = red[0] + red[2] + red[4] + red[6];
  float tots = red[1] + red[3] + red[5] + red[7];
  float mu = tot * (1.0f / 1024.0f);
  float var = tots * (1.0f / 1024.0f) - mu * mu;
  float rstd = rsqrtf(var + 1e-5f);
  float4 g = ((const float4*)gamma)[tid];
  float4 be = ((const float4*)beta)[tid];
  float4 o = f4((s4.x - mu) * rstd * g.x + be.x, (s4.y - mu) * rstd * g.y + be.y,
                (s4.z - mu) * rstd * g.z + be.z, (s4.w - mu) * rstd * g.w + be.w);
  ((float4*)(out + (size_t)row * DD))[tid] = o;
  if (outb) {
    ushort4 r;
    r.x = f2bf(o.x); r.y = f2bf(o.y); r.z = f2bf(o.z); r.w = f2bf(o.w);
    ((ushort4*)(outb + (size_t)row * DD))[tid] = r;
  }
}

// ------------------------------ launch -------------------------------------
extern "C" void kernel_launch(void* const* d_in, const int* in_sizes, int n_in,
                              void* d_out, int out_size, void* d_ws, size_t ws_size,
                              hipStream_t stream) {
  (void)in_sizes; (void)n_in; (void)out_size; (void)ws_size;
  const float* x      = (const float*)d_in[0];
  const float* kv0    = (const float*)d_in[1];
  const float* kst0   = (const float*)d_in[2];
  const float* kbuf   = (const float*)d_in[3];
  const float* vbufw  = (const float*)d_in[4];
  const float* Wq_lin = (const float*)d_in[5];
  const float* bq_lin = (const float*)d_in[6];
  const float* Wk_lin = (const float*)d_in[7];
  const float* bk_lin = (const float*)d_in[8];
  const float* Wv_lin = (const float*)d_in[9];
  const float* bv_lin = (const float*)d_in[10];
  const float* Wo_lin = (const float*)d_in[11];
  const float* bo_lin = (const float*)d_in[12];
  const float* Wq     = (const float*)d_in[13];
  const float* bq     = (const float*)d_in[14];
  const float* Wk     = (const float*)d_in[15];
  const float* bk     = (const float*)d_in[16];
  const float* Wv     = (const float*)d_in[17];
  const float* bv     = (const float*)d_in[18];
  const float* Wo     = (const float*)d_in[19];
  const float* bo     = (const float*)d_in[20];
  const float* gamma  = (const float*)d_in[21];
  const float* beta   = (const float*)d_in[22];

  float* out = (float*)d_out;
  float* kv_out  = out + 8388608;
  float* kst_out = out + 8388608 + 1118208;

  float* ws = (float*)d_ws;
  const size_t MF = 1024 * 1024;
  // float-offset layout (lifetimes in comments)
  unsigned short* qlin_b = (unsigned short*)(ws);              // [0,1)  until phaseC
  unsigned short* klin_b = (unsigned short*)(ws + 1 * MF);     // [1,2)  until phaseC
  unsigned short* v_b    = (unsigned short*)(ws + 2 * MF);     // [2,6)  until transV
  unsigned short* vT     = (unsigned short*)(ws + 6 * MF);     // [6,10) until phaseC
  unsigned short* KVc_t  = (unsigned short*)(ws + 10 * MF);    // [10,19) A->B
  unsigned short* kstc   = (unsigned short*)(ws + 19 * MF);    // [19,19.15) A->B
  unsigned short* KVp_t  = (unsigned short*)(ws + 20 * MF);    // [20,29) B->C
  unsigned short* kstp   = (unsigned short*)(ws + 29 * MF);    // [29,29.15) B->C
  unsigned short* x_bf   = (unsigned short*)(ws + 30 * MF);    // [30,34) until v GEMM
  unsigned short* outs_bf = (unsigned short*)(ws + 2 * MF);    // [2,6)  C->O1 (v_b dead)
  float* tmp  = ws + 10 * MF;                                  // [10,18) O1->ln (KVc_t dead)
  float* x1   = ws + 20 * MF;                                  // [20,28) (KVp_t dead)
  unsigned short* x1b = (unsigned short*)(ws + 30 * MF);       // [30,32) (x_bf dead)
  unsigned short* q2b = (unsigned short*)ws;                   // [0,4)  (qlin/klin/outs/vT dead)
  unsigned short* winb = (unsigned short*)(ws + 8 * MF);       // [8,12) (tmp dead)
  float* tmp2 = ws + 12 * MF;                                  // [12,20)
  float* klast = ws + 34 * MF;                                 // 4096 floats
  float* vlast = klast + 4096;                                 // 4096 floats
  unsigned short* ukb = (unsigned short*)(ws + 34 * MF + 8192);      // 64*64*64 bf16
  unsigned short* uvTw = ukb + 262144;                               // 64*64*64 bf16
  unsigned short* WtQL = (unsigned short*)(ws + 35 * MF);
  unsigned short* WtKL = WtQL + 262144;
  unsigned short* WtVL = WtQL + 524288;
  unsigned short* WtO1 = WtQL + 1572864;
  unsigned short* WtQ2 = WtQL + 2621440;
  unsigned short* WtO2 = WtQL + 3670016;

  dim3 blk(256);
  cast_bf16<<<8192, blk, 0, stream>>>(x, x_bf, 2097152);
  castT<<<dim3(16, 4), blk, 0, stream>>>(Wq_lin, WtQL, 1024, 256);
  castT<<<dim3(16, 4), blk, 0, stream>>>(Wk_lin, WtKL, 1024, 256);
  castT<<<dim3(16, 16), blk, 0, stream>>>(Wv_lin, WtVL, 1024, 1024);
  castT<<<dim3(16, 16), blk, 0, stream>>>(Wo_lin, WtO1, 1024, 1024);
  castT<<<dim3(16, 16), blk, 0, stream>>>(Wq, WtQ2, 1024, 1024);
  castT<<<dim3(16, 16), blk, 0, stream>>>(Wo, WtO2, 1024, 1024);
  gemm_mfma<<<dim3(64, 2), blk, 0, stream>>>(x_bf, WtQL, bq_lin, (float*)0, qlin_b, 8192, 256, 1024);
  gemm_mfma<<<dim3(64, 2), blk, 0, stream>>>(x_bf, WtKL, bk_lin, (float*)0, klin_b, 8192, 256, 1024);
  gemm_mfma<<<dim3(64, 8), blk, 0, stream>>>(x_bf, WtVL, bv_lin, (float*)0, v_b, 8192, 1024, 1024);
  transV<<<2048, blk, 0, stream>>>(v_b, vT);
  phaseA2<<<1024, blk, 0, stream>>>(klin_b, vT, KVc_t, kstc);
  phaseB3<<<585, blk, 0, stream>>>(KVc_t, kstc, kv0, kst0, KVp_t, kstp, kv_out, kst_out);
  phaseC3<<<4096, dim3(64), 0, stream>>>(qlin_b, klin_b, vT, KVp_t, kstp, outs_bf);
  gemm_mfma<<<dim3(64, 8), blk, 0, stream>>>(outs_bf, WtO1, bo_lin, tmp, (unsigned short*)0, 8192, 1024, 1024);
  ln_add<<<8192, blk, 0, stream>>>(x, tmp, gamma, beta, x1, x1b);
  gemm_mfma<<<dim3(64, 8), blk, 0, stream>>>(x1b, WtQ2, bq, (float*)0, q2b, 8192, 1024, 1024);
  lastrow_qkv<<<32, blk, 0, stream>>>(x1, Wk, bk, Wv, bv, klast, vlast);
  prep_window<<<64, blk, 0, stream>>>(kbuf, vbufw, klast, vlast, ukb, uvTw);
  window_attn2<<<1024, blk, 0, stream>>>(q2b, ukb, uvTw, winb);
  gemm_mfma<<<dim3(64, 8), blk, 0, stream>>>(winb, WtO2, bo, tmp2, (unsigned short*)0, 8192, 1024, 1024);
  ln_add<<<8192, blk, 0, stream>>>(x1, tmp2, gamma, beta, out, (unsigned short*)0);
}

// Round 3
// 479.739 us; speedup vs baseline: 1.0849x; 1.0304x over previous
//
#include <hip/hip_runtime.h>
#include <math.h>

// ---------------------------------------------------------------------------
// BasedBlock: B=4 L=2048 d=1024 h=16 f=16 hd=64 w=64, D=1+f+f*f=273
// Round 8: phaseC4 — recombine the 4 causal quarters of a (bh,ck) chunk into
// one 256-thread block (wave w = quarter qw), still fully barrier-free with
// wave-private qs/S_l. The 4 waves share the CU, so the 36.6KB KV' chunk is
// fetched from HBM once per block instead of 4x (phaseC3 over-fetch: 144MB).
// ---------------------------------------------------------------------------

#define LL 2048
#define DD 1024
#define DFEAT 273
#define NC 16
#define CHUNK 128

typedef __attribute__((ext_vector_type(8))) short short8;
typedef __attribute__((ext_vector_type(4))) float f32x4;

#define SQ 0.42044820762685725f   // sqrt(1/(sqrt(2)*sqrt(16))) = sqrt(0.176776...)
#define LF 1.18920711500272107f   // 0.5 / SQ

__device__ __forceinline__ float4 f4(float a, float b, float c, float d) {
  float4 r; r.x = a; r.y = b; r.z = c; r.w = d; return r;
}

__device__ __forceinline__ unsigned short f2bf(float f) {
  union { float f; unsigned u; } v; v.f = f;
  unsigned r = v.u + 0x7fffu + ((v.u >> 16) & 1u);
  return (unsigned short)(r >> 16);
}

__device__ __forceinline__ float bf2f(unsigned short u) {
  union { unsigned u; float f; } v; v.u = ((unsigned)u) << 16; return v.f;
}

// --------------------------- cast kernels ----------------------------------
__global__ __launch_bounds__(256) void cast_bf16(
    const float* __restrict__ in, unsigned short* __restrict__ o, int n4) {
  int i = blockIdx.x * 256 + threadIdx.x;
  if (i < n4) {
    float4 v = ((const float4*)in)[i];
    ushort4 r;
    r.x = f2bf(v.x); r.y = f2bf(v.y); r.z = f2bf(v.z); r.w = f2bf(v.w);
    ((ushort4*)o)[i] = r;
  }
}

// W[K][N] fp32 -> Wt[N][K] bf16
__global__ __launch_bounds__(256) void castT(
    const float* __restrict__ W, unsigned short* __restrict__ Wt, int K, int N) {
  __shared__ float t[64][65];
  int k0 = blockIdx.x * 64, n0 = blockIdx.y * 64;
  int tid = threadIdx.x;
#pragma unroll
  for (int p = 0; p < 16; p++) {
    int idx = p * 256 + tid;
    int r = idx >> 6, c = idx & 63;
    t[r][c] = W[(size_t)(k0 + r) * N + n0 + c];
  }
  __syncthreads();
#pragma unroll
  for (int p = 0; p < 16; p++) {
    int idx = p * 256 + tid;
    int rn = idx >> 6, ck = idx & 63;
    Wt[(size_t)(n0 + rn) * K + k0 + ck] = f2bf(t[ck][rn]);
  }
}

// --------------------------- MFMA GEMM -------------------------------------
__global__ __launch_bounds__(256) void gemm_mfma(
    const unsigned short* __restrict__ A, const unsigned short* __restrict__ Bt,
    const float* __restrict__ bias, float* __restrict__ C,
    unsigned short* __restrict__ Cb, int M, int N, int K) {
  __shared__ unsigned short As[128 * 64];
  __shared__ unsigned short Bs[128 * 64];
  const int tid = threadIdx.x;
  const int lane = tid & 63, w = tid >> 6;
  const int row0 = blockIdx.x * 128, col0 = blockIdx.y * 128;
  const int wm0 = (w & 1) * 64, wn0 = (w >> 1) * 64;
  const int lr = lane >> 3;
  const int gc = (lane & 7) ^ lr;
  const unsigned short* aP = A + (size_t)(row0 + w * 32 + lr) * K + gc * 8;
  const unsigned short* bP = Bt + (size_t)(col0 + w * 32 + lr) * K + gc * 8;
  unsigned short* asW = As + w * 2048;
  unsigned short* bsW = Bs + w * 2048;
  const int m15 = lane & 15, quad = lane >> 4;
  f32x4 acc[4][4] = {};
  for (int k0 = 0; k0 < K; k0 += 64) {
#pragma unroll
    for (int i = 0; i < 4; i++) {
      __builtin_amdgcn_global_load_lds(
          (const __attribute__((address_space(1))) unsigned int*)(const void*)(aP + (size_t)(i * 8) * K + k0),
          (__attribute__((address_space(3))) unsigned int*)(void*)(asW + i * 512), 16, 0, 0);
      __builtin_amdgcn_global_load_lds(
          (const __attribute__((address_space(1))) unsigned int*)(const void*)(bP + (size_t)(i * 8) * K + k0),
          (__attribute__((address_space(3))) unsigned int*)(void*)(bsW + i * 512), 16, 0, 0);
    }
    __syncthreads();
#pragma unroll
    for (int ks = 0; ks < 2; ks++) {
      short8 aF[4], bF[4];
#pragma unroll
      for (int mi = 0; mi < 4; mi++) {
        int r = wm0 + mi * 16 + m15;
        int g = (ks * 4 + quad) ^ (r & 7);
        aF[mi] = *(const short8*)(As + r * 64 + g * 8);
      }
#pragma unroll
      for (int ni = 0; ni < 4; ni++) {
        int r = wn0 + ni * 16 + m15;
        int g = (ks * 4 + quad) ^ (r & 7);
        bF[ni] = *(const short8*)(Bs + r * 64 + g * 8);
      }
#pragma unroll
      for (int mi = 0; mi < 4; mi++)
#pragma unroll
        for (int ni = 0; ni < 4; ni++)
          acc[mi][ni] = __builtin_amdgcn_mfma_f32_16x16x32_bf16(
              aF[mi], bF[ni], acc[mi][ni], 0, 0, 0);
    }
    __syncthreads();
  }
#pragma unroll
  for (int mi = 0; mi < 4; mi++)
#pragma unroll
    for (int ni = 0; ni < 4; ni++) {
      int col = col0 + wn0 + ni * 16 + m15;
      float bb = bias[col];
#pragma unroll
      for (int r = 0; r < 4; r++) {
        int row = row0 + wm0 + mi * 16 + quad * 4 + r;
        float val = acc[mi][ni][r] + bb;
        if (Cb) Cb[(size_t)row * N + col] = f2bf(val);
        else C[(size_t)row * N + col] = val;
      }
    }
}

// ------------------------------ transV -------------------------------------
// v_b[t][h*64+c] -> vT[bh][c][t]
__global__ __launch_bounds__(256) void transV(
    const unsigned short* __restrict__ v_b, unsigned short* __restrict__ vT) {
  __shared__ unsigned short Tv[64][72];
  const int blk = blockIdx.x;
  const int bh = blk >> 5, tt = blk & 31;
  const int b = bh >> 4, hh = bh & 15;
  const int t0 = tt * 64;
  const int tid = threadIdx.x;
  {
    int t = tid >> 2, cs = tid & 3;
    const unsigned short* p = v_b + ((size_t)(b * LL + t0 + t)) * DD + hh * 64 + cs * 16;
    *(short8*)&Tv[t][cs * 16] = *(const short8*)p;
    *(short8*)&Tv[t][cs * 16 + 8] = *(const short8*)(p + 8);
  }
  __syncthreads();
  {
    int c = tid & 63, ts = tid >> 6;
    unsigned short vals[16];
#pragma unroll
    for (int j = 0; j < 16; j++) vals[j] = Tv[ts * 16 + j][c];
    unsigned short* op = vT + ((size_t)bh * 64 + c) * LL + t0 + ts * 16;
    *(short8*)op = *(short8*)&vals[0];
    *(short8*)(op + 8) = *(short8*)&vals[8];
  }
}

// ------------------------------ phase A ------------------------------------
// KVc_t[bh][ck][c][f] = sum_t Kf[t][f] V[t][c] (bf16); kstc[bh][ck][f].
__global__ __launch_bounds__(256) void phaseA2(
    const unsigned short* __restrict__ klin, const unsigned short* __restrict__ vT,
    unsigned short* __restrict__ KVc_t, unsigned short* __restrict__ kstc) {
  __shared__ unsigned short kT[16][136];   // kT[i][t] = bf16(k[t][i]*SQ)
  const int tid = threadIdx.x, lane = tid & 63, w = tid >> 6;
  const int m15 = lane & 15, quad = lane >> 4;
  const int bh = blockIdx.x >> 4, ck = blockIdx.x & 15;
  const int b = bh >> 4, hh = bh & 15;
  const int t0 = ck * CHUNK;
  {
    int r = tid >> 1, half = tid & 1;
    short8 kv = *(const short8*)(klin + ((size_t)(b * LL + t0 + r)) * 256 + hh * 16 + half * 8);
#pragma unroll
    for (int j = 0; j < 8; j++)
      kT[half * 8 + j][r] = f2bf(bf2f(((unsigned short*)&kv)[j]) * SQ);
  }
  __syncthreads();
  short8 ones8 = {16256, 16256, 16256, 16256, 16256, 16256, 16256, 16256};
  short8 zer8 = {0, 0, 0, 0, 0, 0, 0, 0};
  f32x4 acc[5][5] = {};
  const unsigned short* vbase = vT + (size_t)bh * 64 * LL + t0;
#pragma unroll
  for (int ks = 0; ks < 4; ++ks) {
    const int tt = ks * 32 + quad * 8;
    short8 aF[5], bF[5];
#pragma unroll
    for (int mi = 0; mi < 5; mi++) {
      int r = (w * 5 + mi) * 16 + m15;
      short8 av;
      unsigned short* pv = (unsigned short*)&av;
      if (r == 0) {
        av = ones8;
      } else if (r < 17) {
        short8 k1 = *(const short8*)&kT[r - 1][tt];
#pragma unroll
        for (int j = 0; j < 8; j++) pv[j] = f2bf(bf2f(((unsigned short*)&k1)[j]) * LF);
      } else if (r < DFEAT) {
        int ij = r - 17;
        short8 k1 = *(const short8*)&kT[ij >> 4][tt];
        short8 k2 = *(const short8*)&kT[ij & 15][tt];
#pragma unroll
        for (int j = 0; j < 8; j++)
          pv[j] = f2bf(bf2f(((unsigned short*)&k1)[j]) * bf2f(((unsigned short*)&k2)[j]));
      } else {
        av = zer8;
      }
      aF[mi] = av;
    }
#pragma unroll
    for (int ni = 0; ni < 4; ni++)
      bF[ni] = *(const short8*)(vbase + ((size_t)(ni * 16 + m15)) * LL + tt);
    bF[4] = (m15 == 0) ? ones8 : zer8;
#pragma unroll
    for (int mi = 0; mi < 5; mi++)
#pragma unroll
      for (int ni = 0; ni < 5; ni++)
        acc[mi][ni] = __builtin_amdgcn_mfma_f32_16x16x32_bf16(
            aF[mi], bF[ni], acc[mi][ni], 0, 0, 0);
  }
  const size_t cb = ((size_t)bh * NC + ck) * (64 * 288);
  const size_t kb = ((size_t)bh * NC + ck) * 288;
#pragma unroll
  for (int mi = 0; mi < 5; mi++) {
    int fb = (w * 5 + mi) * 16 + quad * 4;
    if (fb < 288) {
#pragma unroll
      for (int ni = 0; ni < 4; ni++) {
        int c = ni * 16 + m15;
        ushort4 sv;
        sv.x = f2bf(acc[mi][ni][0]); sv.y = f2bf(acc[mi][ni][1]);
        sv.z = f2bf(acc[mi][ni][2]); sv.w = f2bf(acc[mi][ni][3]);
        *(ushort4*)(KVc_t + cb + (size_t)c * 288 + fb) = sv;
      }
      if (m15 == 0) {
        ushort4 sv;
        sv.x = f2bf(acc[mi][4][0]); sv.y = f2bf(acc[mi][4][1]);
        sv.z = f2bf(acc[mi][4][2]); sv.w = f2bf(acc[mi][4][3]);
        *(ushort4*)(kstc + kb + fb) = sv;
      }
    }
  }
}

// ------------------------------ phase B ------------------------------------
// Blocks [0,576): KV scan (thread per (bh,c,f8)); [576,585): kst scan.
__global__ __launch_bounds__(256) void phaseB3(
    const unsigned short* __restrict__ KVc_t, const unsigned short* __restrict__ kstc,
    const float* __restrict__ kv0, const float* __restrict__ kst0,
    unsigned short* __restrict__ KVp_t, unsigned short* __restrict__ kstp,
    float* __restrict__ kv_out, float* __restrict__ kst_out) {
  const int tid = threadIdx.x;
  if (blockIdx.x < 576) {
    int gid = blockIdx.x * 256 + tid;
    int bh = gid / 2304, rem = gid - bh * 2304;
    int c = rem / 36, fg = rem - c * 36;
    int f0 = fg * 8;
    float acc[8];
#pragma unroll
    for (int j = 0; j < 8; j++) {
      int f = f0 + j;
      acc[j] = (f < DFEAT) ? kv0[((size_t)bh * DFEAT + f) * 64 + c] : 0.0f;
    }
    size_t base = ((size_t)bh * NC) * (64 * 288) + (size_t)c * 288 + f0;
    for (int ck = 0; ck < NC; ck++) {
      size_t idx = base + (size_t)ck * (64 * 288);
      short8 t = *(const short8*)(KVc_t + idx);
      unsigned short ov[8];
#pragma unroll
      for (int j = 0; j < 8; j++) {
        ov[j] = f2bf(acc[j]);
        acc[j] += bf2f(((unsigned short*)&t)[j]);
      }
      *(short8*)(KVp_t + idx) = *(short8*)ov;
    }
#pragma unroll
    for (int j = 0; j < 8; j++) {
      int f = f0 + j;
      if (f < DFEAT) kv_out[((size_t)bh * DFEAT + f) * 64 + c] = acc[j];
    }
  } else {
    int idx0 = (blockIdx.x - 576) * 256 + tid;   // 0..2303
    int bh = idx0 / 36, fg = idx0 - bh * 36;
    int f0 = fg * 8;
    float acc[8];
#pragma unroll
    for (int j = 0; j < 8; j++) {
      int f = f0 + j;
      acc[j] = (f < DFEAT) ? kst0[bh * DFEAT + f] : 0.0f;
    }
    for (int ck = 0; ck < NC; ck++) {
      size_t idx = ((size_t)bh * NC + ck) * 288 + f0;
      short8 t = *(const short8*)(kstc + idx);
      unsigned short ov[8];
#pragma unroll
      for (int j = 0; j < 8; j++) {
        ov[j] = f2bf(acc[j]);
        acc[j] += bf2f(((unsigned short*)&t)[j]);
      }
      *(short8*)(kstp + idx) = *(short8*)ov;
    }
#pragma unroll
    for (int j = 0; j < 8; j++) {
      int f = f0 + j;
      if (f < DFEAT) kst_out[bh * DFEAT + f] = acc[j];
    }
  }
}

// ------------------------------ phase C ------------------------------------
// 256-thread blocks, grid 1024 = (bh, ck); wave w = causal quarter qw.
// Fully barrier-free: qs / S_l are wave-private slices. The 4 waves read the
// same KV'/kst fragments on the same CU -> one HBM fetch per chunk.
__global__ __launch_bounds__(256) void phaseC4(
    const unsigned short* __restrict__ qlin, const unsigned short* __restrict__ klin,
    const unsigned short* __restrict__ vT, const unsigned short* __restrict__ KVp_t,
    const unsigned short* __restrict__ kstp, unsigned short* __restrict__ outs) {
  __shared__ float qs[4][32][36];              // per-wave: [0..15]=q*SQ, [16..31]=rot dup
  __shared__ unsigned short S_l[4][32 * 128];  // per-wave swizzled intra scores
  const int tid = threadIdx.x, lane = tid & 63, w = tid >> 6;
  const int m15 = lane & 15, quad = lane >> 4;
  const int bh = blockIdx.x >> 4, ck = blockIdx.x & 15;
  const int qw = w;
  const int b = bh >> 4, hh = bh & 15;
  const int t0 = ck * CHUNK;
  const int tr0 = qw * 32;
  float (*qsw)[36] = qs[w];
  unsigned short* Sw = S_l[w];
  const unsigned short* qbase = qlin + ((size_t)(b * LL + t0 + tr0)) * 256 + hh * 16;
  const unsigned short* kbase = klin + ((size_t)(b * LL + t0)) * 256 + hh * 16;
  // ---- fill qs (wave-private rows, no barrier) ----
  {
    int r = lane >> 1, h8 = lane & 1;
    short8 qv = *(const short8*)(qbase + (size_t)r * 256 + h8 * 8);
    float qf[8];
#pragma unroll
    for (int j = 0; j < 8; j++) qf[j] = bf2f(((unsigned short*)&qv)[j]) * SQ;
    *(float4*)&qsw[r][h8 * 8] = f4(qf[0], qf[1], qf[2], qf[3]);
    *(float4*)&qsw[r][h8 * 8 + 4] = f4(qf[4], qf[5], qf[6], qf[7]);
#pragma unroll
    for (int j = 0; j < 8; j++)
      qsw[r][16 + ((h8 * 8 + j + 9) & 15)] = qf[j];   // rot[m] = q[(m+7)&15]
  }
  short8 ones8 = {16256, 16256, 16256, 16256, 16256, 16256, 16256, 16256};
  short8 zer8 = {0, 0, 0, 0, 0, 0, 0, 0};
  f32x4 acc[2][5] = {};
  const unsigned short* KVb = KVp_t + ((size_t)(bh * NC + ck)) * (64 * 288);
  const unsigned short* kstb = kstp + ((size_t)(bh * NC + ck)) * 288;
  // ---- pass 1: inter (Qf @ KV'), K = 288 ----
#pragma unroll
  for (int ks = 0; ks < 9; ++ks) {
    const int fs = ks * 32 + quad * 8;
    short8 aF[2], bF[5];
#pragma unroll
    for (int ni = 0; ni < 4; ni++)
      bF[ni] = *(const short8*)(KVb + ((size_t)(ni * 16 + m15)) * 288 + fs);
    bF[4] = (m15 == 0) ? *(const short8*)(kstb + fs) : zer8;
#pragma unroll
    for (int mi = 0; mi < 2; mi++) {
      const float* qr = &qsw[mi * 16 + m15][0];
      unsigned short pv[8];
      if (ks == 0) {
        // f = quad*8 + j in [0,32): mix of const-1, linear, i=0 products
        float qr0 = qr[0];
#pragma unroll
        for (int j = 0; j < 8; j++) {
          int f = (quad << 3) + j;
          int fl = f - 1; fl = fl < 0 ? 0 : fl;
          int fm = f - 17; fm = fm < 0 ? 0 : fm;     // < 16 here
          float lin = qr[fl] * LF;
          float prod = qr0 * qr[fm];
          float val = (f == 0) ? 1.0f : ((f < 17) ? lin : prod);
          pv[j] = f2bf(val);
        }
      } else {
        // all products: i = (f-17)>>4, jj = (f-17)&15; jj0 in {7,15}
        int base = fs - 17;                 // >= 15
        int i0 = base >> 4;
        float qi0 = qr[i0];
        float qi1 = qr[i0 + 1];
        const float* qv = qr + 16 + (base & 8);   // aligned 32B window (rot dup)
        float qj[8];
        *(float4*)&qj[0] = *(const float4*)qv;
        *(float4*)&qj[4] = *(const float4*)(qv + 4);
        float qiB = (quad & 1) ? qi0 : qi1;       // jj0==7 -> i const; ==15 -> bump after j=0
#pragma unroll
        for (int j = 0; j < 8; j++) {
          float qi = (j == 0) ? qi0 : qiB;
          float val = qi * qj[j];
          if (ks == 8) val = ((quad << 3) + j < 17) ? val : 0.0f;  // f >= 273 -> 0
          pv[j] = f2bf(val);
        }
      }
      aF[mi] = *(short8*)pv;
    }
#pragma unroll
    for (int mi = 0; mi < 2; mi++)
#pragma unroll
      for (int ni = 0; ni < 5; ni++)
        acc[mi][ni] = __builtin_amdgcn_mfma_f32_16x16x32_bf16(
            aF[mi], bF[ni], acc[mi][ni], 0, 0, 0);
  }
  // ---- intra: u = q@k^T (K=16 pad 32) -> poly/mask -> S_l (wave-private) ----
  const int nsn = 2 * qw + 2;               // s covers [0, (qw+1)*32)
  {
    short8 aU[2], bU[8];
    aU[0] = (quad < 2) ? *(const short8*)(qbase + (size_t)m15 * 256 + quad * 8) : zer8;
    aU[1] = (quad < 2) ? *(const short8*)(qbase + (size_t)(16 + m15) * 256 + quad * 8) : zer8;
#pragma unroll
    for (int sn = 0; sn < 8; sn++) {
      if (sn < nsn) {
        int s = sn * 16 + m15;
        bU[sn] = (quad < 2) ? *(const short8*)(kbase + (size_t)s * 256 + quad * 8) : zer8;
      }
    }
#pragma unroll
    for (int mi = 0; mi < 2; mi++) {
#pragma unroll
      for (int sn = 0; sn < 8; sn++) {
        if (sn < nsn) {
          f32x4 zz = {0.f, 0.f, 0.f, 0.f};
          f32x4 u = __builtin_amdgcn_mfma_f32_16x16x32_bf16(aU[mi], bU[sn], zz, 0, 0, 0);
          int s = sn * 16 + m15;
          int gRow = s >> 3;
#pragma unroll
          for (int rr = 0; rr < 4; rr++) {
            int tl = mi * 16 + quad * 4 + rr;        // local row 0..31
            int tc = tr0 + tl;                       // chunk-local row for mask
            float uu = u[rr];
            float sv = (s <= tc) ? fmaf(uu, fmaf(uu, 0.03125f, 0.25f), 1.0f) : 0.0f;
            int p = gRow ^ (tl & 7);
            Sw[tl * 128 + p * 8 + (s & 7)] = f2bf(sv);
          }
        }
      }
    }
  }
  // ---- pass 2: S @ V' — no barrier (same-wave LDS RAW) ----
  const unsigned short* vbase = vT + (size_t)bh * 64 * LL + t0;
#pragma unroll
  for (int ks = 0; ks < 4; ++ks) {
    if (ks <= qw) {
      const int tt = ks * 32 + quad * 8;
      short8 aF[2], bF[5];
#pragma unroll
      for (int mi = 0; mi < 2; mi++) {
        int tl = mi * 16 + m15;
        int p = (ks * 4 + quad) ^ (tl & 7);
        aF[mi] = *(const short8*)&Sw[tl * 128 + p * 8];
      }
#pragma unroll
      for (int ni = 0; ni < 4; ni++)
        bF[ni] = *(const short8*)(vbase + ((size_t)(ni * 16 + m15)) * LL + tt);
      bF[4] = (m15 == 0) ? ones8 : zer8;
#pragma unroll
      for (int mi = 0; mi < 2; mi++)
#pragma unroll
        for (int ni = 0; ni < 5; ni++)
          acc[mi][ni] = __builtin_amdgcn_mfma_f32_16x16x32_bf16(
              aF[mi], bF[ni], acc[mi][ni], 0, 0, 0);
    }
  }
  // ---- epilogue ----
#pragma unroll
  for (int mi = 0; mi < 2; mi++) {
#pragma unroll
    for (int rr = 0; rr < 4; rr++) {
      float den = __shfl(acc[mi][4][rr], (lane & 48));
      float inv = 1.0f / (den + 1e-6f);
      int tl = mi * 16 + quad * 4 + rr;
      unsigned short* op = outs + ((size_t)(b * LL + t0 + tr0 + tl)) * DD + hh * 64;
#pragma unroll
      for (int ni = 0; ni < 4; ni++)
        op[ni * 16 + m15] = f2bf(acc[mi][ni][rr] * inv);
    }
  }
}

// --------------------------- last-row k2/v2 --------------------------------
__global__ __launch_bounds__(256) void lastrow_qkv(
    const float* __restrict__ x1,
    const float* __restrict__ Wk, const float* __restrict__ bk,
    const float* __restrict__ Wv, const float* __restrict__ bv,
    float* __restrict__ klast, float* __restrict__ vlast) {
  int gid = blockIdx.x * 256 + threadIdx.x;
  int which = gid >> 12;
  int b = (gid >> 10) & 3;
  int n = gid & 1023;
  const float* W = which ? Wv : Wk;
  const float* xr = x1 + ((size_t)(b * LL + LL - 1)) * DD;
  float s = 0.f;
  for (int k = 0; k < 1024; k++) s = fmaf(xr[k], W[(size_t)k * 1024 + n], s);
  s += which ? bv[n] : bk[n];
  (which ? vlast : klast)[b * 1024 + n] = s;
}

// --------------------------- window prep -----------------------------------
// Build bf16 ukb[bh][w][d] and uvT[bh][c][w] from fp32 kbuf/vbufw + klast/vlast.
__global__ __launch_bounds__(256) void prep_window(
    const float* __restrict__ kbuf, const float* __restrict__ vbufw,
    const float* __restrict__ klast, const float* __restrict__ vlast,
    unsigned short* __restrict__ ukb, unsigned short* __restrict__ uvT) {
  __shared__ float Tv[64][68];
  const int bh = blockIdx.x;
  const int b = bh >> 4, hh = bh & 15;
  const int tid = threadIdx.x;
  const int wi = tid >> 2, d0 = (tid & 3) * 16;
  // uk row (shift-by-one window): straight bf16 convert
  {
    const float* kp = (wi < 63) ? (kbuf + ((size_t)hh * 64 + wi + 1) * 64 + d0)
                                : (klast + (size_t)b * 1024 + hh * 64 + d0);
    unsigned short* op = ukb + ((size_t)bh * 64 + wi) * 64 + d0;
#pragma unroll
    for (int j4 = 0; j4 < 4; j4++) {
      float4 v = *(const float4*)(kp + j4 * 4);
      ushort4 r;
      r.x = f2bf(v.x); r.y = f2bf(v.y); r.z = f2bf(v.z); r.w = f2bf(v.w);
      *(ushort4*)(op + j4 * 4) = r;
    }
  }
  // uv: stage fp32 rows, then write transposed bf16
  {
    const float* vp = (wi < 63) ? (vbufw + ((size_t)hh * 64 + wi + 1) * 64 + d0)
                                : (vlast + (size_t)b * 1024 + hh * 64 + d0);
#pragma unroll
    for (int j4 = 0; j4 < 4; j4++)
      *(float4*)&Tv[wi][d0 + j4 * 4] = *(const float4*)(vp + j4 * 4);
  }
  __syncthreads();
  {
    int c = tid & 63, w0 = (tid >> 6) * 16;
    unsigned short* op = uvT + ((size_t)bh * 64 + c) * 64 + w0;
    unsigned short vals[16];
#pragma unroll
    for (int j = 0; j < 16; j++) vals[j] = f2bf(Tv[w0 + j][c]);
    *(short8*)op = *(short8*)&vals[0];
    *(short8*)(op + 8) = *(short8*)&vals[8];
  }
}

// --------------------------- window attention ------------------------------
// MFMA version: 1024 blocks = (bh, tile of 128 q-rows), 4 waves, barrier-free.
// scores = q2b @ ukb^T / 8; softmax over w (64); out = A @ uv.
__global__ __launch_bounds__(256) void window_attn2(
    const unsigned short* __restrict__ q2b, const unsigned short* __restrict__ ukb,
    const unsigned short* __restrict__ uvT, unsigned short* __restrict__ win) {
  __shared__ unsigned short S_l[128 * 64];   // 16 KB, swizzled softmax weights
  const int tid = threadIdx.x, lane = tid & 63, w = tid >> 6;
  const int m15 = lane & 15, quad = lane >> 4;
  const int bh = blockIdx.x >> 4, tile = blockIdx.x & 15;
  const int b = bh >> 4, hh = bh & 15;
  const int t0 = tile * 128 + w * 32;        // this wave's 32 rows (within b)
  const unsigned short* ukbase = ukb + (size_t)bh * 64 * 64;
  const unsigned short* uvbase = uvT + (size_t)bh * 64 * 64;
  // ---- QK^T (K=64) ----
  f32x4 accS[2][4] = {};
#pragma unroll
  for (int ks = 0; ks < 2; ks++) {
    short8 aF[2], bF[4];
#pragma unroll
    for (int mi = 0; mi < 2; mi++)
      aF[mi] = *(const short8*)(q2b + ((size_t)(b * LL + t0 + mi * 16 + m15)) * DD +
                                hh * 64 + ks * 32 + quad * 8);
#pragma unroll
    for (int ni = 0; ni < 4; ni++)
      bF[ni] = *(const short8*)(ukbase + ((size_t)(ni * 16 + m15)) * 64 + ks * 32 + quad * 8);
#pragma unroll
    for (int mi = 0; mi < 2; mi++)
#pragma unroll
      for (int ni = 0; ni < 4; ni++)
        accS[mi][ni] = __builtin_amdgcn_mfma_f32_16x16x32_bf16(
            aF[mi], bF[ni], accS[mi][ni], 0, 0, 0);
  }
  // ---- wave-parallel softmax over w (rows live across 16 lanes x 4 ni) ----
#pragma unroll
  for (int mi = 0; mi < 2; mi++) {
#pragma unroll
    for (int rr = 0; rr < 4; rr++) {
      float s0 = accS[mi][0][rr] * 0.125f;
      float s1 = accS[mi][1][rr] * 0.125f;
      float s2 = accS[mi][2][rr] * 0.125f;
      float s3 = accS[mi][3][rr] * 0.125f;
      float m = fmaxf(fmaxf(s0, s1), fmaxf(s2, s3));
      m = fmaxf(m, __shfl_xor(m, 1));
      m = fmaxf(m, __shfl_xor(m, 2));
      m = fmaxf(m, __shfl_xor(m, 4));
      m = fmaxf(m, __shfl_xor(m, 8));
      float p0 = __expf(s0 - m), p1 = __expf(s1 - m);
      float p2 = __expf(s2 - m), p3 = __expf(s3 - m);
      float l = p0 + p1 + p2 + p3;
      l += __shfl_xor(l, 1);
      l += __shfl_xor(l, 2);
      l += __shfl_xor(l, 4);
      l += __shfl_xor(l, 8);
      float inv = 1.0f / l;
      int tl = w * 32 + mi * 16 + quad * 4 + rr;
      int t7 = tl & 7;
      float pr[4] = {p0 * inv, p1 * inv, p2 * inv, p3 * inv};
#pragma unroll
      for (int ni = 0; ni < 4; ni++) {
        int s = ni * 16 + m15;
        S_l[tl * 64 + ((s >> 3) ^ t7) * 8 + (s & 7)] = f2bf(pr[ni]);
      }
    }
  }
  // ---- PV (K=64) — same-wave LDS RAW, no barrier ----
  f32x4 accO[2][4] = {};
#pragma unroll
  for (int ks = 0; ks < 2; ks++) {
    short8 aF[2], bF[4];
#pragma unroll
    for (int mi = 0; mi < 2; mi++) {
      int tl = w * 32 + mi * 16 + m15;
      int g = (ks * 4 + quad) ^ (tl & 7);
      aF[mi] = *(const short8*)&S_l[tl * 64 + g * 8];
    }
#pragma unroll
    for (int ni = 0; ni < 4; ni++)
      bF[ni] = *(const short8*)(uvbase + ((size_t)(ni * 16 + m15)) * 64 + ks * 32 + quad * 8);
#pragma unroll
    for (int mi = 0; mi < 2; mi++)
#pragma unroll
      for (int ni = 0; ni < 4; ni++)
        accO[mi][ni] = __builtin_amdgcn_mfma_f32_16x16x32_bf16(
            aF[mi], bF[ni], accO[mi][ni], 0, 0, 0);
  }
  // ---- epilogue ----
#pragma unroll
  for (int mi = 0; mi < 2; mi++) {
#pragma unroll
    for (int rr = 0; rr < 4; rr++) {
      int row = t0 + mi * 16 + quad * 4 + rr;
      unsigned short* op = win + ((size_t)(b * LL + row)) * DD + hh * 64;
#pragma unroll
      for (int ni = 0; ni < 4; ni++)
        op[ni * 16 + m15] = f2bf(accO[mi][ni][rr]);
    }
  }
}

// ------------------------------ LayerNorm ----------------------------------
__global__ __launch_bounds__(256) void ln_add(
    const float* __restrict__ A, const float* __restrict__ Bm,
    const float* __restrict__ gamma, const float* __restrict__ beta,
    float* __restrict__ out, unsigned short* __restrict__ outb) {
  const int row = blockIdx.x, tid = threadIdx.x;
  float4 va = ((const float4*)(A + (size_t)row * DD))[tid];
  float4 vb = ((const float4*)(Bm + (size_t)row * DD))[tid];
  float4 s4 = f4(va.x + vb.x, va.y + vb.y, va.z + vb.z, va.w + vb.w);
  float s = s4.x + s4.y + s4.z + s4.w;
  float ss = s4.x * s4.x + s4.y * s4.y + s4.z * s4.z + s4.w * s4.w;
  for (int o = 32; o; o >>= 1) { s += __shfl_xor(s, o); ss += __shfl_xor(ss, o); }
  __shared__ float red[8];
  int wid = tid >> 6;
  if ((tid & 63) == 0) { red[wid * 2] = s; red[wid * 2 + 1] = ss; }
  __syncthreads();
  float tot = red[0] + red[2] + red[4] + red[6];
  float tots = red[1] + red[3] + red[5] + red[7];
  float mu = tot * (1.0f / 1024.0f);
  float var = tots * (1.0f / 1024.0f) - mu * mu;
  float rstd = rsqrtf(var + 1e-5f);
  float4 g = ((const float4*)gamma)[tid];
  float4 be = ((const float4*)beta)[tid];
  float4 o = f4((s4.x - mu) * rstd * g.x + be.x, (s4.y - mu) * rstd * g.y + be.y,
                (s4.z - mu) * rstd * g.z + be.z, (s4.w - mu) * rstd * g.w + be.w);
  ((float4*)(out + (size_t)row * DD))[tid] = o;
  if (outb) {
    ushort4 r;
    r.x = f2bf(o.x); r.y = f2bf(o.y); r.z = f2bf(o.z); r.w = f2bf(o.w);
    ((ushort4*)(outb + (size_t)row * DD))[tid] = r;
  }
}

// ------------------------------ launch -------------------------------------
extern "C" void kernel_launch(void* const* d_in, const int* in_sizes, int n_in,
                              void* d_out, int out_size, void* d_ws, size_t ws_size,
                              hipStream_t stream) {
  (void)in_sizes; (void)n_in; (void)out_size; (void)ws_size;
  const float* x      = (const float*)d_in[0];
  const float* kv0    = (const float*)d_in[1];
  const float* kst0   = (const float*)d_in[2];
  const float* kbuf   = (const float*)d_in[3];
  const float* vbufw  = (const float*)d_in[4];
  const float* Wq_lin = (const float*)d_in[5];
  const float* bq_lin = (const float*)d_in[6];
  const float* Wk_lin = (const float*)d_in[7];
  const float* bk_lin = (const float*)d_in[8];
  const float* Wv_lin = (const float*)d_in[9];
  const float* bv_lin = (const float*)d_in[10];
  const float* Wo_lin = (const float*)d_in[11];
  const float* bo_lin = (const float*)d_in[12];
  const float* Wq     = (const float*)d_in[13];
  const float* bq     = (const float*)d_in[14];
  const float* Wk     = (const float*)d_in[15];
  const float* bk     = (const float*)d_in[16];
  const float* Wv     = (const float*)d_in[17];
  const float* bv     = (const float*)d_in[18];
  const float* Wo     = (const float*)d_in[19];
  const float* bo     = (const float*)d_in[20];
  const float* gamma  = (const float*)d_in[21];
  const float* beta   = (const float*)d_in[22];

  float* out = (float*)d_out;
  float* kv_out  = out + 8388608;
  float* kst_out = out + 8388608 + 1118208;

  float* ws = (float*)d_ws;
  const size_t MF = 1024 * 1024;
  // float-offset layout (lifetimes in comments)
  unsigned short* qlin_b = (unsigned short*)(ws);              // [0,1)  until phaseC
  unsigned short* klin_b = (unsigned short*)(ws + 1 * MF);     // [1,2)  until phaseC
  unsigned short* v_b    = (unsigned short*)(ws + 2 * MF);     // [2,6)  until transV
  unsigned short* vT     = (unsigned short*)(ws + 6 * MF);     // [6,10) until phaseC
  unsigned short* KVc_t  = (unsigned short*)(ws + 10 * MF);    // [10,19) A->B
  unsigned short* kstc   = (unsigned short*)(ws + 19 * MF);    // [19,19.15) A->B
  unsigned short* KVp_t  = (unsigned short*)(ws + 20 * MF);    // [20,29) B->C
  unsigned short* kstp   = (unsigned short*)(ws + 29 * MF);    // [29,29.15) B->C
  unsigned short* x_bf   = (unsigned short*)(ws + 30 * MF);    // [30,34) until v GEMM
  unsigned short* outs_bf = (unsigned short*)(ws + 2 * MF);    // [2,6)  C->O1 (v_b dead)
  float* tmp  = ws + 10 * MF;                                  // [10,18) O1->ln (KVc_t dead)
  float* x1   = ws + 20 * MF;                                  // [20,28) (KVp_t dead)
  unsigned short* x1b = (unsigned short*)(ws + 30 * MF);       // [30,32) (x_bf dead)
  unsigned short* q2b = (unsigned short*)ws;                   // [0,4)  (qlin/klin/outs/vT dead)
  unsigned short* winb = (unsigned short*)(ws + 8 * MF);       // [8,12) (tmp dead)
  float* tmp2 = ws + 12 * MF;                                  // [12,20)
  float* klast = ws + 34 * MF;                                 // 4096 floats
  float* vlast = klast + 4096;                                 // 4096 floats
  unsigned short* ukb = (unsigned short*)(ws + 34 * MF + 8192);      // 64*64*64 bf16
  unsigned short* uvTw = ukb + 262144;                               // 64*64*64 bf16
  unsigned short* WtQL = (unsigned short*)(ws + 35 * MF);
  unsigned short* WtKL = WtQL + 262144;
  unsigned short* WtVL = WtQL + 524288;
  unsigned short* WtO1 = WtQL + 1572864;
  unsigned short* WtQ2 = WtQL + 2621440;
  unsigned short* WtO2 = WtQL + 3670016;

  dim3 blk(256);
  cast_bf16<<<8192, blk, 0, stream>>>(x, x_bf, 2097152);
  castT<<<dim3(16, 4), blk, 0, stream>>>(Wq_lin, WtQL, 1024, 256);
  castT<<<dim3(16, 4), blk, 0, stream>>>(Wk_lin, WtKL, 1024, 256);
  castT<<<dim3(16, 16), blk, 0, stream>>>(Wv_lin, WtVL, 1024, 1024);
  castT<<<dim3(16, 16), blk, 0, stream>>>(Wo_lin, WtO1, 1024, 1024);
  castT<<<dim3(16, 16), blk, 0, stream>>>(Wq, WtQ2, 1024, 1024);
  castT<<<dim3(16, 16), blk, 0, stream>>>(Wo, WtO2, 1024, 1024);
  gemm_mfma<<<dim3(64, 2), blk, 0, stream>>>(x_bf, WtQL, bq_lin, (float*)0, qlin_b, 8192, 256, 1024);
  gemm_mfma<<<dim3(64, 2), blk, 0, stream>>>(x_bf, WtKL, bk_lin, (float*)0, klin_b, 8192, 256, 1024);
  gemm_mfma<<<dim3(64, 8), blk, 0, stream>>>(x_bf, WtVL, bv_lin, (float*)0, v_b, 8192, 1024, 1024);
  transV<<<2048, blk, 0, stream>>>(v_b, vT);
  phaseA2<<<1024, blk, 0, stream>>>(klin_b, vT, KVc_t, kstc);
  phaseB3<<<585, blk, 0, stream>>>(KVc_t, kstc, kv0, kst0, KVp_t, kstp, kv_out, kst_out);
  phaseC4<<<1024, blk, 0, stream>>>(qlin_b, klin_b, vT, KVp_t, kstp, outs_bf);
  gemm_mfma<<<dim3(64, 8), blk, 0, stream>>>(outs_bf, WtO1, bo_lin, tmp, (unsigned short*)0, 8192, 1024, 1024);
  ln_add<<<8192, blk, 0, stream>>>(x, tmp, gamma, beta, x1, x1b);
  gemm_mfma<<<dim3(64, 8), blk, 0, stream>>>(x1b, WtQ2, bq, (float*)0, q2b, 8192, 1024, 1024);
  lastrow_qkv<<<32, blk, 0, stream>>>(x1, Wk, bk, Wv, bv, klast, vlast);
  prep_window<<<64, blk, 0, stream>>>(kbuf, vbufw, klast, vlast, ukb, uvTw);
  window_attn2<<<1024, blk, 0, stream>>>(q2b, ukb, uvTw, winb);
  gemm_mfma<<<dim3(64, 8), blk, 0, stream>>>(winb, WtO2, bo, tmp2, (unsigned short*)0, 8192, 1024, 1024);
  ln_add<<<8192, blk, 0, stream>>>(x1, tmp2, gamma, beta, out, (unsigned short*)0);
}

// Round 4
// 443.425 us; speedup vs baseline: 1.1737x; 1.0819x over previous
//
#include <hip/hip_runtime.h>
#include <math.h>

// ---------------------------------------------------------------------------
// BasedBlock: B=4 L=2048 d=1024 h=16 f=16 hd=64 w=64, D=1+f+f*f=273
// Round 9: lastrow_qkv was 46us at 1.2% occupancy (32 blocks). Replaced by
//   lastrow_init (bias) + lastrow_qkv2: k-split across 512 blocks, LDS
//   reduce, one atomicAdd per (b,n) per block. Roofline ~1.3us + overhead.
// ---------------------------------------------------------------------------

#define LL 2048
#define DD 1024
#define DFEAT 273
#define NC 16
#define CHUNK 128

typedef __attribute__((ext_vector_type(8))) short short8;
typedef __attribute__((ext_vector_type(4))) float f32x4;

#define SQ 0.42044820762685725f   // sqrt(1/(sqrt(2)*sqrt(16))) = sqrt(0.176776...)
#define LF 1.18920711500272107f   // 0.5 / SQ

__device__ __forceinline__ float4 f4(float a, float b, float c, float d) {
  float4 r; r.x = a; r.y = b; r.z = c; r.w = d; return r;
}

__device__ __forceinline__ unsigned short f2bf(float f) {
  union { float f; unsigned u; } v; v.f = f;
  unsigned r = v.u + 0x7fffu + ((v.u >> 16) & 1u);
  return (unsigned short)(r >> 16);
}

__device__ __forceinline__ float bf2f(unsigned short u) {
  union { unsigned u; float f; } v; v.u = ((unsigned)u) << 16; return v.f;
}

// --------------------------- cast kernels ----------------------------------
__global__ __launch_bounds__(256) void cast_bf16(
    const float* __restrict__ in, unsigned short* __restrict__ o, int n4) {
  int i = blockIdx.x * 256 + threadIdx.x;
  if (i < n4) {
    float4 v = ((const float4*)in)[i];
    ushort4 r;
    r.x = f2bf(v.x); r.y = f2bf(v.y); r.z = f2bf(v.z); r.w = f2bf(v.w);
    ((ushort4*)o)[i] = r;
  }
}

// W[K][N] fp32 -> Wt[N][K] bf16
__global__ __launch_bounds__(256) void castT(
    const float* __restrict__ W, unsigned short* __restrict__ Wt, int K, int N) {
  __shared__ float t[64][65];
  int k0 = blockIdx.x * 64, n0 = blockIdx.y * 64;
  int tid = threadIdx.x;
#pragma unroll
  for (int p = 0; p < 16; p++) {
    int idx = p * 256 + tid;
    int r = idx >> 6, c = idx & 63;
    t[r][c] = W[(size_t)(k0 + r) * N + n0 + c];
  }
  __syncthreads();
#pragma unroll
  for (int p = 0; p < 16; p++) {
    int idx = p * 256 + tid;
    int rn = idx >> 6, ck = idx & 63;
    Wt[(size_t)(n0 + rn) * K + k0 + ck] = f2bf(t[ck][rn]);
  }
}

// --------------------------- MFMA GEMM -------------------------------------
__global__ __launch_bounds__(256) void gemm_mfma(
    const unsigned short* __restrict__ A, const unsigned short* __restrict__ Bt,
    const float* __restrict__ bias, float* __restrict__ C,
    unsigned short* __restrict__ Cb, int M, int N, int K) {
  __shared__ unsigned short As[128 * 64];
  __shared__ unsigned short Bs[128 * 64];
  const int tid = threadIdx.x;
  const int lane = tid & 63, w = tid >> 6;
  const int row0 = blockIdx.x * 128, col0 = blockIdx.y * 128;
  const int wm0 = (w & 1) * 64, wn0 = (w >> 1) * 64;
  const int lr = lane >> 3;
  const int gc = (lane & 7) ^ lr;
  const unsigned short* aP = A + (size_t)(row0 + w * 32 + lr) * K + gc * 8;
  const unsigned short* bP = Bt + (size_t)(col0 + w * 32 + lr) * K + gc * 8;
  unsigned short* asW = As + w * 2048;
  unsigned short* bsW = Bs + w * 2048;
  const int m15 = lane & 15, quad = lane >> 4;
  f32x4 acc[4][4] = {};
  for (int k0 = 0; k0 < K; k0 += 64) {
#pragma unroll
    for (int i = 0; i < 4; i++) {
      __builtin_amdgcn_global_load_lds(
          (const __attribute__((address_space(1))) unsigned int*)(const void*)(aP + (size_t)(i * 8) * K + k0),
          (__attribute__((address_space(3))) unsigned int*)(void*)(asW + i * 512), 16, 0, 0);
      __builtin_amdgcn_global_load_lds(
          (const __attribute__((address_space(1))) unsigned int*)(const void*)(bP + (size_t)(i * 8) * K + k0),
          (__attribute__((address_space(3))) unsigned int*)(void*)(bsW + i * 512), 16, 0, 0);
    }
    __syncthreads();
#pragma unroll
    for (int ks = 0; ks < 2; ks++) {
      short8 aF[4], bF[4];
#pragma unroll
      for (int mi = 0; mi < 4; mi++) {
        int r = wm0 + mi * 16 + m15;
        int g = (ks * 4 + quad) ^ (r & 7);
        aF[mi] = *(const short8*)(As + r * 64 + g * 8);
      }
#pragma unroll
      for (int ni = 0; ni < 4; ni++) {
        int r = wn0 + ni * 16 + m15;
        int g = (ks * 4 + quad) ^ (r & 7);
        bF[ni] = *(const short8*)(Bs + r * 64 + g * 8);
      }
#pragma unroll
      for (int mi = 0; mi < 4; mi++)
#pragma unroll
        for (int ni = 0; ni < 4; ni++)
          acc[mi][ni] = __builtin_amdgcn_mfma_f32_16x16x32_bf16(
              aF[mi], bF[ni], acc[mi][ni], 0, 0, 0);
    }
    __syncthreads();
  }
#pragma unroll
  for (int mi = 0; mi < 4; mi++)
#pragma unroll
    for (int ni = 0; ni < 4; ni++) {
      int col = col0 + wn0 + ni * 16 + m15;
      float bb = bias[col];
#pragma unroll
      for (int r = 0; r < 4; r++) {
        int row = row0 + wm0 + mi * 16 + quad * 4 + r;
        float val = acc[mi][ni][r] + bb;
        if (Cb) Cb[(size_t)row * N + col] = f2bf(val);
        else C[(size_t)row * N + col] = val;
      }
    }
}

// ------------------------------ transV -------------------------------------
// v_b[t][h*64+c] -> vT[bh][c][t]
__global__ __launch_bounds__(256) void transV(
    const unsigned short* __restrict__ v_b, unsigned short* __restrict__ vT) {
  __shared__ unsigned short Tv[64][72];
  const int blk = blockIdx.x;
  const int bh = blk >> 5, tt = blk & 31;
  const int b = bh >> 4, hh = bh & 15;
  const int t0 = tt * 64;
  const int tid = threadIdx.x;
  {
    int t = tid >> 2, cs = tid & 3;
    const unsigned short* p = v_b + ((size_t)(b * LL + t0 + t)) * DD + hh * 64 + cs * 16;
    *(short8*)&Tv[t][cs * 16] = *(const short8*)p;
    *(short8*)&Tv[t][cs * 16 + 8] = *(const short8*)(p + 8);
  }
  __syncthreads();
  {
    int c = tid & 63, ts = tid >> 6;
    unsigned short vals[16];
#pragma unroll
    for (int j = 0; j < 16; j++) vals[j] = Tv[ts * 16 + j][c];
    unsigned short* op = vT + ((size_t)bh * 64 + c) * LL + t0 + ts * 16;
    *(short8*)op = *(short8*)&vals[0];
    *(short8*)(op + 8) = *(short8*)&vals[8];
  }
}

// ------------------------------ phase A ------------------------------------
// KVc_t[bh][ck][c][f] = sum_t Kf[t][f] V[t][c] (bf16); kstc[bh][ck][f].
__global__ __launch_bounds__(256) void phaseA2(
    const unsigned short* __restrict__ klin, const unsigned short* __restrict__ vT,
    unsigned short* __restrict__ KVc_t, unsigned short* __restrict__ kstc) {
  __shared__ unsigned short kT[16][136];   // kT[i][t] = bf16(k[t][i]*SQ)
  const int tid = threadIdx.x, lane = tid & 63, w = tid >> 6;
  const int m15 = lane & 15, quad = lane >> 4;
  const int bh = blockIdx.x >> 4, ck = blockIdx.x & 15;
  const int b = bh >> 4, hh = bh & 15;
  const int t0 = ck * CHUNK;
  {
    int r = tid >> 1, half = tid & 1;
    short8 kv = *(const short8*)(klin + ((size_t)(b * LL + t0 + r)) * 256 + hh * 16 + half * 8);
#pragma unroll
    for (int j = 0; j < 8; j++)
      kT[half * 8 + j][r] = f2bf(bf2f(((unsigned short*)&kv)[j]) * SQ);
  }
  __syncthreads();
  short8 ones8 = {16256, 16256, 16256, 16256, 16256, 16256, 16256, 16256};
  short8 zer8 = {0, 0, 0, 0, 0, 0, 0, 0};
  f32x4 acc[5][5] = {};
  const unsigned short* vbase = vT + (size_t)bh * 64 * LL + t0;
#pragma unroll
  for (int ks = 0; ks < 4; ++ks) {
    const int tt = ks * 32 + quad * 8;
    short8 aF[5], bF[5];
#pragma unroll
    for (int mi = 0; mi < 5; mi++) {
      int r = (w * 5 + mi) * 16 + m15;
      short8 av;
      unsigned short* pv = (unsigned short*)&av;
      if (r == 0) {
        av = ones8;
      } else if (r < 17) {
        short8 k1 = *(const short8*)&kT[r - 1][tt];
#pragma unroll
        for (int j = 0; j < 8; j++) pv[j] = f2bf(bf2f(((unsigned short*)&k1)[j]) * LF);
      } else if (r < DFEAT) {
        int ij = r - 17;
        short8 k1 = *(const short8*)&kT[ij >> 4][tt];
        short8 k2 = *(const short8*)&kT[ij & 15][tt];
#pragma unroll
        for (int j = 0; j < 8; j++)
          pv[j] = f2bf(bf2f(((unsigned short*)&k1)[j]) * bf2f(((unsigned short*)&k2)[j]));
      } else {
        av = zer8;
      }
      aF[mi] = av;
    }
#pragma unroll
    for (int ni = 0; ni < 4; ni++)
      bF[ni] = *(const short8*)(vbase + ((size_t)(ni * 16 + m15)) * LL + tt);
    bF[4] = (m15 == 0) ? ones8 : zer8;
#pragma unroll
    for (int mi = 0; mi < 5; mi++)
#pragma unroll
      for (int ni = 0; ni < 5; ni++)
        acc[mi][ni] = __builtin_amdgcn_mfma_f32_16x16x32_bf16(
            aF[mi], bF[ni], acc[mi][ni], 0, 0, 0);
  }
  const size_t cb = ((size_t)bh * NC + ck) * (64 * 288);
  const size_t kb = ((size_t)bh * NC + ck) * 288;
#pragma unroll
  for (int mi = 0; mi < 5; mi++) {
    int fb = (w * 5 + mi) * 16 + quad * 4;
    if (fb < 288) {
#pragma unroll
      for (int ni = 0; ni < 4; ni++) {
        int c = ni * 16 + m15;
        ushort4 sv;
        sv.x = f2bf(acc[mi][ni][0]); sv.y = f2bf(acc[mi][ni][1]);
        sv.z = f2bf(acc[mi][ni][2]); sv.w = f2bf(acc[mi][ni][3]);
        *(ushort4*)(KVc_t + cb + (size_t)c * 288 + fb) = sv;
      }
      if (m15 == 0) {
        ushort4 sv;
        sv.x = f2bf(acc[mi][4][0]); sv.y = f2bf(acc[mi][4][1]);
        sv.z = f2bf(acc[mi][4][2]); sv.w = f2bf(acc[mi][4][3]);
        *(ushort4*)(kstc + kb + fb) = sv;
      }
    }
  }
}

// ------------------------------ phase B ------------------------------------
// Blocks [0,576): KV scan (thread per (bh,c,f8)); [576,585): kst scan.
__global__ __launch_bounds__(256) void phaseB3(
    const unsigned short* __restrict__ KVc_t, const unsigned short* __restrict__ kstc,
    const float* __restrict__ kv0, const float* __restrict__ kst0,
    unsigned short* __restrict__ KVp_t, unsigned short* __restrict__ kstp,
    float* __restrict__ kv_out, float* __restrict__ kst_out) {
  const int tid = threadIdx.x;
  if (blockIdx.x < 576) {
    int gid = blockIdx.x * 256 + tid;
    int bh = gid / 2304, rem = gid - bh * 2304;
    int c = rem / 36, fg = rem - c * 36;
    int f0 = fg * 8;
    float acc[8];
#pragma unroll
    for (int j = 0; j < 8; j++) {
      int f = f0 + j;
      acc[j] = (f < DFEAT) ? kv0[((size_t)bh * DFEAT + f) * 64 + c] : 0.0f;
    }
    size_t base = ((size_t)bh * NC) * (64 * 288) + (size_t)c * 288 + f0;
    for (int ck = 0; ck < NC; ck++) {
      size_t idx = base + (size_t)ck * (64 * 288);
      short8 t = *(const short8*)(KVc_t + idx);
      unsigned short ov[8];
#pragma unroll
      for (int j = 0; j < 8; j++) {
        ov[j] = f2bf(acc[j]);
        acc[j] += bf2f(((unsigned short*)&t)[j]);
      }
      *(short8*)(KVp_t + idx) = *(short8*)ov;
    }
#pragma unroll
    for (int j = 0; j < 8; j++) {
      int f = f0 + j;
      if (f < DFEAT) kv_out[((size_t)bh * DFEAT + f) * 64 + c] = acc[j];
    }
  } else {
    int idx0 = (blockIdx.x - 576) * 256 + tid;   // 0..2303
    int bh = idx0 / 36, fg = idx0 - bh * 36;
    int f0 = fg * 8;
    float acc[8];
#pragma unroll
    for (int j = 0; j < 8; j++) {
      int f = f0 + j;
      acc[j] = (f < DFEAT) ? kst0[bh * DFEAT + f] : 0.0f;
    }
    for (int ck = 0; ck < NC; ck++) {
      size_t idx = ((size_t)bh * NC + ck) * 288 + f0;
      short8 t = *(const short8*)(kstc + idx);
      unsigned short ov[8];
#pragma unroll
      for (int j = 0; j < 8; j++) {
        ov[j] = f2bf(acc[j]);
        acc[j] += bf2f(((unsigned short*)&t)[j]);
      }
      *(short8*)(kstp + idx) = *(short8*)ov;
    }
#pragma unroll
    for (int j = 0; j < 8; j++) {
      int f = f0 + j;
      if (f < DFEAT) kst_out[bh * DFEAT + f] = acc[j];
    }
  }
}

// ------------------------------ phase C ------------------------------------
// 256-thread blocks, grid 1024 = (bh, ck); wave w = causal quarter qw.
// Fully barrier-free: qs / S_l are wave-private slices. The 4 waves read the
// same KV'/kst fragments on the same CU -> one HBM fetch per chunk.
__global__ __launch_bounds__(256) void phaseC4(
    const unsigned short* __restrict__ qlin, const unsigned short* __restrict__ klin,
    const unsigned short* __restrict__ vT, const unsigned short* __restrict__ KVp_t,
    const unsigned short* __restrict__ kstp, unsigned short* __restrict__ outs) {
  __shared__ float qs[4][32][36];              // per-wave: [0..15]=q*SQ, [16..31]=rot dup
  __shared__ unsigned short S_l[4][32 * 128];  // per-wave swizzled intra scores
  const int tid = threadIdx.x, lane = tid & 63, w = tid >> 6;
  const int m15 = lane & 15, quad = lane >> 4;
  const int bh = blockIdx.x >> 4, ck = blockIdx.x & 15;
  const int qw = w;
  const int b = bh >> 4, hh = bh & 15;
  const int t0 = ck * CHUNK;
  const int tr0 = qw * 32;
  float (*qsw)[36] = qs[w];
  unsigned short* Sw = S_l[w];
  const unsigned short* qbase = qlin + ((size_t)(b * LL + t0 + tr0)) * 256 + hh * 16;
  const unsigned short* kbase = klin + ((size_t)(b * LL + t0)) * 256 + hh * 16;
  // ---- fill qs (wave-private rows, no barrier) ----
  {
    int r = lane >> 1, h8 = lane & 1;
    short8 qv = *(const short8*)(qbase + (size_t)r * 256 + h8 * 8);
    float qf[8];
#pragma unroll
    for (int j = 0; j < 8; j++) qf[j] = bf2f(((unsigned short*)&qv)[j]) * SQ;
    *(float4*)&qsw[r][h8 * 8] = f4(qf[0], qf[1], qf[2], qf[3]);
    *(float4*)&qsw[r][h8 * 8 + 4] = f4(qf[4], qf[5], qf[6], qf[7]);
#pragma unroll
    for (int j = 0; j < 8; j++)
      qsw[r][16 + ((h8 * 8 + j + 9) & 15)] = qf[j];   // rot[m] = q[(m+7)&15]
  }
  short8 ones8 = {16256, 16256, 16256, 16256, 16256, 16256, 16256, 16256};
  short8 zer8 = {0, 0, 0, 0, 0, 0, 0, 0};
  f32x4 acc[2][5] = {};
  const unsigned short* KVb = KVp_t + ((size_t)(bh * NC + ck)) * (64 * 288);
  const unsigned short* kstb = kstp + ((size_t)(bh * NC + ck)) * 288;
  // ---- pass 1: inter (Qf @ KV'), K = 288 ----
#pragma unroll
  for (int ks = 0; ks < 9; ++ks) {
    const int fs = ks * 32 + quad * 8;
    short8 aF[2], bF[5];
#pragma unroll
    for (int ni = 0; ni < 4; ni++)
      bF[ni] = *(const short8*)(KVb + ((size_t)(ni * 16 + m15)) * 288 + fs);
    bF[4] = (m15 == 0) ? *(const short8*)(kstb + fs) : zer8;
#pragma unroll
    for (int mi = 0; mi < 2; mi++) {
      const float* qr = &qsw[mi * 16 + m15][0];
      unsigned short pv[8];
      if (ks == 0) {
        // f = quad*8 + j in [0,32): mix of const-1, linear, i=0 products
        float qr0 = qr[0];
#pragma unroll
        for (int j = 0; j < 8; j++) {
          int f = (quad << 3) + j;
          int fl = f - 1; fl = fl < 0 ? 0 : fl;
          int fm = f - 17; fm = fm < 0 ? 0 : fm;     // < 16 here
          float lin = qr[fl] * LF;
          float prod = qr0 * qr[fm];
          float val = (f == 0) ? 1.0f : ((f < 17) ? lin : prod);
          pv[j] = f2bf(val);
        }
      } else {
        // all products: i = (f-17)>>4, jj = (f-17)&15; jj0 in {7,15}
        int base = fs - 17;                 // >= 15
        int i0 = base >> 4;
        float qi0 = qr[i0];
        float qi1 = qr[i0 + 1];
        const float* qv = qr + 16 + (base & 8);   // aligned 32B window (rot dup)
        float qj[8];
        *(float4*)&qj[0] = *(const float4*)qv;
        *(float4*)&qj[4] = *(const float4*)(qv + 4);
        float qiB = (quad & 1) ? qi0 : qi1;       // jj0==7 -> i const; ==15 -> bump after j=0
#pragma unroll
        for (int j = 0; j < 8; j++) {
          float qi = (j == 0) ? qi0 : qiB;
          float val = qi * qj[j];
          if (ks == 8) val = ((quad << 3) + j < 17) ? val : 0.0f;  // f >= 273 -> 0
          pv[j] = f2bf(val);
        }
      }
      aF[mi] = *(short8*)pv;
    }
#pragma unroll
    for (int mi = 0; mi < 2; mi++)
#pragma unroll
      for (int ni = 0; ni < 5; ni++)
        acc[mi][ni] = __builtin_amdgcn_mfma_f32_16x16x32_bf16(
            aF[mi], bF[ni], acc[mi][ni], 0, 0, 0);
  }
  // ---- intra: u = q@k^T (K=16 pad 32) -> poly/mask -> S_l (wave-private) ----
  const int nsn = 2 * qw + 2;               // s covers [0, (qw+1)*32)
  {
    short8 aU[2], bU[8];
    aU[0] = (quad < 2) ? *(const short8*)(qbase + (size_t)m15 * 256 + quad * 8) : zer8;
    aU[1] = (quad < 2) ? *(const short8*)(qbase + (size_t)(16 + m15) * 256 + quad * 8) : zer8;
#pragma unroll
    for (int sn = 0; sn < 8; sn++) {
      if (sn < nsn) {
        int s = sn * 16 + m15;
        bU[sn] = (quad < 2) ? *(const short8*)(kbase + (size_t)s * 256 + quad * 8) : zer8;
      }
    }
#pragma unroll
    for (int mi = 0; mi < 2; mi++) {
#pragma unroll
      for (int sn = 0; sn < 8; sn++) {
        if (sn < nsn) {
          f32x4 zz = {0.f, 0.f, 0.f, 0.f};
          f32x4 u = __builtin_amdgcn_mfma_f32_16x16x32_bf16(aU[mi], bU[sn], zz, 0, 0, 0);
          int s = sn * 16 + m15;
          int gRow = s >> 3;
#pragma unroll
          for (int rr = 0; rr < 4; rr++) {
            int tl = mi * 16 + quad * 4 + rr;        // local row 0..31
            int tc = tr0 + tl;                       // chunk-local row for mask
            float uu = u[rr];
            float sv = (s <= tc) ? fmaf(uu, fmaf(uu, 0.03125f, 0.25f), 1.0f) : 0.0f;
            int p = gRow ^ (tl & 7);
            Sw[tl * 128 + p * 8 + (s & 7)] = f2bf(sv);
          }
        }
      }
    }
  }
  // ---- pass 2: S @ V' — no barrier (same-wave LDS RAW) ----
  const unsigned short* vbase = vT + (size_t)bh * 64 * LL + t0;
#pragma unroll
  for (int ks = 0; ks < 4; ++ks) {
    if (ks <= qw) {
      const int tt = ks * 32 + quad * 8;
      short8 aF[2], bF[5];
#pragma unroll
      for (int mi = 0; mi < 2; mi++) {
        int tl = mi * 16 + m15;
        int p = (ks * 4 + quad) ^ (tl & 7);
        aF[mi] = *(const short8*)&Sw[tl * 128 + p * 8];
      }
#pragma unroll
      for (int ni = 0; ni < 4; ni++)
        bF[ni] = *(const short8*)(vbase + ((size_t)(ni * 16 + m15)) * LL + tt);
      bF[4] = (m15 == 0) ? ones8 : zer8;
#pragma unroll
      for (int mi = 0; mi < 2; mi++)
#pragma unroll
        for (int ni = 0; ni < 5; ni++)
          acc[mi][ni] = __builtin_amdgcn_mfma_f32_16x16x32_bf16(
              aF[mi], bF[ni], acc[mi][ni], 0, 0, 0);
    }
  }
  // ---- epilogue ----
#pragma unroll
  for (int mi = 0; mi < 2; mi++) {
#pragma unroll
    for (int rr = 0; rr < 4; rr++) {
      float den = __shfl(acc[mi][4][rr], (lane & 48));
      float inv = 1.0f / (den + 1e-6f);
      int tl = mi * 16 + quad * 4 + rr;
      unsigned short* op = outs + ((size_t)(b * LL + t0 + tr0 + tl)) * DD + hh * 64;
#pragma unroll
      for (int ni = 0; ni < 4; ni++)
        op[ni * 16 + m15] = f2bf(acc[mi][ni][rr] * inv);
    }
  }
}

// --------------------------- last-row k2/v2 --------------------------------
// init: klast/vlast = bias (one write per element)
__global__ __launch_bounds__(256) void lastrow_init(
    const float* __restrict__ bk, const float* __restrict__ bv,
    float* __restrict__ klast, float* __restrict__ vlast) {
  int gid = blockIdx.x * 256 + threadIdx.x;   // grid 32 -> 8192
  int which = gid >> 12;
  int b = (gid >> 10) & 3;
  int n = gid & 1023;
  (which ? vlast : klast)[b * 1024 + n] = which ? bv[n] : bk[n];
}

// main: grid 512 = which(2) x nstrip(16 x 64 cols) x kslice(16 x 64 rows).
// Each block: LDS-stage 4 last-row x-slices, stream 64x64 W tile coalesced,
// LDS-reduce the 4 waves, one atomicAdd per (b,n).
__global__ __launch_bounds__(256) void lastrow_qkv2(
    const float* __restrict__ x1,
    const float* __restrict__ Wk, const float* __restrict__ Wv,
    float* __restrict__ klast, float* __restrict__ vlast) {
  __shared__ float xs[4][64];
  __shared__ float red[4][4][64];
  const int blk = blockIdx.x;
  const int which = blk >> 8;
  const int nstrip = (blk >> 4) & 15;
  const int kslice = blk & 15;
  const int n0 = nstrip * 64, k0 = kslice * 64;
  const int tid = threadIdx.x;
  const int nn = tid & 63, p = tid >> 6;
  {
    int b = tid >> 6, k = tid & 63;
    xs[b][k] = x1[((size_t)(b * LL + LL - 1)) * DD + k0 + k];
  }
  __syncthreads();
  const float* W = which ? Wv : Wk;
  float acc[4] = {};
#pragma unroll
  for (int i = 0; i < 16; i++) {
    int kk = p * 16 + i;
    float wv = W[(size_t)(k0 + kk) * 1024 + n0 + nn];
#pragma unroll
    for (int b = 0; b < 4; b++) acc[b] = fmaf(xs[b][kk], wv, acc[b]);
  }
#pragma unroll
  for (int b = 0; b < 4; b++) red[p][b][nn] = acc[b];
  __syncthreads();
  if (p == 0) {
    float* outp = which ? vlast : klast;
#pragma unroll
    for (int b = 0; b < 4; b++) {
      float s = red[0][b][nn] + red[1][b][nn] + red[2][b][nn] + red[3][b][nn];
      atomicAdd(outp + b * 1024 + n0 + nn, s);
    }
  }
}

// --------------------------- window prep -----------------------------------
// Build bf16 ukb[bh][w][d] and uvT[bh][c][w] from fp32 kbuf/vbufw + klast/vlast.
__global__ __launch_bounds__(256) void prep_window(
    const float* __restrict__ kbuf, const float* __restrict__ vbufw,
    const float* __restrict__ klast, const float* __restrict__ vlast,
    unsigned short* __restrict__ ukb, unsigned short* __restrict__ uvT) {
  __shared__ float Tv[64][68];
  const int bh = blockIdx.x;
  const int b = bh >> 4, hh = bh & 15;
  const int tid = threadIdx.x;
  const int wi = tid >> 2, d0 = (tid & 3) * 16;
  // uk row (shift-by-one window): straight bf16 convert
  {
    const float* kp = (wi < 63) ? (kbuf + ((size_t)hh * 64 + wi + 1) * 64 + d0)
                                : (klast + (size_t)b * 1024 + hh * 64 + d0);
    unsigned short* op = ukb + ((size_t)bh * 64 + wi) * 64 + d0;
#pragma unroll
    for (int j4 = 0; j4 < 4; j4++) {
      float4 v = *(const float4*)(kp + j4 * 4);
      ushort4 r;
      r.x = f2bf(v.x); r.y = f2bf(v.y); r.z = f2bf(v.z); r.w = f2bf(v.w);
      *(ushort4*)(op + j4 * 4) = r;
    }
  }
  // uv: stage fp32 rows, then write transposed bf16
  {
    const float* vp = (wi < 63) ? (vbufw + ((size_t)hh * 64 + wi + 1) * 64 + d0)
                                : (vlast + (size_t)b * 1024 + hh * 64 + d0);
#pragma unroll
    for (int j4 = 0; j4 < 4; j4++)
      *(float4*)&Tv[wi][d0 + j4 * 4] = *(const float4*)(vp + j4 * 4);
  }
  __syncthreads();
  {
    int c = tid & 63, w0 = (tid >> 6) * 16;
    unsigned short* op = uvT + ((size_t)bh * 64 + c) * 64 + w0;
    unsigned short vals[16];
#pragma unroll
    for (int j = 0; j < 16; j++) vals[j] = f2bf(Tv[w0 + j][c]);
    *(short8*)op = *(short8*)&vals[0];
    *(short8*)(op + 8) = *(short8*)&vals[8];
  }
}

// --------------------------- window attention ------------------------------
// MFMA version: 1024 blocks = (bh, tile of 128 q-rows), 4 waves, barrier-free.
// scores = q2b @ ukb^T / 8; softmax over w (64); out = A @ uv.
__global__ __launch_bounds__(256) void window_attn2(
    const unsigned short* __restrict__ q2b, const unsigned short* __restrict__ ukb,
    const unsigned short* __restrict__ uvT, unsigned short* __restrict__ win) {
  __shared__ unsigned short S_l[128 * 64];   // 16 KB, swizzled softmax weights
  const int tid = threadIdx.x, lane = tid & 63, w = tid >> 6;
  const int m15 = lane & 15, quad = lane >> 4;
  const int bh = blockIdx.x >> 4, tile = blockIdx.x & 15;
  const int b = bh >> 4, hh = bh & 15;
  const int t0 = tile * 128 + w * 32;        // this wave's 32 rows (within b)
  const unsigned short* ukbase = ukb + (size_t)bh * 64 * 64;
  const unsigned short* uvbase = uvT + (size_t)bh * 64 * 64;
  // ---- QK^T (K=64) ----
  f32x4 accS[2][4] = {};
#pragma unroll
  for (int ks = 0; ks < 2; ks++) {
    short8 aF[2], bF[4];
#pragma unroll
    for (int mi = 0; mi < 2; mi++)
      aF[mi] = *(const short8*)(q2b + ((size_t)(b * LL + t0 + mi * 16 + m15)) * DD +
                                hh * 64 + ks * 32 + quad * 8);
#pragma unroll
    for (int ni = 0; ni < 4; ni++)
      bF[ni] = *(const short8*)(ukbase + ((size_t)(ni * 16 + m15)) * 64 + ks * 32 + quad * 8);
#pragma unroll
    for (int mi = 0; mi < 2; mi++)
#pragma unroll
      for (int ni = 0; ni < 4; ni++)
        accS[mi][ni] = __builtin_amdgcn_mfma_f32_16x16x32_bf16(
            aF[mi], bF[ni], accS[mi][ni], 0, 0, 0);
  }
  // ---- wave-parallel softmax over w (rows live across 16 lanes x 4 ni) ----
#pragma unroll
  for (int mi = 0; mi < 2; mi++) {
#pragma unroll
    for (int rr = 0; rr < 4; rr++) {
      float s0 = accS[mi][0][rr] * 0.125f;
      float s1 = accS[mi][1][rr] * 0.125f;
      float s2 = accS[mi][2][rr] * 0.125f;
      float s3 = accS[mi][3][rr] * 0.125f;
      float m = fmaxf(fmaxf(s0, s1), fmaxf(s2, s3));
      m = fmaxf(m, __shfl_xor(m, 1));
      m = fmaxf(m, __shfl_xor(m, 2));
      m = fmaxf(m, __shfl_xor(m, 4));
      m = fmaxf(m, __shfl_xor(m, 8));
      float p0 = __expf(s0 - m), p1 = __expf(s1 - m);
      float p2 = __expf(s2 - m), p3 = __expf(s3 - m);
      float l = p0 + p1 + p2 + p3;
      l += __shfl_xor(l, 1);
      l += __shfl_xor(l, 2);
      l += __shfl_xor(l, 4);
      l += __shfl_xor(l, 8);
      float inv = 1.0f / l;
      int tl = w * 32 + mi * 16 + quad * 4 + rr;
      int t7 = tl & 7;
      float pr[4] = {p0 * inv, p1 * inv, p2 * inv, p3 * inv};
#pragma unroll
      for (int ni = 0; ni < 4; ni++) {
        int s = ni * 16 + m15;
        S_l[tl * 64 + ((s >> 3) ^ t7) * 8 + (s & 7)] = f2bf(pr[ni]);
      }
    }
  }
  // ---- PV (K=64) — same-wave LDS RAW, no barrier ----
  f32x4 accO[2][4] = {};
#pragma unroll
  for (int ks = 0; ks < 2; ks++) {
    short8 aF[2], bF[4];
#pragma unroll
    for (int mi = 0; mi < 2; mi++) {
      int tl = w * 32 + mi * 16 + m15;
      int g = (ks * 4 + quad) ^ (tl & 7);
      aF[mi] = *(const short8*)&S_l[tl * 64 + g * 8];
    }
#pragma unroll
    for (int ni = 0; ni < 4; ni++)
      bF[ni] = *(const short8*)(uvbase + ((size_t)(ni * 16 + m15)) * 64 + ks * 32 + quad * 8);
#pragma unroll
    for (int mi = 0; mi < 2; mi++)
#pragma unroll
      for (int ni = 0; ni < 4; ni++)
        accO[mi][ni] = __builtin_amdgcn_mfma_f32_16x16x32_bf16(
            aF[mi], bF[ni], accO[mi][ni], 0, 0, 0);
  }
  // ---- epilogue ----
#pragma unroll
  for (int mi = 0; mi < 2; mi++) {
#pragma unroll
    for (int rr = 0; rr < 4; rr++) {
      int row = t0 + mi * 16 + quad * 4 + rr;
      unsigned short* op = win + ((size_t)(b * LL + row)) * DD + hh * 64;
#pragma unroll
      for (int ni = 0; ni < 4; ni++)
        op[ni * 16 + m15] = f2bf(accO[mi][ni][rr]);
    }
  }
}

// ------------------------------ LayerNorm ----------------------------------
__global__ __launch_bounds__(256) void ln_add(
    const float* __restrict__ A, const float* __restrict__ Bm,
    const float* __restrict__ gamma, const float* __restrict__ beta,
    float* __restrict__ out, unsigned short* __restrict__ outb) {
  const int row = blockIdx.x, tid = threadIdx.x;
  float4 va = ((const float4*)(A + (size_t)row * DD))[tid];
  float4 vb = ((const float4*)(Bm + (size_t)row * DD))[tid];
  float4 s4 = f4(va.x + vb.x, va.y + vb.y, va.z + vb.z, va.w + vb.w);
  float s = s4.x + s4.y + s4.z + s4.w;
  float ss = s4.x * s4.x + s4.y * s4.y + s4.z * s4.z + s4.w * s4.w;
  for (int o = 32; o; o >>= 1) { s += __shfl_xor(s, o); ss += __shfl_xor(ss, o); }
  __shared__ float red[8];
  int wid = tid >> 6;
  if ((tid & 63) == 0) { red[wid * 2] = s; red[wid * 2 + 1] = ss; }
  __syncthreads();
  float tot = red[0] + red[2] + red[4] + red[6];
  float tots = red[1] + red[3] + red[5] + red[7];
  float mu = tot * (1.0f / 1024.0f);
  float var = tots * (1.0f / 1024.0f) - mu * mu;
  float rstd = rsqrtf(var + 1e-5f);
  float4 g = ((const float4*)gamma)[tid];
  float4 be = ((const float4*)beta)[tid];
  float4 o = f4((s4.x - mu) * rstd * g.x + be.x, (s4.y - mu) * rstd * g.y + be.y,
                (s4.z - mu) * rstd * g.z + be.z, (s4.w - mu) * rstd * g.w + be.w);
  ((float4*)(out + (size_t)row * DD))[tid] = o;
  if (outb) {
    ushort4 r;
    r.x = f2bf(o.x); r.y = f2bf(o.y); r.z = f2bf(o.z); r.w = f2bf(o.w);
    ((ushort4*)(outb + (size_t)row * DD))[tid] = r;
  }
}

// ------------------------------ launch -------------------------------------
extern "C" void kernel_launch(void* const* d_in, const int* in_sizes, int n_in,
                              void* d_out, int out_size, void* d_ws, size_t ws_size,
                              hipStream_t stream) {
  (void)in_sizes; (void)n_in; (void)out_size; (void)ws_size;
  const float* x      = (const float*)d_in[0];
  const float* kv0    = (const float*)d_in[1];
  const float* kst0   = (const float*)d_in[2];
  const float* kbuf   = (const float*)d_in[3];
  const float* vbufw  = (const float*)d_in[4];
  const float* Wq_lin = (const float*)d_in[5];
  const float* bq_lin = (const float*)d_in[6];
  const float* Wk_lin = (const float*)d_in[7];
  const float* bk_lin = (const float*)d_in[8];
  const float* Wv_lin = (const float*)d_in[9];
  const float* bv_lin = (const float*)d_in[10];
  const float* Wo_lin = (const float*)d_in[11];
  const float* bo_lin = (const float*)d_in[12];
  const float* Wq     = (const float*)d_in[13];
  const float* bq     = (const float*)d_in[14];
  const float* Wk     = (const float*)d_in[15];
  const float* bk     = (const float*)d_in[16];
  const float* Wv     = (const float*)d_in[17];
  const float* bv     = (const float*)d_in[18];
  const float* Wo     = (const float*)d_in[19];
  const float* bo     = (const float*)d_in[20];
  const float* gamma  = (const float*)d_in[21];
  const float* beta   = (const float*)d_in[22];

  float* out = (float*)d_out;
  float* kv_out  = out + 8388608;
  float* kst_out = out + 8388608 + 1118208;

  float* ws = (float*)d_ws;
  const size_t MF = 1024 * 1024;
  // float-offset layout (lifetimes in comments)
  unsigned short* qlin_b = (unsigned short*)(ws);              // [0,1)  until phaseC
  unsigned short* klin_b = (unsigned short*)(ws + 1 * MF);     // [1,2)  until phaseC
  unsigned short* v_b    = (unsigned short*)(ws + 2 * MF);     // [2,6)  until transV
  unsigned short* vT     = (unsigned short*)(ws + 6 * MF);     // [6,10) until phaseC
  unsigned short* KVc_t  = (unsigned short*)(ws + 10 * MF);    // [10,19) A->B
  unsigned short* kstc   = (unsigned short*)(ws + 19 * MF);    // [19,19.15) A->B
  unsigned short* KVp_t  = (unsigned short*)(ws + 20 * MF);    // [20,29) B->C
  unsigned short* kstp   = (unsigned short*)(ws + 29 * MF);    // [29,29.15) B->C
  unsigned short* x_bf   = (unsigned short*)(ws + 30 * MF);    // [30,34) until v GEMM
  unsigned short* outs_bf = (unsigned short*)(ws + 2 * MF);    // [2,6)  C->O1 (v_b dead)
  float* tmp  = ws + 10 * MF;                                  // [10,18) O1->ln (KVc_t dead)
  float* x1   = ws + 20 * MF;                                  // [20,28) (KVp_t dead)
  unsigned short* x1b = (unsigned short*)(ws + 30 * MF);       // [30,32) (x_bf dead)
  unsigned short* q2b = (unsigned short*)ws;                   // [0,4)  (qlin/klin/outs/vT dead)
  unsigned short* winb = (unsigned short*)(ws + 8 * MF);       // [8,12) (tmp dead)
  float* tmp2 = ws + 12 * MF;                                  // [12,20)
  float* klast = ws + 34 * MF;                                 // 4096 floats
  float* vlast = klast + 4096;                                 // 4096 floats
  unsigned short* ukb = (unsigned short*)(ws + 34 * MF + 8192);      // 64*64*64 bf16
  unsigned short* uvTw = ukb + 262144;                               // 64*64*64 bf16
  unsigned short* WtQL = (unsigned short*)(ws + 35 * MF);
  unsigned short* WtKL = WtQL + 262144;
  unsigned short* WtVL = WtQL + 524288;
  unsigned short* WtO1 = WtQL + 1572864;
  unsigned short* WtQ2 = WtQL + 2621440;
  unsigned short* WtO2 = WtQL + 3670016;

  dim3 blk(256);
  cast_bf16<<<8192, blk, 0, stream>>>(x, x_bf, 2097152);
  castT<<<dim3(16, 4), blk, 0, stream>>>(Wq_lin, WtQL, 1024, 256);
  castT<<<dim3(16, 4), blk, 0, stream>>>(Wk_lin, WtKL, 1024, 256);
  castT<<<dim3(16, 16), blk, 0, stream>>>(Wv_lin, WtVL, 1024, 1024);
  castT<<<dim3(16, 16), blk, 0, stream>>>(Wo_lin, WtO1, 1024, 1024);
  castT<<<dim3(16, 16), blk, 0, stream>>>(Wq, WtQ2, 1024, 1024);
  castT<<<dim3(16, 16), blk, 0, stream>>>(Wo, WtO2, 1024, 1024);
  gemm_mfma<<<dim3(64, 2), blk, 0, stream>>>(x_bf, WtQL, bq_lin, (float*)0, qlin_b, 8192, 256, 1024);
  gemm_mfma<<<dim3(64, 2), blk, 0, stream>>>(x_bf, WtKL, bk_lin, (float*)0, klin_b, 8192, 256, 1024);
  gemm_mfma<<<dim3(64, 8), blk, 0, stream>>>(x_bf, WtVL, bv_lin, (float*)0, v_b, 8192, 1024, 1024);
  transV<<<2048, blk, 0, stream>>>(v_b, vT);
  phaseA2<<<1024, blk, 0, stream>>>(klin_b, vT, KVc_t, kstc);
  phaseB3<<<585, blk, 0, stream>>>(KVc_t, kstc, kv0, kst0, KVp_t, kstp, kv_out, kst_out);
  phaseC4<<<1024, blk, 0, stream>>>(qlin_b, klin_b, vT, KVp_t, kstp, outs_bf);
  gemm_mfma<<<dim3(64, 8), blk, 0, stream>>>(outs_bf, WtO1, bo_lin, tmp, (unsigned short*)0, 8192, 1024, 1024);
  ln_add<<<8192, blk, 0, stream>>>(x, tmp, gamma, beta, x1, x1b);
  gemm_mfma<<<dim3(64, 8), blk, 0, stream>>>(x1b, WtQ2, bq, (float*)0, q2b, 8192, 1024, 1024);
  lastrow_init<<<32, blk, 0, stream>>>(bk, bv, klast, vlast);
  lastrow_qkv2<<<512, blk, 0, stream>>>(x1, Wk, Wv, klast, vlast);
  prep_window<<<64, blk, 0, stream>>>(kbuf, vbufw, klast, vlast, ukb, uvTw);
  window_attn2<<<1024, blk, 0, stream>>>(q2b, ukb, uvTw, winb);
  gemm_mfma<<<dim3(64, 8), blk, 0, stream>>>(winb, WtO2, bo, tmp2, (unsigned short*)0, 8192, 1024, 1024);
  ln_add<<<8192, blk, 0, stream>>>(x1, tmp2, gamma, beta, out, (unsigned short*)0);
}

// Round 5
// 388.904 us; speedup vs baseline: 1.3383x; 1.1402x over previous
//
#include <hip/hip_runtime.h>
#include <math.h>

// ---------------------------------------------------------------------------
// BasedBlock: B=4 L=2048 d=1024 h=16 f=16 hd=64 w=64, D=1+f+f*f=273
// Round 10: long-tail consolidation.
//   * QKV fused into one N=1536 GEMM (qkv_b[t][1536] = Q|K|V), A read once
//   * castT_all: all 6 weight transposes + bias concat in ONE launch
//   * x1 fp32 eliminated (x1b bf16 everywhere); tmp/tmp2 stored bf16
//   * ln_add2 takes fp32-or-bf16 A, bf16 Bm, optional fp32/bf16 outputs
//   ~160 MB HBM traffic + ~7 launches removed.
// ---------------------------------------------------------------------------

#define LL 2048
#define DD 1024
#define DFEAT 273
#define NC 16
#define CHUNK 128
#define QKVN 1536

typedef __attribute__((ext_vector_type(8))) short short8;
typedef __attribute__((ext_vector_type(4))) float f32x4;

#define SQ 0.42044820762685725f   // sqrt(1/(sqrt(2)*sqrt(16)))
#define LF 1.18920711500272107f   // 0.5 / SQ

__device__ __forceinline__ float4 f4(float a, float b, float c, float d) {
  float4 r; r.x = a; r.y = b; r.z = c; r.w = d; return r;
}

__device__ __forceinline__ unsigned short f2bf(float f) {
  union { float f; unsigned u; } v; v.f = f;
  unsigned r = v.u + 0x7fffu + ((v.u >> 16) & 1u);
  return (unsigned short)(r >> 16);
}

__device__ __forceinline__ float bf2f(unsigned short u) {
  union { unsigned u; float f; } v; v.u = ((unsigned)u) << 16; return v.f;
}

// --------------------------- cast kernels ----------------------------------
__global__ __launch_bounds__(256) void cast_bf16(
    const float* __restrict__ in, unsigned short* __restrict__ o, int n4) {
  int i = blockIdx.x * 256 + threadIdx.x;
  if (i < n4) {
    float4 v = ((const float4*)in)[i];
    ushort4 r;
    r.x = f2bf(v.x); r.y = f2bf(v.y); r.z = f2bf(v.z); r.w = f2bf(v.w);
    ((ushort4*)o)[i] = r;
  }
}

// All six W[1024][N] fp32 -> Wt[N][1024] bf16 transposes in one launch.
// Blocks: [0,64) QL, [64,128) KL, [128,384) V, [384,640) O1, [640,896) Q2,
// [896,1152) O2. Blocks 0..5 also concat biases into bqkv[1536].
__global__ __launch_bounds__(256) void castT_all(
    const float* __restrict__ Wql, const float* __restrict__ Wkl,
    const float* __restrict__ Wvl, const float* __restrict__ Wo1,
    const float* __restrict__ Wq2, const float* __restrict__ Wo2,
    const float* __restrict__ bql, const float* __restrict__ bkl,
    const float* __restrict__ bvl,
    unsigned short* __restrict__ Wcomb, unsigned short* __restrict__ WtO1,
    unsigned short* __restrict__ WtQ2, unsigned short* __restrict__ WtO2,
    float* __restrict__ bqkv) {
  __shared__ float t[64][65];
  const int blk = blockIdx.x, tid = threadIdx.x;
  if (blk < 6) {
    int i = blk * 256 + tid;   // 0..1535
    float v = (i < 256) ? bql[i] : (i < 512) ? bkl[i - 256] : bvl[i - 512];
    bqkv[i] = v;
  }
  const float* W; unsigned short* Wt; int N, t0;
  if (blk < 64)       { W = Wql; Wt = Wcomb;               N = 256;  t0 = blk; }
  else if (blk < 128) { W = Wkl; Wt = Wcomb + 256 * 1024;  N = 256;  t0 = blk - 64; }
  else if (blk < 384) { W = Wvl; Wt = Wcomb + 512 * 1024;  N = 1024; t0 = blk - 128; }
  else if (blk < 640) { W = Wo1; Wt = WtO1;                N = 1024; t0 = blk - 384; }
  else if (blk < 896) { W = Wq2; Wt = WtQ2;                N = 1024; t0 = blk - 640; }
  else                { W = Wo2; Wt = WtO2;                N = 1024; t0 = blk - 896; }
  const int nt = N >> 6;
  const int k0 = (t0 / nt) * 64, n0 = (t0 % nt) * 64;
#pragma unroll
  for (int p = 0; p < 16; p++) {
    int idx = p * 256 + tid;
    int r = idx >> 6, c = idx & 63;
    t[r][c] = W[(size_t)(k0 + r) * N + n0 + c];
  }
  __syncthreads();
#pragma unroll
  for (int p = 0; p < 16; p++) {
    int idx = p * 256 + tid;
    int rn = idx >> 6, ck = idx & 63;
    Wt[(size_t)(n0 + rn) * 1024 + k0 + ck] = f2bf(t[ck][rn]);
  }
}

// --------------------------- MFMA GEMM -------------------------------------
__global__ __launch_bounds__(256) void gemm_mfma(
    const unsigned short* __restrict__ A, const unsigned short* __restrict__ Bt,
    const float* __restrict__ bias, float* __restrict__ C,
    unsigned short* __restrict__ Cb, int M, int N, int K) {
  __shared__ unsigned short As[128 * 64];
  __shared__ unsigned short Bs[128 * 64];
  const int tid = threadIdx.x;
  const int lane = tid & 63, w = tid >> 6;
  const int row0 = blockIdx.x * 128, col0 = blockIdx.y * 128;
  const int wm0 = (w & 1) * 64, wn0 = (w >> 1) * 64;
  const int lr = lane >> 3;
  const int gc = (lane & 7) ^ lr;
  const unsigned short* aP = A + (size_t)(row0 + w * 32 + lr) * K + gc * 8;
  const unsigned short* bP = Bt + (size_t)(col0 + w * 32 + lr) * K + gc * 8;
  unsigned short* asW = As + w * 2048;
  unsigned short* bsW = Bs + w * 2048;
  const int m15 = lane & 15, quad = lane >> 4;
  f32x4 acc[4][4] = {};
  for (int k0 = 0; k0 < K; k0 += 64) {
#pragma unroll
    for (int i = 0; i < 4; i++) {
      __builtin_amdgcn_global_load_lds(
          (const __attribute__((address_space(1))) unsigned int*)(const void*)(aP + (size_t)(i * 8) * K + k0),
          (__attribute__((address_space(3))) unsigned int*)(void*)(asW + i * 512), 16, 0, 0);
      __builtin_amdgcn_global_load_lds(
          (const __attribute__((address_space(1))) unsigned int*)(const void*)(bP + (size_t)(i * 8) * K + k0),
          (__attribute__((address_space(3))) unsigned int*)(void*)(bsW + i * 512), 16, 0, 0);
    }
    __syncthreads();
#pragma unroll
    for (int ks = 0; ks < 2; ks++) {
      short8 aF[4], bF[4];
#pragma unroll
      for (int mi = 0; mi < 4; mi++) {
        int r = wm0 + mi * 16 + m15;
        int g = (ks * 4 + quad) ^ (r & 7);
        aF[mi] = *(const short8*)(As + r * 64 + g * 8);
      }
#pragma unroll
      for (int ni = 0; ni < 4; ni++) {
        int r = wn0 + ni * 16 + m15;
        int g = (ks * 4 + quad) ^ (r & 7);
        bF[ni] = *(const short8*)(Bs + r * 64 + g * 8);
      }
#pragma unroll
      for (int mi = 0; mi < 4; mi++)
#pragma unroll
        for (int ni = 0; ni < 4; ni++)
          acc[mi][ni] = __builtin_amdgcn_mfma_f32_16x16x32_bf16(
              aF[mi], bF[ni], acc[mi][ni], 0, 0, 0);
    }
    __syncthreads();
  }
#pragma unroll
  for (int mi = 0; mi < 4; mi++)
#pragma unroll
    for (int ni = 0; ni < 4; ni++) {
      int col = col0 + wn0 + ni * 16 + m15;
      float bb = bias[col];
#pragma unroll
      for (int r = 0; r < 4; r++) {
        int row = row0 + wm0 + mi * 16 + quad * 4 + r;
        float val = acc[mi][ni][r] + bb;
        if (Cb) Cb[(size_t)row * N + col] = f2bf(val);
        else C[(size_t)row * N + col] = val;
      }
    }
}

// ------------------------------ transV -------------------------------------
// qkv[t][512 + h*64+c] -> vT[bh][c][t]
__global__ __launch_bounds__(256) void transV(
    const unsigned short* __restrict__ qkv, unsigned short* __restrict__ vT) {
  __shared__ unsigned short Tv[64][72];
  const int blk = blockIdx.x;
  const int bh = blk >> 5, tt = blk & 31;
  const int b = bh >> 4, hh = bh & 15;
  const int t0 = tt * 64;
  const int tid = threadIdx.x;
  {
    int t = tid >> 2, cs = tid & 3;
    const unsigned short* p = qkv + ((size_t)(b * LL + t0 + t)) * QKVN + 512 + hh * 64 + cs * 16;
    *(short8*)&Tv[t][cs * 16] = *(const short8*)p;
    *(short8*)&Tv[t][cs * 16 + 8] = *(const short8*)(p + 8);
  }
  __syncthreads();
  {
    int c = tid & 63, ts = tid >> 6;
    unsigned short vals[16];
#pragma unroll
    for (int j = 0; j < 16; j++) vals[j] = Tv[ts * 16 + j][c];
    unsigned short* op = vT + ((size_t)bh * 64 + c) * LL + t0 + ts * 16;
    *(short8*)op = *(short8*)&vals[0];
    *(short8*)(op + 8) = *(short8*)&vals[8];
  }
}

// ------------------------------ phase A ------------------------------------
// KVc_t[bh][ck][c][f] = sum_t Kf[t][f] V[t][c] (bf16); kstc[bh][ck][f].
__global__ __launch_bounds__(256) void phaseA2(
    const unsigned short* __restrict__ qkv, const unsigned short* __restrict__ vT,
    unsigned short* __restrict__ KVc_t, unsigned short* __restrict__ kstc) {
  __shared__ unsigned short kT[16][136];   // kT[i][t] = bf16(k[t][i]*SQ)
  const int tid = threadIdx.x, lane = tid & 63, w = tid >> 6;
  const int m15 = lane & 15, quad = lane >> 4;
  const int bh = blockIdx.x >> 4, ck = blockIdx.x & 15;
  const int b = bh >> 4, hh = bh & 15;
  const int t0 = ck * CHUNK;
  {
    int r = tid >> 1, half = tid & 1;
    short8 kv = *(const short8*)(qkv + ((size_t)(b * LL + t0 + r)) * QKVN + 256 + hh * 16 + half * 8);
#pragma unroll
    for (int j = 0; j < 8; j++)
      kT[half * 8 + j][r] = f2bf(bf2f(((unsigned short*)&kv)[j]) * SQ);
  }
  __syncthreads();
  short8 ones8 = {16256, 16256, 16256, 16256, 16256, 16256, 16256, 16256};
  short8 zer8 = {0, 0, 0, 0, 0, 0, 0, 0};
  f32x4 acc[5][5] = {};
  const unsigned short* vbase = vT + (size_t)bh * 64 * LL + t0;
#pragma unroll
  for (int ks = 0; ks < 4; ++ks) {
    const int tt = ks * 32 + quad * 8;
    short8 aF[5], bF[5];
#pragma unroll
    for (int mi = 0; mi < 5; mi++) {
      int r = (w * 5 + mi) * 16 + m15;
      short8 av;
      unsigned short* pv = (unsigned short*)&av;
      if (r == 0) {
        av = ones8;
      } else if (r < 17) {
        short8 k1 = *(const short8*)&kT[r - 1][tt];
#pragma unroll
        for (int j = 0; j < 8; j++) pv[j] = f2bf(bf2f(((unsigned short*)&k1)[j]) * LF);
      } else if (r < DFEAT) {
        int ij = r - 17;
        short8 k1 = *(const short8*)&kT[ij >> 4][tt];
        short8 k2 = *(const short8*)&kT[ij & 15][tt];
#pragma unroll
        for (int j = 0; j < 8; j++)
          pv[j] = f2bf(bf2f(((unsigned short*)&k1)[j]) * bf2f(((unsigned short*)&k2)[j]));
      } else {
        av = zer8;
      }
      aF[mi] = av;
    }
#pragma unroll
    for (int ni = 0; ni < 4; ni++)
      bF[ni] = *(const short8*)(vbase + ((size_t)(ni * 16 + m15)) * LL + tt);
    bF[4] = (m15 == 0) ? ones8 : zer8;
#pragma unroll
    for (int mi = 0; mi < 5; mi++)
#pragma unroll
      for (int ni = 0; ni < 5; ni++)
        acc[mi][ni] = __builtin_amdgcn_mfma_f32_16x16x32_bf16(
            aF[mi], bF[ni], acc[mi][ni], 0, 0, 0);
  }
  const size_t cb = ((size_t)bh * NC + ck) * (64 * 288);
  const size_t kb = ((size_t)bh * NC + ck) * 288;
#pragma unroll
  for (int mi = 0; mi < 5; mi++) {
    int fb = (w * 5 + mi) * 16 + quad * 4;
    if (fb < 288) {
#pragma unroll
      for (int ni = 0; ni < 4; ni++) {
        int c = ni * 16 + m15;
        ushort4 sv;
        sv.x = f2bf(acc[mi][ni][0]); sv.y = f2bf(acc[mi][ni][1]);
        sv.z = f2bf(acc[mi][ni][2]); sv.w = f2bf(acc[mi][ni][3]);
        *(ushort4*)(KVc_t + cb + (size_t)c * 288 + fb) = sv;
      }
      if (m15 == 0) {
        ushort4 sv;
        sv.x = f2bf(acc[mi][4][0]); sv.y = f2bf(acc[mi][4][1]);
        sv.z = f2bf(acc[mi][4][2]); sv.w = f2bf(acc[mi][4][3]);
        *(ushort4*)(kstc + kb + fb) = sv;
      }
    }
  }
}

// ------------------------------ phase B ------------------------------------
__global__ __launch_bounds__(256) void phaseB3(
    const unsigned short* __restrict__ KVc_t, const unsigned short* __restrict__ kstc,
    const float* __restrict__ kv0, const float* __restrict__ kst0,
    unsigned short* __restrict__ KVp_t, unsigned short* __restrict__ kstp,
    float* __restrict__ kv_out, float* __restrict__ kst_out) {
  const int tid = threadIdx.x;
  if (blockIdx.x < 576) {
    int gid = blockIdx.x * 256 + tid;
    int bh = gid / 2304, rem = gid - bh * 2304;
    int c = rem / 36, fg = rem - c * 36;
    int f0 = fg * 8;
    float acc[8];
#pragma unroll
    for (int j = 0; j < 8; j++) {
      int f = f0 + j;
      acc[j] = (f < DFEAT) ? kv0[((size_t)bh * DFEAT + f) * 64 + c] : 0.0f;
    }
    size_t base = ((size_t)bh * NC) * (64 * 288) + (size_t)c * 288 + f0;
    for (int ck = 0; ck < NC; ck++) {
      size_t idx = base + (size_t)ck * (64 * 288);
      short8 t = *(const short8*)(KVc_t + idx);
      unsigned short ov[8];
#pragma unroll
      for (int j = 0; j < 8; j++) {
        ov[j] = f2bf(acc[j]);
        acc[j] += bf2f(((unsigned short*)&t)[j]);
      }
      *(short8*)(KVp_t + idx) = *(short8*)ov;
    }
#pragma unroll
    for (int j = 0; j < 8; j++) {
      int f = f0 + j;
      if (f < DFEAT) kv_out[((size_t)bh * DFEAT + f) * 64 + c] = acc[j];
    }
  } else {
    int idx0 = (blockIdx.x - 576) * 256 + tid;   // 0..2303
    int bh = idx0 / 36, fg = idx0 - bh * 36;
    int f0 = fg * 8;
    float acc[8];
#pragma unroll
    for (int j = 0; j < 8; j++) {
      int f = f0 + j;
      acc[j] = (f < DFEAT) ? kst0[bh * DFEAT + f] : 0.0f;
    }
    for (int ck = 0; ck < NC; ck++) {
      size_t idx = ((size_t)bh * NC + ck) * 288 + f0;
      short8 t = *(const short8*)(kstc + idx);
      unsigned short ov[8];
#pragma unroll
      for (int j = 0; j < 8; j++) {
        ov[j] = f2bf(acc[j]);
        acc[j] += bf2f(((unsigned short*)&t)[j]);
      }
      *(short8*)(kstp + idx) = *(short8*)ov;
    }
#pragma unroll
    for (int j = 0; j < 8; j++) {
      int f = f0 + j;
      if (f < DFEAT) kst_out[bh * DFEAT + f] = acc[j];
    }
  }
}

// ------------------------------ phase C ------------------------------------
// 256-thread blocks, grid 1024 = (bh, ck); wave w = causal quarter qw.
__global__ __launch_bounds__(256) void phaseC4(
    const unsigned short* __restrict__ qkv,
    const unsigned short* __restrict__ vT, const unsigned short* __restrict__ KVp_t,
    const unsigned short* __restrict__ kstp, unsigned short* __restrict__ outs) {
  __shared__ float qs[4][32][36];              // per-wave: [0..15]=q*SQ, [16..31]=rot dup
  __shared__ unsigned short S_l[4][32 * 128];  // per-wave swizzled intra scores
  const int tid = threadIdx.x, lane = tid & 63, w = tid >> 6;
  const int m15 = lane & 15, quad = lane >> 4;
  const int bh = blockIdx.x >> 4, ck = blockIdx.x & 15;
  const int qw = w;
  const int b = bh >> 4, hh = bh & 15;
  const int t0 = ck * CHUNK;
  const int tr0 = qw * 32;
  float (*qsw)[36] = qs[w];
  unsigned short* Sw = S_l[w];
  const unsigned short* qbase = qkv + ((size_t)(b * LL + t0 + tr0)) * QKVN + hh * 16;
  const unsigned short* kbase = qkv + ((size_t)(b * LL + t0)) * QKVN + 256 + hh * 16;
  // ---- fill qs (wave-private rows, no barrier) ----
  {
    int r = lane >> 1, h8 = lane & 1;
    short8 qv = *(const short8*)(qbase + (size_t)r * QKVN + h8 * 8);
    float qf[8];
#pragma unroll
    for (int j = 0; j < 8; j++) qf[j] = bf2f(((unsigned short*)&qv)[j]) * SQ;
    *(float4*)&qsw[r][h8 * 8] = f4(qf[0], qf[1], qf[2], qf[3]);
    *(float4*)&qsw[r][h8 * 8 + 4] = f4(qf[4], qf[5], qf[6], qf[7]);
#pragma unroll
    for (int j = 0; j < 8; j++)
      qsw[r][16 + ((h8 * 8 + j + 9) & 15)] = qf[j];   // rot[m] = q[(m+7)&15]
  }
  short8 ones8 = {16256, 16256, 16256, 16256, 16256, 16256, 16256, 16256};
  short8 zer8 = {0, 0, 0, 0, 0, 0, 0, 0};
  f32x4 acc[2][5] = {};
  const unsigned short* KVb = KVp_t + ((size_t)(bh * NC + ck)) * (64 * 288);
  const unsigned short* kstb = kstp + ((size_t)(bh * NC + ck)) * 288;
  // ---- pass 1: inter (Qf @ KV'), K = 288 ----
#pragma unroll
  for (int ks = 0; ks < 9; ++ks) {
    const int fs = ks * 32 + quad * 8;
    short8 aF[2], bF[5];
#pragma unroll
    for (int ni = 0; ni < 4; ni++)
      bF[ni] = *(const short8*)(KVb + ((size_t)(ni * 16 + m15)) * 288 + fs);
    bF[4] = (m15 == 0) ? *(const short8*)(kstb + fs) : zer8;
#pragma unroll
    for (int mi = 0; mi < 2; mi++) {
      const float* qr = &qsw[mi * 16 + m15][0];
      unsigned short pv[8];
      if (ks == 0) {
        float qr0 = qr[0];
#pragma unroll
        for (int j = 0; j < 8; j++) {
          int f = (quad << 3) + j;
          int fl = f - 1; fl = fl < 0 ? 0 : fl;
          int fm = f - 17; fm = fm < 0 ? 0 : fm;     // < 16 here
          float lin = qr[fl] * LF;
          float prod = qr0 * qr[fm];
          float val = (f == 0) ? 1.0f : ((f < 17) ? lin : prod);
          pv[j] = f2bf(val);
        }
      } else {
        int base = fs - 17;                 // >= 15
        int i0 = base >> 4;
        float qi0 = qr[i0];
        float qi1 = qr[i0 + 1];
        const float* qv = qr + 16 + (base & 8);   // aligned 32B window (rot dup)
        float qj[8];
        *(float4*)&qj[0] = *(const float4*)qv;
        *(float4*)&qj[4] = *(const float4*)(qv + 4);
        float qiB = (quad & 1) ? qi0 : qi1;
#pragma unroll
        for (int j = 0; j < 8; j++) {
          float qi = (j == 0) ? qi0 : qiB;
          float val = qi * qj[j];
          if (ks == 8) val = ((quad << 3) + j < 17) ? val : 0.0f;  // f >= 273 -> 0
          pv[j] = f2bf(val);
        }
      }
      aF[mi] = *(short8*)pv;
    }
#pragma unroll
    for (int mi = 0; mi < 2; mi++)
#pragma unroll
      for (int ni = 0; ni < 5; ni++)
        acc[mi][ni] = __builtin_amdgcn_mfma_f32_16x16x32_bf16(
            aF[mi], bF[ni], acc[mi][ni], 0, 0, 0);
  }
  // ---- intra: u = q@k^T (K=16 pad 32) -> poly/mask -> S_l (wave-private) ----
  const int nsn = 2 * qw + 2;               // s covers [0, (qw+1)*32)
  {
    short8 aU[2], bU[8];
    aU[0] = (quad < 2) ? *(const short8*)(qbase + (size_t)m15 * QKVN + quad * 8) : zer8;
    aU[1] = (quad < 2) ? *(const short8*)(qbase + (size_t)(16 + m15) * QKVN + quad * 8) : zer8;
#pragma unroll
    for (int sn = 0; sn < 8; sn++) {
      if (sn < nsn) {
        int s = sn * 16 + m15;
        bU[sn] = (quad < 2) ? *(const short8*)(kbase + (size_t)s * QKVN + quad * 8) : zer8;
      }
    }
#pragma unroll
    for (int mi = 0; mi < 2; mi++) {
#pragma unroll
      for (int sn = 0; sn < 8; sn++) {
        if (sn < nsn) {
          f32x4 zz = {0.f, 0.f, 0.f, 0.f};
          f32x4 u = __builtin_amdgcn_mfma_f32_16x16x32_bf16(aU[mi], bU[sn], zz, 0, 0, 0);
          int s = sn * 16 + m15;
          int gRow = s >> 3;
#pragma unroll
          for (int rr = 0; rr < 4; rr++) {
            int tl = mi * 16 + quad * 4 + rr;        // local row 0..31
            int tc = tr0 + tl;                       // chunk-local row for mask
            float uu = u[rr];
            float sv = (s <= tc) ? fmaf(uu, fmaf(uu, 0.03125f, 0.25f), 1.0f) : 0.0f;
            int p = gRow ^ (tl & 7);
            Sw[tl * 128 + p * 8 + (s & 7)] = f2bf(sv);
          }
        }
      }
    }
  }
  // ---- pass 2: S @ V' — no barrier (same-wave LDS RAW) ----
  const unsigned short* vbase = vT + (size_t)bh * 64 * LL + t0;
#pragma unroll
  for (int ks = 0; ks < 4; ++ks) {
    if (ks <= qw) {
      const int tt = ks * 32 + quad * 8;
      short8 aF[2], bF[5];
#pragma unroll
      for (int mi = 0; mi < 2; mi++) {
        int tl = mi * 16 + m15;
        int p = (ks * 4 + quad) ^ (tl & 7);
        aF[mi] = *(const short8*)&Sw[tl * 128 + p * 8];
      }
#pragma unroll
      for (int ni = 0; ni < 4; ni++)
        bF[ni] = *(const short8*)(vbase + ((size_t)(ni * 16 + m15)) * LL + tt);
      bF[4] = (m15 == 0) ? ones8 : zer8;
#pragma unroll
      for (int mi = 0; mi < 2; mi++)
#pragma unroll
        for (int ni = 0; ni < 5; ni++)
          acc[mi][ni] = __builtin_amdgcn_mfma_f32_16x16x32_bf16(
              aF[mi], bF[ni], acc[mi][ni], 0, 0, 0);
    }
  }
  // ---- epilogue ----
#pragma unroll
  for (int mi = 0; mi < 2; mi++) {
#pragma unroll
    for (int rr = 0; rr < 4; rr++) {
      float den = __shfl(acc[mi][4][rr], (lane & 48));
      float inv = 1.0f / (den + 1e-6f);
      int tl = mi * 16 + quad * 4 + rr;
      unsigned short* op = outs + ((size_t)(b * LL + t0 + tr0 + tl)) * DD + hh * 64;
#pragma unroll
      for (int ni = 0; ni < 4; ni++)
        op[ni * 16 + m15] = f2bf(acc[mi][ni][rr] * inv);
    }
  }
}

// --------------------------- last-row k2/v2 --------------------------------
__global__ __launch_bounds__(256) void lastrow_init(
    const float* __restrict__ bk, const float* __restrict__ bv,
    float* __restrict__ klast, float* __restrict__ vlast) {
  int gid = blockIdx.x * 256 + threadIdx.x;   // grid 32 -> 8192
  int which = gid >> 12;
  int b = (gid >> 10) & 3;
  int n = gid & 1023;
  (which ? vlast : klast)[b * 1024 + n] = which ? bv[n] : bk[n];
}

// grid 512 = which(2) x nstrip(16) x kslice(16); bf16 x1 input.
__global__ __launch_bounds__(256) void lastrow_qkv2(
    const unsigned short* __restrict__ x1b,
    const float* __restrict__ Wk, const float* __restrict__ Wv,
    float* __restrict__ klast, float* __restrict__ vlast) {
  __shared__ float xs[4][64];
  __shared__ float red[4][4][64];
  const int blk = blockIdx.x;
  const int which = blk >> 8;
  const int nstrip = (blk >> 4) & 15;
  const int kslice = blk & 15;
  const int n0 = nstrip * 64, k0 = kslice * 64;
  const int tid = threadIdx.x;
  const int nn = tid & 63, p = tid >> 6;
  {
    int b = tid >> 6, k = tid & 63;
    xs[b][k] = bf2f(x1b[((size_t)(b * LL + LL - 1)) * DD + k0 + k]);
  }
  __syncthreads();
  const float* W = which ? Wv : Wk;
  float acc[4] = {};
#pragma unroll
  for (int i = 0; i < 16; i++) {
    int kk = p * 16 + i;
    float wv = W[(size_t)(k0 + kk) * 1024 + n0 + nn];
#pragma unroll
    for (int b = 0; b < 4; b++) acc[b] = fmaf(xs[b][kk], wv, acc[b]);
  }
#pragma unroll
  for (int b = 0; b < 4; b++) red[p][b][nn] = acc[b];
  __syncthreads();
  if (p == 0) {
    float* outp = which ? vlast : klast;
#pragma unroll
    for (int b = 0; b < 4; b++) {
      float s = red[0][b][nn] + red[1][b][nn] + red[2][b][nn] + red[3][b][nn];
      atomicAdd(outp + b * 1024 + n0 + nn, s);
    }
  }
}

// --------------------------- window prep -----------------------------------
__global__ __launch_bounds__(256) void prep_window(
    const float* __restrict__ kbuf, const float* __restrict__ vbufw,
    const float* __restrict__ klast, const float* __restrict__ vlast,
    unsigned short* __restrict__ ukb, unsigned short* __restrict__ uvT) {
  __shared__ float Tv[64][68];
  const int bh = blockIdx.x;
  const int b = bh >> 4, hh = bh & 15;
  const int tid = threadIdx.x;
  const int wi = tid >> 2, d0 = (tid & 3) * 16;
  {
    const float* kp = (wi < 63) ? (kbuf + ((size_t)hh * 64 + wi + 1) * 64 + d0)
                                : (klast + (size_t)b * 1024 + hh * 64 + d0);
    unsigned short* op = ukb + ((size_t)bh * 64 + wi) * 64 + d0;
#pragma unroll
    for (int j4 = 0; j4 < 4; j4++) {
      float4 v = *(const float4*)(kp + j4 * 4);
      ushort4 r;
      r.x = f2bf(v.x); r.y = f2bf(v.y); r.z = f2bf(v.z); r.w = f2bf(v.w);
      *(ushort4*)(op + j4 * 4) = r;
    }
  }
  {
    const float* vp = (wi < 63) ? (vbufw + ((size_t)hh * 64 + wi + 1) * 64 + d0)
                                : (vlast + (size_t)b * 1024 + hh * 64 + d0);
#pragma unroll
    for (int j4 = 0; j4 < 4; j4++)
      *(float4*)&Tv[wi][d0 + j4 * 4] = *(const float4*)(vp + j4 * 4);
  }
  __syncthreads();
  {
    int c = tid & 63, w0 = (tid >> 6) * 16;
    unsigned short* op = uvT + ((size_t)bh * 64 + c) * 64 + w0;
    unsigned short vals[16];
#pragma unroll
    for (int j = 0; j < 16; j++) vals[j] = f2bf(Tv[w0 + j][c]);
    *(short8*)op = *(short8*)&vals[0];
    *(short8*)(op + 8) = *(short8*)&vals[8];
  }
}

// --------------------------- window attention ------------------------------
__global__ __launch_bounds__(256) void window_attn2(
    const unsigned short* __restrict__ q2b, const unsigned short* __restrict__ ukb,
    const unsigned short* __restrict__ uvT, unsigned short* __restrict__ win) {
  __shared__ unsigned short S_l[128 * 64];   // 16 KB, swizzled softmax weights
  const int tid = threadIdx.x, lane = tid & 63, w = tid >> 6;
  const int m15 = lane & 15, quad = lane >> 4;
  const int bh = blockIdx.x >> 4, tile = blockIdx.x & 15;
  const int b = bh >> 4, hh = bh & 15;
  const int t0 = tile * 128 + w * 32;
  const unsigned short* ukbase = ukb + (size_t)bh * 64 * 64;
  const unsigned short* uvbase = uvT + (size_t)bh * 64 * 64;
  f32x4 accS[2][4] = {};
#pragma unroll
  for (int ks = 0; ks < 2; ks++) {
    short8 aF[2], bF[4];
#pragma unroll
    for (int mi = 0; mi < 2; mi++)
      aF[mi] = *(const short8*)(q2b + ((size_t)(b * LL + t0 + mi * 16 + m15)) * DD +
                                hh * 64 + ks * 32 + quad * 8);
#pragma unroll
    for (int ni = 0; ni < 4; ni++)
      bF[ni] = *(const short8*)(ukbase + ((size_t)(ni * 16 + m15)) * 64 + ks * 32 + quad * 8);
#pragma unroll
    for (int mi = 0; mi < 2; mi++)
#pragma unroll
      for (int ni = 0; ni < 4; ni++)
        accS[mi][ni] = __builtin_amdgcn_mfma_f32_16x16x32_bf16(
            aF[mi], bF[ni], accS[mi][ni], 0, 0, 0);
  }
#pragma unroll
  for (int mi = 0; mi < 2; mi++) {
#pragma unroll
    for (int rr = 0; rr < 4; rr++) {
      float s0 = accS[mi][0][rr] * 0.125f;
      float s1 = accS[mi][1][rr] * 0.125f;
      float s2 = accS[mi][2][rr] * 0.125f;
      float s3 = accS[mi][3][rr] * 0.125f;
      float m = fmaxf(fmaxf(s0, s1), fmaxf(s2, s3));
      m = fmaxf(m, __shfl_xor(m, 1));
      m = fmaxf(m, __shfl_xor(m, 2));
      m = fmaxf(m, __shfl_xor(m, 4));
      m = fmaxf(m, __shfl_xor(m, 8));
      float p0 = __expf(s0 - m), p1 = __expf(s1 - m);
      float p2 = __expf(s2 - m), p3 = __expf(s3 - m);
      float l = p0 + p1 + p2 + p3;
      l += __shfl_xor(l, 1);
      l += __shfl_xor(l, 2);
      l += __shfl_xor(l, 4);
      l += __shfl_xor(l, 8);
      float inv = 1.0f / l;
      int tl = w * 32 + mi * 16 + quad * 4 + rr;
      int t7 = tl & 7;
      float pr[4] = {p0 * inv, p1 * inv, p2 * inv, p3 * inv};
#pragma unroll
      for (int ni = 0; ni < 4; ni++) {
        int s = ni * 16 + m15;
        S_l[tl * 64 + ((s >> 3) ^ t7) * 8 + (s & 7)] = f2bf(pr[ni]);
      }
    }
  }
  f32x4 accO[2][4] = {};
#pragma unroll
  for (int ks = 0; ks < 2; ks++) {
    short8 aF[2], bF[4];
#pragma unroll
    for (int mi = 0; mi < 2; mi++) {
      int tl = w * 32 + mi * 16 + m15;
      int g = (ks * 4 + quad) ^ (tl & 7);
      aF[mi] = *(const short8*)&S_l[tl * 64 + g * 8];
    }
#pragma unroll
    for (int ni = 0; ni < 4; ni++)
      bF[ni] = *(const short8*)(uvbase + ((size_t)(ni * 16 + m15)) * 64 + ks * 32 + quad * 8);
#pragma unroll
    for (int mi = 0; mi < 2; mi++)
#pragma unroll
      for (int ni = 0; ni < 4; ni++)
        accO[mi][ni] = __builtin_amdgcn_mfma_f32_16x16x32_bf16(
            aF[mi], bF[ni], accO[mi][ni], 0, 0, 0);
  }
#pragma unroll
  for (int mi = 0; mi < 2; mi++) {
#pragma unroll
    for (int rr = 0; rr < 4; rr++) {
      int row = t0 + mi * 16 + quad * 4 + rr;
      unsigned short* op = win + ((size_t)(b * LL + row)) * DD + hh * 64;
#pragma unroll
      for (int ni = 0; ni < 4; ni++)
        op[ni * 16 + m15] = f2bf(accO[mi][ni][rr]);
    }
  }
}

// ------------------------------ LayerNorm ----------------------------------
// A = Af (fp32) or Ab (bf16); Bm = bf16; outputs optional.
__global__ __launch_bounds__(256) void ln_add2(
    const float* __restrict__ Af, const unsigned short* __restrict__ Ab,
    const unsigned short* __restrict__ Bmb,
    const float* __restrict__ gamma, const float* __restrict__ beta,
    float* __restrict__ out, unsigned short* __restrict__ outb) {
  const int row = blockIdx.x, tid = threadIdx.x;
  float a0, a1, a2, a3;
  if (Af) {
    float4 va = ((const float4*)(Af + (size_t)row * DD))[tid];
    a0 = va.x; a1 = va.y; a2 = va.z; a3 = va.w;
  } else {
    ushort4 ua = ((const ushort4*)(Ab + (size_t)row * DD))[tid];
    a0 = bf2f(ua.x); a1 = bf2f(ua.y); a2 = bf2f(ua.z); a3 = bf2f(ua.w);
  }
  ushort4 ub = ((const ushort4*)(Bmb + (size_t)row * DD))[tid];
  float4 s4 = f4(a0 + bf2f(ub.x), a1 + bf2f(ub.y), a2 + bf2f(ub.z), a3 + bf2f(ub.w));
  float s = s4.x + s4.y + s4.z + s4.w;
  float ss = s4.x * s4.x + s4.y * s4.y + s4.z * s4.z + s4.w * s4.w;
  for (int o = 32; o; o >>= 1) { s += __shfl_xor(s, o); ss += __shfl_xor(ss, o); }
  __shared__ float red[8];
  int wid = tid >> 6;
  if ((tid & 63) == 0) { red[wid * 2] = s; red[wid * 2 + 1] = ss; }
  __syncthreads();
  float tot = red[0] + red[2] + red[4] + red[6];
  float tots = red[1] + red[3] + red[5] + red[7];
  float mu = tot * (1.0f / 1024.0f);
  float var = tots * (1.0f / 1024.0f) - mu * mu;
  float rstd = rsqrtf(var + 1e-5f);
  float4 g = ((const float4*)gamma)[tid];
  float4 be = ((const float4*)beta)[tid];
  float4 o = f4((s4.x - mu) * rstd * g.x + be.x, (s4.y - mu) * rstd * g.y + be.y,
                (s4.z - mu) * rstd * g.z + be.z, (s4.w - mu) * rstd * g.w + be.w);
  if (out) ((float4*)(out + (size_t)row * DD))[tid] = o;
  if (outb) {
    ushort4 r;
    r.x = f2bf(o.x); r.y = f2bf(o.y); r.z = f2bf(o.z); r.w = f2bf(o.w);
    ((ushort4*)(outb + (size_t)row * DD))[tid] = r;
  }
}

// ------------------------------ launch -------------------------------------
extern "C" void kernel_launch(void* const* d_in, const int* in_sizes, int n_in,
                              void* d_out, int out_size, void* d_ws, size_t ws_size,
                              hipStream_t stream) {
  (void)in_sizes; (void)n_in; (void)out_size; (void)ws_size;
  const float* x      = (const float*)d_in[0];
  const float* kv0    = (const float*)d_in[1];
  const float* kst0   = (const float*)d_in[2];
  const float* kbuf   = (const float*)d_in[3];
  const float* vbufw  = (const float*)d_in[4];
  const float* Wq_lin = (const float*)d_in[5];
  const float* bq_lin = (const float*)d_in[6];
  const float* Wk_lin = (const float*)d_in[7];
  const float* bk_lin = (const float*)d_in[8];
  const float* Wv_lin = (const float*)d_in[9];
  const float* bv_lin = (const float*)d_in[10];
  const float* Wo_lin = (const float*)d_in[11];
  const float* bo_lin = (const float*)d_in[12];
  const float* Wq     = (const float*)d_in[13];
  const float* bq     = (const float*)d_in[14];
  const float* Wk     = (const float*)d_in[15];
  const float* bk     = (const float*)d_in[16];
  const float* Wv     = (const float*)d_in[17];
  const float* bv     = (const float*)d_in[18];
  const float* Wo     = (const float*)d_in[19];
  const float* bo     = (const float*)d_in[20];
  const float* gamma  = (const float*)d_in[21];
  const float* beta   = (const float*)d_in[22];

  float* out = (float*)d_out;
  float* kv_out  = out + 8388608;
  float* kst_out = out + 8388608 + 1118208;

  float* ws = (float*)d_ws;
  const size_t MF = 1024 * 1024;
  // float-offset layout (no overlaps; ws >= 256 MiB per harness fill)
  unsigned short* x_bf   = (unsigned short*)(ws);              // [0,4)
  unsigned short* qkv_b  = (unsigned short*)(ws + 4 * MF);     // [4,10)  Q|K|V bf16
  unsigned short* vT     = (unsigned short*)(ws + 10 * MF);    // [10,14)
  unsigned short* KVc_t  = (unsigned short*)(ws + 14 * MF);    // [14,23)
  unsigned short* kstc   = (unsigned short*)(ws + 23 * MF);    // [23,23.2)
  unsigned short* KVp_t  = (unsigned short*)(ws + 24 * MF);    // [24,33)
  unsigned short* kstp   = (unsigned short*)(ws + 33 * MF);    // [33,33.2)
  unsigned short* outs_bf = (unsigned short*)(ws + 34 * MF);   // [34,38)
  unsigned short* tmp_b  = (unsigned short*)(ws + 38 * MF);    // [38,42)
  unsigned short* x1b    = (unsigned short*)(ws + 42 * MF);    // [42,46)
  unsigned short* q2b    = (unsigned short*)(ws + 46 * MF);    // [46,50)
  unsigned short* winb   = (unsigned short*)(ws + 50 * MF);    // [50,54)
  unsigned short* tmp2_b = (unsigned short*)(ws + 54 * MF);    // [54,58)
  float* klast = ws + 58 * MF;                                 // 4096
  float* vlast = klast + 4096;                                 // 4096
  unsigned short* ukb  = (unsigned short*)(ws + 58 * MF + 8192);   // 262144 bf16
  unsigned short* uvTw = ukb + 262144;                              // 262144 bf16
  unsigned short* Wcomb = (unsigned short*)(ws + 59 * MF);     // 1536*1024 bf16
  unsigned short* WtO1  = (unsigned short*)(ws + 60 * MF);     // 1024*1024 bf16
  unsigned short* WtQ2  = (unsigned short*)(ws + 61 * MF);     // (0.5MF floats each)
  unsigned short* WtO2  = (unsigned short*)(ws + 62 * MF);
  float* bqkv = ws + 63 * MF;                                  // 1536 floats

  dim3 blk(256);
  cast_bf16<<<8192, blk, 0, stream>>>(x, x_bf, 2097152);
  castT_all<<<1152, blk, 0, stream>>>(Wq_lin, Wk_lin, Wv_lin, Wo_lin, Wq, Wo,
                                      bq_lin, bk_lin, bv_lin,
                                      Wcomb, WtO1, WtQ2, WtO2, bqkv);
  gemm_mfma<<<dim3(64, 12), blk, 0, stream>>>(x_bf, Wcomb, bqkv, (float*)0, qkv_b, 8192, QKVN, 1024);
  transV<<<2048, blk, 0, stream>>>(qkv_b, vT);
  phaseA2<<<1024, blk, 0, stream>>>(qkv_b, vT, KVc_t, kstc);
  phaseB3<<<585, blk, 0, stream>>>(KVc_t, kstc, kv0, kst0, KVp_t, kstp, kv_out, kst_out);
  phaseC4<<<1024, blk, 0, stream>>>(qkv_b, vT, KVp_t, kstp, outs_bf);
  gemm_mfma<<<dim3(64, 8), blk, 0, stream>>>(outs_bf, WtO1, bo_lin, (float*)0, tmp_b, 8192, 1024, 1024);
  ln_add2<<<8192, blk, 0, stream>>>(x, (const unsigned short*)0, tmp_b, gamma, beta, (float*)0, x1b);
  gemm_mfma<<<dim3(64, 8), blk, 0, stream>>>(x1b, WtQ2, bq, (float*)0, q2b, 8192, 1024, 1024);
  lastrow_init<<<32, blk, 0, stream>>>(bk, bv, klast, vlast);
  lastrow_qkv2<<<512, blk, 0, stream>>>(x1b, Wk, Wv, klast, vlast);
  prep_window<<<64, blk, 0, stream>>>(kbuf, vbufw, klast, vlast, ukb, uvTw);
  window_attn2<<<1024, blk, 0, stream>>>(q2b, ukb, uvTw, winb);
  gemm_mfma<<<dim3(64, 8), blk, 0, stream>>>(winb, WtO2, bo, (float*)0, tmp2_b, 8192, 1024, 1024);
  ln_add2<<<8192, blk, 0, stream>>>((const float*)0, x1b, tmp2_b, gamma, beta, out, (unsigned short*)0);
}

// Round 6
// 383.785 us; speedup vs baseline: 1.3561x; 1.0133x over previous
//
#include <hip/hip_runtime.h>
#include <math.h>

// ---------------------------------------------------------------------------
// BasedBlock: B=4 L=2048 d=1024 h=16 f=16 hd=64 w=64, D=1+f+f*f=273
// Round 11:
//   * T1 XCD-aware bijective swizzle on gemm_mfma (1-D grid, row-major decode)
//     and on phaseA2/phaseC4 ((bh,ck) -> contiguous bh bands per XCD)
//   * prep_all: cast_bf16 + castT_all + lastrow_init in ONE launch (17->15)
// ---------------------------------------------------------------------------

#define LL 2048
#define DD 1024
#define DFEAT 273
#define NC 16
#define CHUNK 128
#define QKVN 1536

typedef __attribute__((ext_vector_type(8))) short short8;
typedef __attribute__((ext_vector_type(4))) float f32x4;

#define SQ 0.42044820762685725f   // sqrt(1/(sqrt(2)*sqrt(16)))
#define LF 1.18920711500272107f   // 0.5 / SQ

__device__ __forceinline__ float4 f4(float a, float b, float c, float d) {
  float4 r; r.x = a; r.y = b; r.z = c; r.w = d; return r;
}

__device__ __forceinline__ unsigned short f2bf(float f) {
  union { float f; unsigned u; } v; v.f = f;
  unsigned r = v.u + 0x7fffu + ((v.u >> 16) & 1u);
  return (unsigned short)(r >> 16);
}

__device__ __forceinline__ float bf2f(unsigned short u) {
  union { unsigned u; float f; } v; v.u = ((unsigned)u) << 16; return v.f;
}

// ------------------------------ prep_all -----------------------------------
// Blocks [0,8192): x fp32 -> bf16. [8192,9344): the 6 weight transposes
// (+ bias concat). [9344,9376): klast/vlast = bias init.
__global__ __launch_bounds__(256) void prep_all(
    const float* __restrict__ x, unsigned short* __restrict__ x_bf,
    const float* __restrict__ Wql, const float* __restrict__ Wkl,
    const float* __restrict__ Wvl, const float* __restrict__ Wo1,
    const float* __restrict__ Wq2, const float* __restrict__ Wo2,
    const float* __restrict__ bql, const float* __restrict__ bkl,
    const float* __restrict__ bvl,
    unsigned short* __restrict__ Wcomb, unsigned short* __restrict__ WtO1,
    unsigned short* __restrict__ WtQ2, unsigned short* __restrict__ WtO2,
    float* __restrict__ bqkv,
    const float* __restrict__ bk, const float* __restrict__ bv,
    float* __restrict__ klast, float* __restrict__ vlast) {
  __shared__ float t[64][65];
  const int blk = blockIdx.x, tid = threadIdx.x;
  if (blk < 8192) {
    int i = blk * 256 + tid;
    float4 v = ((const float4*)x)[i];
    ushort4 r;
    r.x = f2bf(v.x); r.y = f2bf(v.y); r.z = f2bf(v.z); r.w = f2bf(v.w);
    ((ushort4*)x_bf)[i] = r;
    return;
  }
  if (blk >= 9344) {
    int gid = (blk - 9344) * 256 + tid;   // 0..8191
    int which = gid >> 12;
    int b = (gid >> 10) & 3;
    int n = gid & 1023;
    (which ? vlast : klast)[b * 1024 + n] = which ? bv[n] : bk[n];
    return;
  }
  const int b2 = blk - 8192;   // 0..1151
  if (b2 < 6) {
    int i = b2 * 256 + tid;   // 0..1535
    float v = (i < 256) ? bql[i] : (i < 512) ? bkl[i - 256] : bvl[i - 512];
    bqkv[i] = v;
  }
  const float* W; unsigned short* Wt; int N, t0;
  if (b2 < 64)       { W = Wql; Wt = Wcomb;               N = 256;  t0 = b2; }
  else if (b2 < 128) { W = Wkl; Wt = Wcomb + 256 * 1024;  N = 256;  t0 = b2 - 64; }
  else if (b2 < 384) { W = Wvl; Wt = Wcomb + 512 * 1024;  N = 1024; t0 = b2 - 128; }
  else if (b2 < 640) { W = Wo1; Wt = WtO1;                N = 1024; t0 = b2 - 384; }
  else if (b2 < 896) { W = Wq2; Wt = WtQ2;                N = 1024; t0 = b2 - 640; }
  else               { W = Wo2; Wt = WtO2;                N = 1024; t0 = b2 - 896; }
  const int nt = N >> 6;
  const int k0 = (t0 / nt) * 64, n0 = (t0 % nt) * 64;
#pragma unroll
  for (int p = 0; p < 16; p++) {
    int idx = p * 256 + tid;
    int r = idx >> 6, c = idx & 63;
    t[r][c] = W[(size_t)(k0 + r) * N + n0 + c];
  }
  __syncthreads();
#pragma unroll
  for (int p = 0; p < 16; p++) {
    int idx = p * 256 + tid;
    int rn = idx >> 6, ck = idx & 63;
    Wt[(size_t)(n0 + rn) * 1024 + k0 + ck] = f2bf(t[ck][rn]);
  }
}

// --------------------------- MFMA GEMM -------------------------------------
// 1-D grid; XCD-aware bijective swizzle (nwg % 8 == 0 for all call sites),
// row-major decode so each XCD owns a contiguous band of row-tiles.
__global__ __launch_bounds__(256) void gemm_mfma(
    const unsigned short* __restrict__ A, const unsigned short* __restrict__ Bt,
    const float* __restrict__ bias, float* __restrict__ C,
    unsigned short* __restrict__ Cb, int M, int N, int K) {
  __shared__ unsigned short As[128 * 64];
  __shared__ unsigned short Bs[128 * 64];
  const int tid = threadIdx.x;
  const int lane = tid & 63, w = tid >> 6;
  const int Ny = N >> 7;
  const int cpx = gridDim.x >> 3;
  const int orig = blockIdx.x;
  const int wg = (orig & 7) * cpx + (orig >> 3);
  const int bxi = wg / Ny, byi = wg - bxi * Ny;
  const int row0 = bxi * 128, col0 = byi * 128;
  const int wm0 = (w & 1) * 64, wn0 = (w >> 1) * 64;
  const int lr = lane >> 3;
  const int gc = (lane & 7) ^ lr;
  const unsigned short* aP = A + (size_t)(row0 + w * 32 + lr) * K + gc * 8;
  const unsigned short* bP = Bt + (size_t)(col0 + w * 32 + lr) * K + gc * 8;
  unsigned short* asW = As + w * 2048;
  unsigned short* bsW = Bs + w * 2048;
  const int m15 = lane & 15, quad = lane >> 4;
  f32x4 acc[4][4] = {};
  for (int k0 = 0; k0 < K; k0 += 64) {
#pragma unroll
    for (int i = 0; i < 4; i++) {
      __builtin_amdgcn_global_load_lds(
          (const __attribute__((address_space(1))) unsigned int*)(const void*)(aP + (size_t)(i * 8) * K + k0),
          (__attribute__((address_space(3))) unsigned int*)(void*)(asW + i * 512), 16, 0, 0);
      __builtin_amdgcn_global_load_lds(
          (const __attribute__((address_space(1))) unsigned int*)(const void*)(bP + (size_t)(i * 8) * K + k0),
          (__attribute__((address_space(3))) unsigned int*)(void*)(bsW + i * 512), 16, 0, 0);
    }
    __syncthreads();
#pragma unroll
    for (int ks = 0; ks < 2; ks++) {
      short8 aF[4], bF[4];
#pragma unroll
      for (int mi = 0; mi < 4; mi++) {
        int r = wm0 + mi * 16 + m15;
        int g = (ks * 4 + quad) ^ (r & 7);
        aF[mi] = *(const short8*)(As + r * 64 + g * 8);
      }
#pragma unroll
      for (int ni = 0; ni < 4; ni++) {
        int r = wn0 + ni * 16 + m15;
        int g = (ks * 4 + quad) ^ (r & 7);
        bF[ni] = *(const short8*)(Bs + r * 64 + g * 8);
      }
#pragma unroll
      for (int mi = 0; mi < 4; mi++)
#pragma unroll
        for (int ni = 0; ni < 4; ni++)
          acc[mi][ni] = __builtin_amdgcn_mfma_f32_16x16x32_bf16(
              aF[mi], bF[ni], acc[mi][ni], 0, 0, 0);
    }
    __syncthreads();
  }
#pragma unroll
  for (int mi = 0; mi < 4; mi++)
#pragma unroll
    for (int ni = 0; ni < 4; ni++) {
      int col = col0 + wn0 + ni * 16 + m15;
      float bb = bias[col];
#pragma unroll
      for (int r = 0; r < 4; r++) {
        int row = row0 + wm0 + mi * 16 + quad * 4 + r;
        float val = acc[mi][ni][r] + bb;
        if (Cb) Cb[(size_t)row * N + col] = f2bf(val);
        else C[(size_t)row * N + col] = val;
      }
    }
}

// ------------------------------ transV -------------------------------------
// qkv[t][512 + h*64+c] -> vT[bh][c][t]
__global__ __launch_bounds__(256) void transV(
    const unsigned short* __restrict__ qkv, unsigned short* __restrict__ vT) {
  __shared__ unsigned short Tv[64][72];
  const int blk = blockIdx.x;
  const int bh = blk >> 5, tt = blk & 31;
  const int b = bh >> 4, hh = bh & 15;
  const int t0 = tt * 64;
  const int tid = threadIdx.x;
  {
    int t = tid >> 2, cs = tid & 3;
    const unsigned short* p = qkv + ((size_t)(b * LL + t0 + t)) * QKVN + 512 + hh * 64 + cs * 16;
    *(short8*)&Tv[t][cs * 16] = *(const short8*)p;
    *(short8*)&Tv[t][cs * 16 + 8] = *(const short8*)(p + 8);
  }
  __syncthreads();
  {
    int c = tid & 63, ts = tid >> 6;
    unsigned short vals[16];
#pragma unroll
    for (int j = 0; j < 16; j++) vals[j] = Tv[ts * 16 + j][c];
    unsigned short* op = vT + ((size_t)bh * 64 + c) * LL + t0 + ts * 16;
    *(short8*)op = *(short8*)&vals[0];
    *(short8*)(op + 8) = *(short8*)&vals[8];
  }
}

// ------------------------------ phase A ------------------------------------
// KVc_t[bh][ck][c][f] = sum_t Kf[t][f] V[t][c] (bf16); kstc[bh][ck][f].
// XCD-swizzled block id: all 16 chunks of a bh land on one XCD.
__global__ __launch_bounds__(256) void phaseA2(
    const unsigned short* __restrict__ qkv, const unsigned short* __restrict__ vT,
    unsigned short* __restrict__ KVc_t, unsigned short* __restrict__ kstc) {
  __shared__ unsigned short kT[16][136];   // kT[i][t] = bf16(k[t][i]*SQ)
  const int tid = threadIdx.x, lane = tid & 63, w = tid >> 6;
  const int m15 = lane & 15, quad = lane >> 4;
  const int orig = blockIdx.x;
  const int wg = (orig & 7) * 128 + (orig >> 3);
  const int bh = wg >> 4, ck = wg & 15;
  const int b = bh >> 4, hh = bh & 15;
  const int t0 = ck * CHUNK;
  {
    int r = tid >> 1, half = tid & 1;
    short8 kv = *(const short8*)(qkv + ((size_t)(b * LL + t0 + r)) * QKVN + 256 + hh * 16 + half * 8);
#pragma unroll
    for (int j = 0; j < 8; j++)
      kT[half * 8 + j][r] = f2bf(bf2f(((unsigned short*)&kv)[j]) * SQ);
  }
  __syncthreads();
  short8 ones8 = {16256, 16256, 16256, 16256, 16256, 16256, 16256, 16256};
  short8 zer8 = {0, 0, 0, 0, 0, 0, 0, 0};
  f32x4 acc[5][5] = {};
  const unsigned short* vbase = vT + (size_t)bh * 64 * LL + t0;
#pragma unroll
  for (int ks = 0; ks < 4; ++ks) {
    const int tt = ks * 32 + quad * 8;
    short8 aF[5], bF[5];
#pragma unroll
    for (int mi = 0; mi < 5; mi++) {
      int r = (w * 5 + mi) * 16 + m15;
      short8 av;
      unsigned short* pv = (unsigned short*)&av;
      if (r == 0) {
        av = ones8;
      } else if (r < 17) {
        short8 k1 = *(const short8*)&kT[r - 1][tt];
#pragma unroll
        for (int j = 0; j < 8; j++) pv[j] = f2bf(bf2f(((unsigned short*)&k1)[j]) * LF);
      } else if (r < DFEAT) {
        int ij = r - 17;
        short8 k1 = *(const short8*)&kT[ij >> 4][tt];
        short8 k2 = *(const short8*)&kT[ij & 15][tt];
#pragma unroll
        for (int j = 0; j < 8; j++)
          pv[j] = f2bf(bf2f(((unsigned short*)&k1)[j]) * bf2f(((unsigned short*)&k2)[j]));
      } else {
        av = zer8;
      }
      aF[mi] = av;
    }
#pragma unroll
    for (int ni = 0; ni < 4; ni++)
      bF[ni] = *(const short8*)(vbase + ((size_t)(ni * 16 + m15)) * LL + tt);
    bF[4] = (m15 == 0) ? ones8 : zer8;
#pragma unroll
    for (int mi = 0; mi < 5; mi++)
#pragma unroll
      for (int ni = 0; ni < 5; ni++)
        acc[mi][ni] = __builtin_amdgcn_mfma_f32_16x16x32_bf16(
            aF[mi], bF[ni], acc[mi][ni], 0, 0, 0);
  }
  const size_t cb = ((size_t)bh * NC + ck) * (64 * 288);
  const size_t kb = ((size_t)bh * NC + ck) * 288;
#pragma unroll
  for (int mi = 0; mi < 5; mi++) {
    int fb = (w * 5 + mi) * 16 + quad * 4;
    if (fb < 288) {
#pragma unroll
      for (int ni = 0; ni < 4; ni++) {
        int c = ni * 16 + m15;
        ushort4 sv;
        sv.x = f2bf(acc[mi][ni][0]); sv.y = f2bf(acc[mi][ni][1]);
        sv.z = f2bf(acc[mi][ni][2]); sv.w = f2bf(acc[mi][ni][3]);
        *(ushort4*)(KVc_t + cb + (size_t)c * 288 + fb) = sv;
      }
      if (m15 == 0) {
        ushort4 sv;
        sv.x = f2bf(acc[mi][4][0]); sv.y = f2bf(acc[mi][4][1]);
        sv.z = f2bf(acc[mi][4][2]); sv.w = f2bf(acc[mi][4][3]);
        *(ushort4*)(kstc + kb + fb) = sv;
      }
    }
  }
}

// ------------------------------ phase B ------------------------------------
__global__ __launch_bounds__(256) void phaseB3(
    const unsigned short* __restrict__ KVc_t, const unsigned short* __restrict__ kstc,
    const float* __restrict__ kv0, const float* __restrict__ kst0,
    unsigned short* __restrict__ KVp_t, unsigned short* __restrict__ kstp,
    float* __restrict__ kv_out, float* __restrict__ kst_out) {
  const int tid = threadIdx.x;
  if (blockIdx.x < 576) {
    int gid = blockIdx.x * 256 + tid;
    int bh = gid / 2304, rem = gid - bh * 2304;
    int c = rem / 36, fg = rem - c * 36;
    int f0 = fg * 8;
    float acc[8];
#pragma unroll
    for (int j = 0; j < 8; j++) {
      int f = f0 + j;
      acc[j] = (f < DFEAT) ? kv0[((size_t)bh * DFEAT + f) * 64 + c] : 0.0f;
    }
    size_t base = ((size_t)bh * NC) * (64 * 288) + (size_t)c * 288 + f0;
    for (int ck = 0; ck < NC; ck++) {
      size_t idx = base + (size_t)ck * (64 * 288);
      short8 t = *(const short8*)(KVc_t + idx);
      unsigned short ov[8];
#pragma unroll
      for (int j = 0; j < 8; j++) {
        ov[j] = f2bf(acc[j]);
        acc[j] += bf2f(((unsigned short*)&t)[j]);
      }
      *(short8*)(KVp_t + idx) = *(short8*)ov;
    }
#pragma unroll
    for (int j = 0; j < 8; j++) {
      int f = f0 + j;
      if (f < DFEAT) kv_out[((size_t)bh * DFEAT + f) * 64 + c] = acc[j];
    }
  } else {
    int idx0 = (blockIdx.x - 576) * 256 + tid;   // 0..2303
    int bh = idx0 / 36, fg = idx0 - bh * 36;
    int f0 = fg * 8;
    float acc[8];
#pragma unroll
    for (int j = 0; j < 8; j++) {
      int f = f0 + j;
      acc[j] = (f < DFEAT) ? kst0[bh * DFEAT + f] : 0.0f;
    }
    for (int ck = 0; ck < NC; ck++) {
      size_t idx = ((size_t)bh * NC + ck) * 288 + f0;
      short8 t = *(const short8*)(kstc + idx);
      unsigned short ov[8];
#pragma unroll
      for (int j = 0; j < 8; j++) {
        ov[j] = f2bf(acc[j]);
        acc[j] += bf2f(((unsigned short*)&t)[j]);
      }
      *(short8*)(kstp + idx) = *(short8*)ov;
    }
#pragma unroll
    for (int j = 0; j < 8; j++) {
      int f = f0 + j;
      if (f < DFEAT) kst_out[bh * DFEAT + f] = acc[j];
    }
  }
}

// ------------------------------ phase C ------------------------------------
// 256-thread blocks, 1024 = (bh, ck) XCD-swizzled; wave w = causal quarter.
__global__ __launch_bounds__(256) void phaseC4(
    const unsigned short* __restrict__ qkv,
    const unsigned short* __restrict__ vT, const unsigned short* __restrict__ KVp_t,
    const unsigned short* __restrict__ kstp, unsigned short* __restrict__ outs) {
  __shared__ float qs[4][32][36];              // per-wave: [0..15]=q*SQ, [16..31]=rot dup
  __shared__ unsigned short S_l[4][32 * 128];  // per-wave swizzled intra scores
  const int tid = threadIdx.x, lane = tid & 63, w = tid >> 6;
  const int m15 = lane & 15, quad = lane >> 4;
  const int orig = blockIdx.x;
  const int wgb = (orig & 7) * 128 + (orig >> 3);
  const int bh = wgb >> 4, ck = wgb & 15;
  const int qw = w;
  const int b = bh >> 4, hh = bh & 15;
  const int t0 = ck * CHUNK;
  const int tr0 = qw * 32;
  float (*qsw)[36] = qs[w];
  unsigned short* Sw = S_l[w];
  const unsigned short* qbase = qkv + ((size_t)(b * LL + t0 + tr0)) * QKVN + hh * 16;
  const unsigned short* kbase = qkv + ((size_t)(b * LL + t0)) * QKVN + 256 + hh * 16;
  // ---- fill qs (wave-private rows, no barrier) ----
  {
    int r = lane >> 1, h8 = lane & 1;
    short8 qv = *(const short8*)(qbase + (size_t)r * QKVN + h8 * 8);
    float qf[8];
#pragma unroll
    for (int j = 0; j < 8; j++) qf[j] = bf2f(((unsigned short*)&qv)[j]) * SQ;
    *(float4*)&qsw[r][h8 * 8] = f4(qf[0], qf[1], qf[2], qf[3]);
    *(float4*)&qsw[r][h8 * 8 + 4] = f4(qf[4], qf[5], qf[6], qf[7]);
#pragma unroll
    for (int j = 0; j < 8; j++)
      qsw[r][16 + ((h8 * 8 + j + 9) & 15)] = qf[j];   // rot[m] = q[(m+7)&15]
  }
  short8 ones8 = {16256, 16256, 16256, 16256, 16256, 16256, 16256, 16256};
  short8 zer8 = {0, 0, 0, 0, 0, 0, 0, 0};
  f32x4 acc[2][5] = {};
  const unsigned short* KVb = KVp_t + ((size_t)(bh * NC + ck)) * (64 * 288);
  const unsigned short* kstb = kstp + ((size_t)(bh * NC + ck)) * 288;
  // ---- pass 1: inter (Qf @ KV'), K = 288 ----
#pragma unroll
  for (int ks = 0; ks < 9; ++ks) {
    const int fs = ks * 32 + quad * 8;
    short8 aF[2], bF[5];
#pragma unroll
    for (int ni = 0; ni < 4; ni++)
      bF[ni] = *(const short8*)(KVb + ((size_t)(ni * 16 + m15)) * 288 + fs);
    bF[4] = (m15 == 0) ? *(const short8*)(kstb + fs) : zer8;
#pragma unroll
    for (int mi = 0; mi < 2; mi++) {
      const float* qr = &qsw[mi * 16 + m15][0];
      unsigned short pv[8];
      if (ks == 0) {
        float qr0 = qr[0];
#pragma unroll
        for (int j = 0; j < 8; j++) {
          int f = (quad << 3) + j;
          int fl = f - 1; fl = fl < 0 ? 0 : fl;
          int fm = f - 17; fm = fm < 0 ? 0 : fm;     // < 16 here
          float lin = qr[fl] * LF;
          float prod = qr0 * qr[fm];
          float val = (f == 0) ? 1.0f : ((f < 17) ? lin : prod);
          pv[j] = f2bf(val);
        }
      } else {
        int base = fs - 17;                 // >= 15
        int i0 = base >> 4;
        float qi0 = qr[i0];
        float qi1 = qr[i0 + 1];
        const float* qv = qr + 16 + (base & 8);   // aligned 32B window (rot dup)
        float qj[8];
        *(float4*)&qj[0] = *(const float4*)qv;
        *(float4*)&qj[4] = *(const float4*)(qv + 4);
        float qiB = (quad & 1) ? qi0 : qi1;
#pragma unroll
        for (int j = 0; j < 8; j++) {
          float qi = (j == 0) ? qi0 : qiB;
          float val = qi * qj[j];
          if (ks == 8) val = ((quad << 3) + j < 17) ? val : 0.0f;  // f >= 273 -> 0
          pv[j] = f2bf(val);
        }
      }
      aF[mi] = *(short8*)pv;
    }
#pragma unroll
    for (int mi = 0; mi < 2; mi++)
#pragma unroll
      for (int ni = 0; ni < 5; ni++)
        acc[mi][ni] = __builtin_amdgcn_mfma_f32_16x16x32_bf16(
            aF[mi], bF[ni], acc[mi][ni], 0, 0, 0);
  }
  // ---- intra: u = q@k^T (K=16 pad 32) -> poly/mask -> S_l (wave-private) ----
  const int nsn = 2 * qw + 2;               // s covers [0, (qw+1)*32)
  {
    short8 aU[2], bU[8];
    aU[0] = (quad < 2) ? *(const short8*)(qbase + (size_t)m15 * QKVN + quad * 8) : zer8;
    aU[1] = (quad < 2) ? *(const short8*)(qbase + (size_t)(16 + m15) * QKVN + quad * 8) : zer8;
#pragma unroll
    for (int sn = 0; sn < 8; sn++) {
      if (sn < nsn) {
        int s = sn * 16 + m15;
        bU[sn] = (quad < 2) ? *(const short8*)(kbase + (size_t)s * QKVN + quad * 8) : zer8;
      }
    }
#pragma unroll
    for (int mi = 0; mi < 2; mi++) {
#pragma unroll
      for (int sn = 0; sn < 8; sn++) {
        if (sn < nsn) {
          f32x4 zz = {0.f, 0.f, 0.f, 0.f};
          f32x4 u = __builtin_amdgcn_mfma_f32_16x16x32_bf16(aU[mi], bU[sn], zz, 0, 0, 0);
          int s = sn * 16 + m15;
          int gRow = s >> 3;
#pragma unroll
          for (int rr = 0; rr < 4; rr++) {
            int tl = mi * 16 + quad * 4 + rr;        // local row 0..31
            int tc = tr0 + tl;                       // chunk-local row for mask
            float uu = u[rr];
            float sv = (s <= tc) ? fmaf(uu, fmaf(uu, 0.03125f, 0.25f), 1.0f) : 0.0f;
            int p = gRow ^ (tl & 7);
            Sw[tl * 128 + p * 8 + (s & 7)] = f2bf(sv);
          }
        }
      }
    }
  }
  // ---- pass 2: S @ V' — no barrier (same-wave LDS RAW) ----
  const unsigned short* vbase = vT + (size_t)bh * 64 * LL + t0;
#pragma unroll
  for (int ks = 0; ks < 4; ++ks) {
    if (ks <= qw) {
      const int tt = ks * 32 + quad * 8;
      short8 aF[2], bF[5];
#pragma unroll
      for (int mi = 0; mi < 2; mi++) {
        int tl = mi * 16 + m15;
        int p = (ks * 4 + quad) ^ (tl & 7);
        aF[mi] = *(const short8*)&Sw[tl * 128 + p * 8];
      }
#pragma unroll
      for (int ni = 0; ni < 4; ni++)
        bF[ni] = *(const short8*)(vbase + ((size_t)(ni * 16 + m15)) * LL + tt);
      bF[4] = (m15 == 0) ? ones8 : zer8;
#pragma unroll
      for (int mi = 0; mi < 2; mi++)
#pragma unroll
        for (int ni = 0; ni < 5; ni++)
          acc[mi][ni] = __builtin_amdgcn_mfma_f32_16x16x32_bf16(
              aF[mi], bF[ni], acc[mi][ni], 0, 0, 0);
    }
  }
  // ---- epilogue ----
#pragma unroll
  for (int mi = 0; mi < 2; mi++) {
#pragma unroll
    for (int rr = 0; rr < 4; rr++) {
      float den = __shfl(acc[mi][4][rr], (lane & 48));
      float inv = 1.0f / (den + 1e-6f);
      int tl = mi * 16 + quad * 4 + rr;
      unsigned short* op = outs + ((size_t)(b * LL + t0 + tr0 + tl)) * DD + hh * 64;
#pragma unroll
      for (int ni = 0; ni < 4; ni++)
        op[ni * 16 + m15] = f2bf(acc[mi][ni][rr] * inv);
    }
  }
}

// --------------------------- last-row k2/v2 --------------------------------
// grid 512 = which(2) x nstrip(16) x kslice(16); bf16 x1 input.
__global__ __launch_bounds__(256) void lastrow_qkv2(
    const unsigned short* __restrict__ x1b,
    const float* __restrict__ Wk, const float* __restrict__ Wv,
    float* __restrict__ klast, float* __restrict__ vlast) {
  __shared__ float xs[4][64];
  __shared__ float red[4][4][64];
  const int blk = blockIdx.x;
  const int which = blk >> 8;
  const int nstrip = (blk >> 4) & 15;
  const int kslice = blk & 15;
  const int n0 = nstrip * 64, k0 = kslice * 64;
  const int tid = threadIdx.x;
  const int nn = tid & 63, p = tid >> 6;
  {
    int b = tid >> 6, k = tid & 63;
    xs[b][k] = bf2f(x1b[((size_t)(b * LL + LL - 1)) * DD + k0 + k]);
  }
  __syncthreads();
  const float* W = which ? Wv : Wk;
  float acc[4] = {};
#pragma unroll
  for (int i = 0; i < 16; i++) {
    int kk = p * 16 + i;
    float wv = W[(size_t)(k0 + kk) * 1024 + n0 + nn];
#pragma unroll
    for (int b = 0; b < 4; b++) acc[b] = fmaf(xs[b][kk], wv, acc[b]);
  }
#pragma unroll
  for (int b = 0; b < 4; b++) red[p][b][nn] = acc[b];
  __syncthreads();
  if (p == 0) {
    float* outp = which ? vlast : klast;
#pragma unroll
    for (int b = 0; b < 4; b++) {
      float s = red[0][b][nn] + red[1][b][nn] + red[2][b][nn] + red[3][b][nn];
      atomicAdd(outp + b * 1024 + n0 + nn, s);
    }
  }
}

// --------------------------- window prep -----------------------------------
__global__ __launch_bounds__(256) void prep_window(
    const float* __restrict__ kbuf, const float* __restrict__ vbufw,
    const float* __restrict__ klast, const float* __restrict__ vlast,
    unsigned short* __restrict__ ukb, unsigned short* __restrict__ uvT) {
  __shared__ float Tv[64][68];
  const int bh = blockIdx.x;
  const int b = bh >> 4, hh = bh & 15;
  const int tid = threadIdx.x;
  const int wi = tid >> 2, d0 = (tid & 3) * 16;
  {
    const float* kp = (wi < 63) ? (kbuf + ((size_t)hh * 64 + wi + 1) * 64 + d0)
                                : (klast + (size_t)b * 1024 + hh * 64 + d0);
    unsigned short* op = ukb + ((size_t)bh * 64 + wi) * 64 + d0;
#pragma unroll
    for (int j4 = 0; j4 < 4; j4++) {
      float4 v = *(const float4*)(kp + j4 * 4);
      ushort4 r;
      r.x = f2bf(v.x); r.y = f2bf(v.y); r.z = f2bf(v.z); r.w = f2bf(v.w);
      *(ushort4*)(op + j4 * 4) = r;
    }
  }
  {
    const float* vp = (wi < 63) ? (vbufw + ((size_t)hh * 64 + wi + 1) * 64 + d0)
                                : (vlast + (size_t)b * 1024 + hh * 64 + d0);
#pragma unroll
    for (int j4 = 0; j4 < 4; j4++)
      *(float4*)&Tv[wi][d0 + j4 * 4] = *(const float4*)(vp + j4 * 4);
  }
  __syncthreads();
  {
    int c = tid & 63, w0 = (tid >> 6) * 16;
    unsigned short* op = uvT + ((size_t)bh * 64 + c) * 64 + w0;
    unsigned short vals[16];
#pragma unroll
    for (int j = 0; j < 16; j++) vals[j] = f2bf(Tv[w0 + j][c]);
    *(short8*)op = *(short8*)&vals[0];
    *(short8*)(op + 8) = *(short8*)&vals[8];
  }
}

// --------------------------- window attention ------------------------------
__global__ __launch_bounds__(256) void window_attn2(
    const unsigned short* __restrict__ q2b, const unsigned short* __restrict__ ukb,
    const unsigned short* __restrict__ uvT, unsigned short* __restrict__ win) {
  __shared__ unsigned short S_l[128 * 64];   // 16 KB, swizzled softmax weights
  const int tid = threadIdx.x, lane = tid & 63, w = tid >> 6;
  const int m15 = lane & 15, quad = lane >> 4;
  const int bh = blockIdx.x >> 4, tile = blockIdx.x & 15;
  const int b = bh >> 4, hh = bh & 15;
  const int t0 = tile * 128 + w * 32;
  const unsigned short* ukbase = ukb + (size_t)bh * 64 * 64;
  const unsigned short* uvbase = uvT + (size_t)bh * 64 * 64;
  f32x4 accS[2][4] = {};
#pragma unroll
  for (int ks = 0; ks < 2; ks++) {
    short8 aF[2], bF[4];
#pragma unroll
    for (int mi = 0; mi < 2; mi++)
      aF[mi] = *(const short8*)(q2b + ((size_t)(b * LL + t0 + mi * 16 + m15)) * DD +
                                hh * 64 + ks * 32 + quad * 8);
#pragma unroll
    for (int ni = 0; ni < 4; ni++)
      bF[ni] = *(const short8*)(ukbase + ((size_t)(ni * 16 + m15)) * 64 + ks * 32 + quad * 8);
#pragma unroll
    for (int mi = 0; mi < 2; mi++)
#pragma unroll
      for (int ni = 0; ni < 4; ni++)
        accS[mi][ni] = __builtin_amdgcn_mfma_f32_16x16x32_bf16(
            aF[mi], bF[ni], accS[mi][ni], 0, 0, 0);
  }
#pragma unroll
  for (int mi = 0; mi < 2; mi++) {
#pragma unroll
    for (int rr = 0; rr < 4; rr++) {
      float s0 = accS[mi][0][rr] * 0.125f;
      float s1 = accS[mi][1][rr] * 0.125f;
      float s2 = accS[mi][2][rr] * 0.125f;
      float s3 = accS[mi][3][rr] * 0.125f;
      float m = fmaxf(fmaxf(s0, s1), fmaxf(s2, s3));
      m = fmaxf(m, __shfl_xor(m, 1));
      m = fmaxf(m, __shfl_xor(m, 2));
      m = fmaxf(m, __shfl_xor(m, 4));
      m = fmaxf(m, __shfl_xor(m, 8));
      float p0 = __expf(s0 - m), p1 = __expf(s1 - m);
      float p2 = __expf(s2 - m), p3 = __expf(s3 - m);
      float l = p0 + p1 + p2 + p3;
      l += __shfl_xor(l, 1);
      l += __shfl_xor(l, 2);
      l += __shfl_xor(l, 4);
      l += __shfl_xor(l, 8);
      float inv = 1.0f / l;
      int tl = w * 32 + mi * 16 + quad * 4 + rr;
      int t7 = tl & 7;
      float pr[4] = {p0 * inv, p1 * inv, p2 * inv, p3 * inv};
#pragma unroll
      for (int ni = 0; ni < 4; ni++) {
        int s = ni * 16 + m15;
        S_l[tl * 64 + ((s >> 3) ^ t7) * 8 + (s & 7)] = f2bf(pr[ni]);
      }
    }
  }
  f32x4 accO[2][4] = {};
#pragma unroll
  for (int ks = 0; ks < 2; ks++) {
    short8 aF[2], bF[4];
#pragma unroll
    for (int mi = 0; mi < 2; mi++) {
      int tl = w * 32 + mi * 16 + m15;
      int g = (ks * 4 + quad) ^ (tl & 7);
      aF[mi] = *(const short8*)&S_l[tl * 64 + g * 8];
    }
#pragma unroll
    for (int ni = 0; ni < 4; ni++)
      bF[ni] = *(const short8*)(uvbase + ((size_t)(ni * 16 + m15)) * 64 + ks * 32 + quad * 8);
#pragma unroll
    for (int mi = 0; mi < 2; mi++)
#pragma unroll
      for (int ni = 0; ni < 4; ni++)
        accO[mi][ni] = __builtin_amdgcn_mfma_f32_16x16x32_bf16(
            aF[mi], bF[ni], accO[mi][ni], 0, 0, 0);
  }
#pragma unroll
  for (int mi = 0; mi < 2; mi++) {
#pragma unroll
    for (int rr = 0; rr < 4; rr++) {
      int row = t0 + mi * 16 + quad * 4 + rr;
      unsigned short* op = win + ((size_t)(b * LL + row)) * DD + hh * 64;
#pragma unroll
      for (int ni = 0; ni < 4; ni++)
        op[ni * 16 + m15] = f2bf(accO[mi][ni][rr]);
    }
  }
}

// ------------------------------ LayerNorm ----------------------------------
// A = Af (fp32) or Ab (bf16); Bm = bf16; outputs optional.
__global__ __launch_bounds__(256) void ln_add2(
    const float* __restrict__ Af, const unsigned short* __restrict__ Ab,
    const unsigned short* __restrict__ Bmb,
    const float* __restrict__ gamma, const float* __restrict__ beta,
    float* __restrict__ out, unsigned short* __restrict__ outb) {
  const int row = blockIdx.x, tid = threadIdx.x;
  float a0, a1, a2, a3;
  if (Af) {
    float4 va = ((const float4*)(Af + (size_t)row * DD))[tid];
    a0 = va.x; a1 = va.y; a2 = va.z; a3 = va.w;
  } else {
    ushort4 ua = ((const ushort4*)(Ab + (size_t)row * DD))[tid];
    a0 = bf2f(ua.x); a1 = bf2f(ua.y); a2 = bf2f(ua.z); a3 = bf2f(ua.w);
  }
  ushort4 ub = ((const ushort4*)(Bmb + (size_t)row * DD))[tid];
  float4 s4 = f4(a0 + bf2f(ub.x), a1 + bf2f(ub.y), a2 + bf2f(ub.z), a3 + bf2f(ub.w));
  float s = s4.x + s4.y + s4.z + s4.w;
  float ss = s4.x * s4.x + s4.y * s4.y + s4.z * s4.z + s4.w * s4.w;
  for (int o = 32; o; o >>= 1) { s += __shfl_xor(s, o); ss += __shfl_xor(ss, o); }
  __shared__ float red[8];
  int wid = tid >> 6;
  if ((tid & 63) == 0) { red[wid * 2] = s; red[wid * 2 + 1] = ss; }
  __syncthreads();
  float tot = red[0] + red[2] + red[4] + red[6];
  float tots = red[1] + red[3] + red[5] + red[7];
  float mu = tot * (1.0f / 1024.0f);
  float var = tots * (1.0f / 1024.0f) - mu * mu;
  float rstd = rsqrtf(var + 1e-5f);
  float4 g = ((const float4*)gamma)[tid];
  float4 be = ((const float4*)beta)[tid];
  float4 o = f4((s4.x - mu) * rstd * g.x + be.x, (s4.y - mu) * rstd * g.y + be.y,
                (s4.z - mu) * rstd * g.z + be.z, (s4.w - mu) * rstd * g.w + be.w);
  if (out) ((float4*)(out + (size_t)row * DD))[tid] = o;
  if (outb) {
    ushort4 r;
    r.x = f2bf(o.x); r.y = f2bf(o.y); r.z = f2bf(o.z); r.w = f2bf(o.w);
    ((ushort4*)(outb + (size_t)row * DD))[tid] = r;
  }
}

// ------------------------------ launch -------------------------------------
extern "C" void kernel_launch(void* const* d_in, const int* in_sizes, int n_in,
                              void* d_out, int out_size, void* d_ws, size_t ws_size,
                              hipStream_t stream) {
  (void)in_sizes; (void)n_in; (void)out_size; (void)ws_size;
  const float* x      = (const float*)d_in[0];
  const float* kv0    = (const float*)d_in[1];
  const float* kst0   = (const float*)d_in[2];
  const float* kbuf   = (const float*)d_in[3];
  const float* vbufw  = (const float*)d_in[4];
  const float* Wq_lin = (const float*)d_in[5];
  const float* bq_lin = (const float*)d_in[6];
  const float* Wk_lin = (const float*)d_in[7];
  const float* bk_lin = (const float*)d_in[8];
  const float* Wv_lin = (const float*)d_in[9];
  const float* bv_lin = (const float*)d_in[10];
  const float* Wo_lin = (const float*)d_in[11];
  const float* bo_lin = (const float*)d_in[12];
  const float* Wq     = (const float*)d_in[13];
  const float* bq     = (const float*)d_in[14];
  const float* Wk     = (const float*)d_in[15];
  const float* bk     = (const float*)d_in[16];
  const float* Wv     = (const float*)d_in[17];
  const float* bv     = (const float*)d_in[18];
  const float* Wo     = (const float*)d_in[19];
  const float* bo     = (const float*)d_in[20];
  const float* gamma  = (const float*)d_in[21];
  const float* beta   = (const float*)d_in[22];

  float* out = (float*)d_out;
  float* kv_out  = out + 8388608;
  float* kst_out = out + 8388608 + 1118208;

  float* ws = (float*)d_ws;
  const size_t MF = 1024 * 1024;
  unsigned short* x_bf   = (unsigned short*)(ws);              // [0,4)
  unsigned short* qkv_b  = (unsigned short*)(ws + 4 * MF);     // [4,10)  Q|K|V bf16
  unsigned short* vT     = (unsigned short*)(ws + 10 * MF);    // [10,14)
  unsigned short* KVc_t  = (unsigned short*)(ws + 14 * MF);    // [14,23)
  unsigned short* kstc   = (unsigned short*)(ws + 23 * MF);    // [23,23.2)
  unsigned short* KVp_t  = (unsigned short*)(ws + 24 * MF);    // [24,33)
  unsigned short* kstp   = (unsigned short*)(ws + 33 * MF);    // [33,33.2)
  unsigned short* outs_bf = (unsigned short*)(ws + 34 * MF);   // [34,38)
  unsigned short* tmp_b  = (unsigned short*)(ws + 38 * MF);    // [38,42)
  unsigned short* x1b    = (unsigned short*)(ws + 42 * MF);    // [42,46)
  unsigned short* q2b    = (unsigned short*)(ws + 46 * MF);    // [46,50)
  unsigned short* winb   = (unsigned short*)(ws + 50 * MF);    // [50,54)
  unsigned short* tmp2_b = (unsigned short*)(ws + 54 * MF);    // [54,58)
  float* klast = ws + 58 * MF;                                 // 4096
  float* vlast = klast + 4096;                                 // 4096
  unsigned short* ukb  = (unsigned short*)(ws + 58 * MF + 8192);   // 262144 bf16
  unsigned short* uvTw = ukb + 262144;                              // 262144 bf16
  unsigned short* Wcomb = (unsigned short*)(ws + 59 * MF);     // 1536*1024 bf16
  unsigned short* WtO1  = (unsigned short*)(ws + 60 * MF);     // 1024*1024 bf16
  unsigned short* WtQ2  = (unsigned short*)(ws + 61 * MF);
  unsigned short* WtO2  = (unsigned short*)(ws + 62 * MF);
  float* bqkv = ws + 63 * MF;                                  // 1536 floats

  dim3 blk(256);
  prep_all<<<9376, blk, 0, stream>>>(x, x_bf,
                                     Wq_lin, Wk_lin, Wv_lin, Wo_lin, Wq, Wo,
                                     bq_lin, bk_lin, bv_lin,
                                     Wcomb, WtO1, WtQ2, WtO2, bqkv,
                                     bk, bv, klast, vlast);
  gemm_mfma<<<768, blk, 0, stream>>>(x_bf, Wcomb, bqkv, (float*)0, qkv_b, 8192, QKVN, 1024);
  transV<<<2048, blk, 0, stream>>>(qkv_b, vT);
  phaseA2<<<1024, blk, 0, stream>>>(qkv_b, vT, KVc_t, kstc);
  phaseB3<<<585, blk, 0, stream>>>(KVc_t, kstc, kv0, kst0, KVp_t, kstp, kv_out, kst_out);
  phaseC4<<<1024, blk, 0, stream>>>(qkv_b, vT, KVp_t, kstp, outs_bf);
  gemm_mfma<<<512, blk, 0, stream>>>(outs_bf, WtO1, bo_lin, (float*)0, tmp_b, 8192, 1024, 1024);
  ln_add2<<<8192, blk, 0, stream>>>(x, (const unsigned short*)0, tmp_b, gamma, beta, (float*)0, x1b);
  gemm_mfma<<<512, blk, 0, stream>>>(x1b, WtQ2, bq, (float*)0, q2b, 8192, 1024, 1024);
  lastrow_qkv2<<<512, blk, 0, stream>>>(x1b, Wk, Wv, klast, vlast);
  prep_window<<<64, blk, 0, stream>>>(kbuf, vbufw, klast, vlast, ukb, uvTw);
  window_attn2<<<1024, blk, 0, stream>>>(q2b, ukb, uvTw, winb);
  gemm_mfma<<<512, blk, 0, stream>>>(winb, WtO2, bo, (float*)0, tmp2_b, 8192, 1024, 1024);
  ln_add2<<<8192, blk, 0, stream>>>((const float*)0, x1b, tmp2_b, gamma, beta, out, (unsigned short*)0);
}